// Round 2
// baseline (2248.546 us; speedup 1.0000x reference)
//
#include <hip/hip_runtime.h>
#include <cmath>

#define NPIX 4352      // 16 * 17 * 16 pixels (incl. cls row)
#define C_DIM 256

__device__ __forceinline__ float gelu_f(float v) {
    return 0.5f * v * (1.0f + erff(v * 0.70710678118654752f));
}

// ---------------- patch embed + pos emb + cls row ----------------
__global__ __launch_bounds__(256) void patch_embed_k(
    const float* __restrict__ x, const float* __restrict__ pw,
    const float* __restrict__ pb, const float* __restrict__ row_emb,
    const float* __restrict__ col_emb, const float* __restrict__ cls_tok,
    float* __restrict__ out)
{
    int p = blockIdx.x;          // pixel: b*272 + y*16 + xw
    int c = threadIdx.x;         // channel
    int b = p / 272;
    int rem = p - b * 272;
    int y = rem >> 4;
    int xw = rem & 15;
    float v;
    if (y == 0) {
        v = cls_tok[c];
    } else {
        int gr = y - 1, gc = xw;
        const float* xb = x + (size_t)b * 3 * 1024;   // (3,32,32)
        const float* wc = pw + (size_t)c * 12;        // (256,3,2,2)
        float acc = pb[c];
        #pragma unroll
        for (int ci = 0; ci < 3; ci++)
            #pragma unroll
            for (int ph = 0; ph < 2; ph++)
                #pragma unroll
                for (int pq = 0; pq < 2; pq++)
                    acc += xb[ci * 1024 + (2 * gr + ph) * 32 + (2 * gc + pq)]
                         * wc[(ci * 2 + ph) * 2 + pq];
        acc += (c < 128) ? row_emb[gr * 128 + c] : col_emb[gc * 128 + (c - 128)];
        v = acc;
    }
    out[(size_t)p * C_DIM + c] = v;
}

// ---------------- layernorm: one block (256 thr) per row ----------------
__global__ __launch_bounds__(256) void layernorm_k(
    const float* __restrict__ in, const float* __restrict__ w,
    const float* __restrict__ b, float* __restrict__ out)
{
    __shared__ float red[8];
    int r = blockIdx.x, c = threadIdx.x;
    float v = in[(size_t)r * C_DIM + c];
    float s = v;
    s += __shfl_down(s, 32); s += __shfl_down(s, 16); s += __shfl_down(s, 8);
    s += __shfl_down(s, 4);  s += __shfl_down(s, 2);  s += __shfl_down(s, 1);
    if ((c & 63) == 0) red[c >> 6] = s;
    __syncthreads();
    float mu = (red[0] + red[1] + red[2] + red[3]) * (1.0f / 256.0f);
    float d = v - mu;
    float s2 = d * d;
    s2 += __shfl_down(s2, 32); s2 += __shfl_down(s2, 16); s2 += __shfl_down(s2, 8);
    s2 += __shfl_down(s2, 4);  s2 += __shfl_down(s2, 2);  s2 += __shfl_down(s2, 1);
    if ((c & 63) == 0) red[4 + (c >> 6)] = s2;
    __syncthreads();
    float var = (red[4] + red[5] + red[6] + red[7]) * (1.0f / 256.0f);
    out[(size_t)r * C_DIM + c] = d * rsqrtf(var + 1e-5f) * w[c] + b[c];
}

// ---------------- generic fp32 GEMM: out[M,N] = A[M,K] @ W[N,K]^T ----------------
// MODE: 0 = plain (no bias), 2 = bias+gelu, 3 = bias+residual
template <int MODE>
__global__ __launch_bounds__(256) void gemm_k(
    const float* __restrict__ A, const float* __restrict__ Wt,
    const float* __restrict__ bias, const float* __restrict__ res,
    float* __restrict__ out, int M, int N, int K)
{
    __shared__ float As[16][68];   // [kk][m], 64-wide + pad
    __shared__ float Bs[16][68];
    int m0 = blockIdx.x * 64;
    int n0 = blockIdx.y * 64;
    int t = threadIdx.x;
    int tx = t & 15, ty = t >> 4;
    int lr = t >> 2;            // load row 0..63
    int lc = (t & 3) * 4;       // load col {0,4,8,12}
    float acc[4][4];
    #pragma unroll
    for (int i = 0; i < 4; i++)
        #pragma unroll
        for (int j = 0; j < 4; j++) acc[i][j] = 0.0f;

    for (int k0 = 0; k0 < K; k0 += 16) {
        __syncthreads();
        float4 av = *(const float4*)&A[(size_t)(m0 + lr) * K + k0 + lc];
        float4 bv = *(const float4*)&Wt[(size_t)(n0 + lr) * K + k0 + lc];
        As[lc + 0][lr] = av.x; As[lc + 1][lr] = av.y;
        As[lc + 2][lr] = av.z; As[lc + 3][lr] = av.w;
        Bs[lc + 0][lr] = bv.x; Bs[lc + 1][lr] = bv.y;
        Bs[lc + 2][lr] = bv.z; Bs[lc + 3][lr] = bv.w;
        __syncthreads();
        #pragma unroll
        for (int kk = 0; kk < 16; kk++) {
            float4 a4 = *(const float4*)&As[kk][ty * 4];
            float4 b4 = *(const float4*)&Bs[kk][tx * 4];
            float a[4] = {a4.x, a4.y, a4.z, a4.w};
            float bb[4] = {b4.x, b4.y, b4.z, b4.w};
            #pragma unroll
            for (int i = 0; i < 4; i++)
                #pragma unroll
                for (int j = 0; j < 4; j++)
                    acc[i][j] += a[i] * bb[j];
        }
    }
    #pragma unroll
    for (int i = 0; i < 4; i++) {
        int mrow = m0 + ty * 4 + i;
        #pragma unroll
        for (int j = 0; j < 4; j++) {
            int ncol = n0 + tx * 4 + j;
            float v = acc[i][j];
            if (MODE >= 2) v += bias[ncol];
            if (MODE == 2) v = gelu_f(v);
            if (MODE == 3) v += res[(size_t)mrow * N + ncol];
            out[(size_t)mrow * N + ncol] = v;
        }
    }
}

// ---------------- sliding-window attention ----------------
// One block per (window, 16-query tile). Online softmax over key chunks of 16.
// Writes normalized per-window outputs to obuf at ((wrel*T + n)*256 + c).
__global__ __launch_bounds__(256) void attn_win(
    const float* __restrict__ qkv, float* __restrict__ obuf,
    int k, int Lh, int Lw, int w0, float scale)
{
    int T = k * k;
    int nqt = T >> 4;
    int bid = blockIdx.x;
    int qt = bid % nqt;
    int wrel = bid / nqt;
    int widx = w0 + wrel;
    int L = Lh * Lw;
    int b = widx / L;
    int l = widx - b * L;
    int lh = l / Lw, lw = l - lh * Lw;

    __shared__ float Qs[16][260];
    __shared__ float Ks[16][260];
    __shared__ float Vs[16][260];

    int t = threadIdx.x;
    int ql = t >> 4;     // query row within tile
    int jj = t & 15;     // key slot / channel phase

    // load Q tile (16 tokens x 256 ch), coalesced
    for (int r = 0; r < 16; r++) {
        int n = qt * 16 + r;
        int y = lh + n / k, xx = lw + n % k;
        Qs[r][t] = qkv[(((size_t)b * 17 + y) * 16 + xx) * 768 + t];
    }

    float m = -1e30f, lsum = 0.0f;
    float o[16];
    #pragma unroll
    for (int i = 0; i < 16; i++) o[i] = 0.0f;

    int lanebase = t & 0x30;   // in-wave base of this query's 16-lane group

    for (int ch = 0; ch < nqt; ch++) {        // nqt == T/16 key chunks
        __syncthreads();
        for (int r = 0; r < 16; r++) {
            int n = ch * 16 + r;
            int y = lh + n / k, xx = lw + n % k;
            const float* base = qkv + (((size_t)b * 17 + y) * 16 + xx) * 768;
            Ks[r][t] = base[256 + t];
            Vs[r][t] = base[512 + t];
        }
        __syncthreads();
        // score S[ql][jj] = scale * dot(Q[ql], K[jj]) over 256 ch
        float s = 0.0f;
        const float4* qrow = (const float4*)Qs[ql];
        const float4* krow = (const float4*)Ks[jj];
        #pragma unroll 8
        for (int c4 = 0; c4 < 64; c4++) {
            float4 a = qrow[c4], bb = krow[c4];
            s += a.x * bb.x + a.y * bb.y + a.z * bb.z + a.w * bb.w;
        }
        s *= scale;
        // online softmax within the 16-lane query group
        float mx = s;
        mx = fmaxf(mx, __shfl_xor(mx, 1));
        mx = fmaxf(mx, __shfl_xor(mx, 2));
        mx = fmaxf(mx, __shfl_xor(mx, 4));
        mx = fmaxf(mx, __shfl_xor(mx, 8));
        float mnew = fmaxf(m, mx);
        float p = __expf(s - mnew);
        float ps = p;
        ps += __shfl_xor(ps, 1);
        ps += __shfl_xor(ps, 2);
        ps += __shfl_xor(ps, 4);
        ps += __shfl_xor(ps, 8);
        float alpha = __expf(m - mnew);
        lsum = lsum * alpha + ps;
        m = mnew;
        #pragma unroll
        for (int i = 0; i < 16; i++) o[i] *= alpha;
        #pragma unroll
        for (int j2 = 0; j2 < 16; j2++) {
            float pj = __shfl(p, lanebase | j2);
            #pragma unroll
            for (int i = 0; i < 16; i++)
                o[i] += pj * Vs[j2][jj + (i << 4)];   // ch = jj + 16*i (bank-clean)
        }
    }
    float inv = 1.0f / lsum;
    int n = qt * 16 + ql;
    float* orow = obuf + ((size_t)wrel * T + n) * C_DIM;
    #pragma unroll
    for (int i = 0; i < 16; i++) orow[jj + (i << 4)] = o[i] * inv;
}

// ---------------- overlap-add fold (gather, deterministic) ----------------
// y[p] = (xin ? xin[p] : y[p]) + sum over covering windows in [w0,w1)
__global__ __launch_bounds__(256) void fold_add(
    const float* __restrict__ obuf, const float* __restrict__ xin,
    float* __restrict__ y, int k, int Lh, int Lw, int w0, int w1)
{
    int p = blockIdx.x;
    int c = threadIdx.x;
    int b = p / 272;
    int rem = p - b * 272;
    int yy = rem >> 4, xx = rem & 15;
    int L = Lh * Lw;
    int T = k * k;
    float acc = xin ? xin[(size_t)p * C_DIM + c] : y[(size_t)p * C_DIM + c];
    int lh0 = max(0, yy - k + 1), lh1 = min(Lh - 1, yy);
    int lw0 = max(0, xx - k + 1), lw1 = min(Lw - 1, xx);
    for (int lh = lh0; lh <= lh1; lh++) {
        for (int lw = lw0; lw <= lw1; lw++) {
            int widx = b * L + lh * Lw + lw;
            if (widx < w0 || widx >= w1) continue;
            int n = (yy - lh) * k + (xx - lw);
            acc += obuf[((size_t)(widx - w0) * T + n) * C_DIM + c];
        }
    }
    y[(size_t)p * C_DIM + c] = acc;
}

// ---------------- classifier: out[b,n] = h[b,0,0,:] @ cls_w[n,:] + cls_b[n] ----------------
__global__ __launch_bounds__(256) void classifier_k(
    const float* __restrict__ h, const float* __restrict__ cw,
    const float* __restrict__ cb, float* __restrict__ out)
{
    __shared__ float hrow[256];
    int b = blockIdx.x;
    int n = blockIdx.y * 256 + threadIdx.x;
    hrow[threadIdx.x] = h[(size_t)b * 272 * C_DIM + threadIdx.x];
    __syncthreads();
    if (n < 1000) {
        float acc = cb[n];
        const float* wr = cw + (size_t)n * C_DIM;
        for (int c = 0; c < 256; c++) acc += hrow[c] * wr[c];
        out[(size_t)b * 1000 + n] = acc;
    }
}

extern "C" void kernel_launch(void* const* d_in, const int* in_sizes, int n_in,
                              void* d_out, int out_size, void* d_ws, size_t ws_size,
                              hipStream_t stream)
{
    const float* x       = (const float*)d_in[0];
    const float* patch_w = (const float*)d_in[1];
    const float* patch_b = (const float*)d_in[2];
    const float* row_emb = (const float*)d_in[3];
    const float* col_emb = (const float*)d_in[4];
    const float* cls_tok = (const float*)d_in[5];
    const float* ln1_w   = (const float*)d_in[6];
    const float* ln1_b   = (const float*)d_in[7];
    const float* qkv_w   = (const float*)d_in[8];
    const float* ln2_w   = (const float*)d_in[9];
    const float* ln2_b   = (const float*)d_in[10];
    const float* mlp_w1  = (const float*)d_in[11];
    const float* mlp_b1  = (const float*)d_in[12];
    const float* mlp_w2  = (const float*)d_in[13];
    const float* mlp_b2  = (const float*)d_in[14];
    const float* cls_w   = (const float*)d_in[15];
    const float* cls_b   = (const float*)d_in[16];
    float* out = (float*)d_out;

    float* ws = (float*)d_ws;
    const size_t OBUF_CAP = 6u * 1024u * 1024u;   // floats
    float* xb0  = ws;                              // NPIX*256
    float* xb1  = xb0 + (size_t)NPIX * C_DIM;      // NPIX*256
    float* qkv  = xb1 + (size_t)NPIX * C_DIM;      // NPIX*768
    float* scr  = qkv + (size_t)NPIX * 768;        // union region
    float* lnb  = scr;                             // NPIX*256
    float* h1   = scr + (size_t)NPIX * C_DIM;      // NPIX*512
    float* obuf = scr;                             // OBUF_CAP

    patch_embed_k<<<NPIX, 256, 0, stream>>>(x, patch_w, patch_b, row_emb,
                                            col_emb, cls_tok, xb0);

    const int KS[7] = {4, 4, 8, 8, 8, 16, 16};
    float* xcur = xb0;
    float* ybuf = xb1;

    for (int i = 0; i < 7; i++) {
        int k = KS[i];
        int Lh = 18 - k, Lw = 17 - k, L = Lh * Lw, T = k * k;
        float scale = 1.0f / std::sqrt((float)(256 / k));    // heads == k here

        // LN1
        layernorm_k<<<NPIX, 256, 0, stream>>>(xcur, ln1_w + i * 256,
                                              ln1_b + i * 256, lnb);
        // QKV GEMM (no bias): M=NPIX, N=768, K=256
        gemm_k<0><<<dim3(NPIX / 64, 768 / 64), 256, 0, stream>>>(
            lnb, qkv_w + (size_t)i * 768 * 256, nullptr, nullptr, qkv,
            NPIX, 768, 256);

        // attention + fold, chunked over windows to bound scratch
        int totalW = 16 * L;
        int perW = T * C_DIM;
        int maxW = (int)(OBUF_CAP / (size_t)perW);
        int nqt = T / 16;
        for (int w0 = 0; w0 < totalW; w0 += maxW) {
            int nW = totalW - w0 < maxW ? totalW - w0 : maxW;
            attn_win<<<nW * nqt, 256, 0, stream>>>(qkv, obuf, k, Lh, Lw, w0, scale);
            fold_add<<<NPIX, 256, 0, stream>>>(obuf, (w0 == 0) ? xcur : nullptr,
                                               ybuf, k, Lh, Lw, w0, w0 + nW);
        }

        // LN2
        layernorm_k<<<NPIX, 256, 0, stream>>>(ybuf, ln2_w + i * 256,
                                              ln2_b + i * 256, lnb);
        // MLP1 + gelu: M=NPIX, N=512, K=256
        gemm_k<2><<<dim3(NPIX / 64, 512 / 64), 256, 0, stream>>>(
            lnb, mlp_w1 + (size_t)i * 512 * 256, mlp_b1 + i * 512, nullptr, h1,
            NPIX, 512, 256);
        // MLP2 + bias + residual(y): M=NPIX, N=256, K=512 -> new x into xcur
        gemm_k<3><<<dim3(NPIX / 64, 256 / 64), 256, 0, stream>>>(
            h1, mlp_w2 + (size_t)i * 256 * 512, mlp_b2 + i * 256, ybuf, xcur,
            NPIX, 256, 512);
    }

    classifier_k<<<dim3(16, 4), 256, 0, stream>>>(xcur, cls_w, cls_b, out);
}

// Round 3
// 1241.967 us; speedup vs baseline: 1.8105x; 1.8105x over previous
//
#include <hip/hip_runtime.h>
#include <cmath>

#define NPIX 4352      // 16 * 17 * 16 pixels (incl. cls row)
#define C_DIM 256

typedef unsigned short ushort_t;
typedef unsigned int uint_t;
typedef float f32x4 __attribute__((ext_vector_type(4)));
typedef __bf16 bfx8 __attribute__((ext_vector_type(8)));

__device__ __forceinline__ ushort_t f2bf(float f) {
    uint_t u = __float_as_uint(f);
    u = (u + 0x7FFFu + ((u >> 16) & 1u)) >> 16;
    return (ushort_t)u;
}
__device__ __forceinline__ float bf2f(ushort_t b) {
    return __uint_as_float(((uint_t)b) << 16);
}
__device__ __forceinline__ float gelu_f(float v) {
    return 0.5f * v * (1.0f + erff(v * 0.70710678118654752f));
}

// ---------------- fp32 -> bf16 converter (weights) ----------------
__global__ __launch_bounds__(256) void conv_bf16(
    const float* __restrict__ in, ushort_t* __restrict__ out, int n)
{
    for (int i = blockIdx.x * 256 + threadIdx.x; i < n; i += gridDim.x * 256)
        out[i] = f2bf(in[i]);
}

// ---------------- patch embed + pos emb + cls row ----------------
__global__ __launch_bounds__(256) void patch_embed_k(
    const float* __restrict__ x, const float* __restrict__ pw,
    const float* __restrict__ pb, const float* __restrict__ row_emb,
    const float* __restrict__ col_emb, const float* __restrict__ cls_tok,
    float* __restrict__ out)
{
    int p = blockIdx.x;
    int c = threadIdx.x;
    int b = p / 272;
    int rem = p - b * 272;
    int y = rem >> 4;
    int xw = rem & 15;
    float v;
    if (y == 0) {
        v = cls_tok[c];
    } else {
        int gr = y - 1, gc = xw;
        const float* xb = x + (size_t)b * 3 * 1024;
        const float* wc = pw + (size_t)c * 12;
        float acc = pb[c];
        #pragma unroll
        for (int ci = 0; ci < 3; ci++)
            #pragma unroll
            for (int ph = 0; ph < 2; ph++)
                #pragma unroll
                for (int pq = 0; pq < 2; pq++)
                    acc += xb[ci * 1024 + (2 * gr + ph) * 32 + (2 * gc + pq)]
                         * wc[(ci * 2 + ph) * 2 + pq];
        acc += (c < 128) ? row_emb[gr * 128 + c] : col_emb[gc * 128 + (c - 128)];
        v = acc;
    }
    out[(size_t)p * C_DIM + c] = v;
}

// ---------------- layernorm: fp32 in -> bf16 out ----------------
__global__ __launch_bounds__(256) void layernorm_k(
    const float* __restrict__ in, const float* __restrict__ w,
    const float* __restrict__ b, ushort_t* __restrict__ out)
{
    __shared__ float red[8];
    int r = blockIdx.x, c = threadIdx.x;
    float v = in[(size_t)r * C_DIM + c];
    float s = v;
    s += __shfl_down(s, 32); s += __shfl_down(s, 16); s += __shfl_down(s, 8);
    s += __shfl_down(s, 4);  s += __shfl_down(s, 2);  s += __shfl_down(s, 1);
    if ((c & 63) == 0) red[c >> 6] = s;
    __syncthreads();
    float mu = (red[0] + red[1] + red[2] + red[3]) * (1.0f / 256.0f);
    float d = v - mu;
    float s2 = d * d;
    s2 += __shfl_down(s2, 32); s2 += __shfl_down(s2, 16); s2 += __shfl_down(s2, 8);
    s2 += __shfl_down(s2, 4);  s2 += __shfl_down(s2, 2);  s2 += __shfl_down(s2, 1);
    if ((c & 63) == 0) red[4 + (c >> 6)] = s2;
    __syncthreads();
    float var = (red[4] + red[5] + red[6] + red[7]) * (1.0f / 256.0f);
    out[(size_t)r * C_DIM + c] = f2bf(d * rsqrtf(var + 1e-5f) * w[c] + b[c]);
}

// ---------------- bf16 MFMA GEMM: C[M,N] = A[M,K] @ B[N,K]^T ----------------
// MODE 0: qkv split epilogue (Q,K bf16 row-major; V -> vT[c][pixel])
// MODE 2: bias + gelu -> bf16 out
// MODE 3: bias + residual -> fp32 out
template <int MODE>
__global__ __launch_bounds__(256) void gemm_bf16(
    const ushort_t* __restrict__ A, const ushort_t* __restrict__ B,
    const float* __restrict__ bias, const float* __restrict__ res,
    void* __restrict__ outp, ushort_t* __restrict__ vT,
    int M, int N, int K)
{
    int m0 = blockIdx.x * 64, n0 = blockIdx.y * 64;
    int t = threadIdx.x, lane = t & 63, wv = t >> 6;
    int l15 = lane & 15, lg = lane >> 4;
    int ncol = n0 + wv * 16 + l15;
    f32x4 acc[4] = {};
    const ushort_t* Brow = B + (size_t)ncol * K;
    for (int ks = 0; ks < K; ks += 32) {
        bfx8 bf = *(const bfx8*)(Brow + ks + lg * 8);
        #pragma unroll
        for (int i = 0; i < 4; i++) {
            bfx8 af = *(const bfx8*)(A + (size_t)(m0 + 16 * i + l15) * K + ks + lg * 8);
            acc[i] = __builtin_amdgcn_mfma_f32_16x16x32_bf16(af, bf, acc[i], 0, 0, 0);
        }
    }
    if (MODE == 0) {
        if (n0 < 512) {
            #pragma unroll
            for (int i = 0; i < 4; i++) {
                int m = m0 + 16 * i + lg * 4;
                #pragma unroll
                for (int r = 0; r < 4; r++)
                    ((ushort_t*)outp)[(size_t)(m + r) * 512 + ncol] = f2bf(acc[i][r]);
            }
        } else {
            #pragma unroll
            for (int i = 0; i < 4; i++) {
                int m = m0 + 16 * i + lg * 4;
                ushort4 pk;
                pk.x = f2bf(acc[i][0]); pk.y = f2bf(acc[i][1]);
                pk.z = f2bf(acc[i][2]); pk.w = f2bf(acc[i][3]);
                *(ushort4*)&vT[(size_t)(ncol - 512) * NPIX + m] = pk;
            }
        }
    } else if (MODE == 2) {
        float bz = bias[ncol];
        #pragma unroll
        for (int i = 0; i < 4; i++) {
            int m = m0 + 16 * i + lg * 4;
            #pragma unroll
            for (int r = 0; r < 4; r++) {
                float v = gelu_f(acc[i][r] + bz);
                ((ushort_t*)outp)[(size_t)(m + r) * N + ncol] = f2bf(v);
            }
        }
    } else {
        float bz = bias[ncol];
        #pragma unroll
        for (int i = 0; i < 4; i++) {
            int m = m0 + 16 * i + lg * 4;
            #pragma unroll
            for (int r = 0; r < 4; r++) {
                float v = acc[i][r] + bz + res[(size_t)(m + r) * N + ncol];
                ((float*)outp)[(size_t)(m + r) * N + ncol] = v;
            }
        }
    }
}

// unaligned (element-granular) loaders from a dword-aligned row
__device__ __forceinline__ uint2 ld_u4_align(const uint_t* drow, int e0) {
    int d0 = e0 >> 1;
    if (!(e0 & 1)) return make_uint2(drow[d0], drow[d0 + 1]);
    uint_t a = drow[d0], b = drow[d0 + 1], c = drow[d0 + 2];
    return make_uint2((a >> 16) | (b << 16), (b >> 16) | (c << 16));
}
__device__ __forceinline__ uint4 ld_u8_align(const uint_t* drow, int e0) {
    int d0 = e0 >> 1;
    if (!(e0 & 1)) return make_uint4(drow[d0], drow[d0 + 1], drow[d0 + 2], drow[d0 + 3]);
    uint_t a = drow[d0], b = drow[d0 + 1], c = drow[d0 + 2], d = drow[d0 + 3], e = drow[d0 + 4];
    return make_uint4((a >> 16) | (b << 16), (b >> 16) | (c << 16),
                      (c >> 16) | (d << 16), (d >> 16) | (e << 16));
}

// ---------------- MFMA sliding-window attention ----------------
// qk: [pixel][512] bf16 (Q|K). vT: [256][pixel] bf16. obuf: bf16 window outputs.
// No __syncthreads anywhere: each wave owns a 16-query strip independently.
template <int KK>
__global__ __launch_bounds__(256) void attn_mfma(
    const ushort_t* __restrict__ qk, const ushort_t* __restrict__ vT,
    ushort_t* __restrict__ obuf, int w0, int nW, float scale)
{
    constexpr int T = KK * KK;
    constexpr int KC = (KK == 4) ? 16 : 64;   // key-chunk tokens
    constexpr int NCH = T / KC;               // chunks (flash loop)
    constexpr int NF = KC / 16;               // S frags per chunk
    constexpr int PVK = (KC < 32) ? 32 : KC;  // zero-padded k for PV MFMA
    constexpr int PVSTR = PVK + 8;
    constexpr int Lh = 18 - KK, Lw = 17 - KK;
    constexpr int L = Lh * Lw;

    __shared__ ushort_t P_lds[4][16][PVSTR];

    int t = threadIdx.x, lane = t & 63, wv = t >> 6;
    int l15 = lane & 15, lg = lane >> 4;

    int wrel, qbase;
    if (KK == 4)       { wrel = blockIdx.x * 4 + wv; qbase = 0; if (wrel >= nW) return; }
    else if (KK == 8)  { wrel = blockIdx.x; qbase = wv * 16; }
    else               { wrel = blockIdx.x >> 2; qbase = (blockIdx.x & 3) * 64 + wv * 16; }

    int widx = w0 + wrel;
    int b = widx / L, lrem = widx % L;
    int lh = lrem / Lw, lw = lrem % Lw;
    int pbase = b * 272 + lh * 16 + lw;     // pixel index of window token 0

    // hoisted Q fragments (16 rows x 256 ch)
    int qtok = qbase + l15;
    int qpix = pbase + (qtok / KK) * 16 + (qtok % KK);
    bfx8 qf[8];
    #pragma unroll
    for (int cs = 0; cs < 8; cs++)
        qf[cs] = *(const bfx8*)(qk + (size_t)qpix * 512 + cs * 32 + lg * 8);

    f32x4 o[16];
    #pragma unroll
    for (int j = 0; j < 16; j++) o[j] = f32x4{0.f, 0.f, 0.f, 0.f};
    float mold[4] = {-1e30f, -1e30f, -1e30f, -1e30f};
    float lsum[4] = {0.f, 0.f, 0.f, 0.f};

    for (int ch = 0; ch < NCH; ch++) {
        int c0 = ch * KC;
        // ---- S = Q.K^T for this key chunk ----
        f32x4 s[NF];
        #pragma unroll
        for (int j = 0; j < NF; j++) s[j] = f32x4{0.f, 0.f, 0.f, 0.f};
        #pragma unroll
        for (int cs = 0; cs < 8; cs++) {
            #pragma unroll
            for (int j = 0; j < NF; j++) {
                int ktok = c0 + j * 16 + l15;
                int kpix = pbase + (ktok / KK) * 16 + (ktok % KK);
                bfx8 kf = *(const bfx8*)(qk + (size_t)kpix * 512 + 256 + cs * 32 + lg * 8);
                s[j] = __builtin_amdgcn_mfma_f32_16x16x32_bf16(qf[cs], kf, s[j], 0, 0, 0);
            }
        }
        // ---- online softmax (rows r across 16-lane groups) ----
        float alpha[4];
        float p[NF][4];
        #pragma unroll
        for (int r = 0; r < 4; r++) {
            float mx = s[0][r];
            #pragma unroll
            for (int j = 1; j < NF; j++) mx = fmaxf(mx, s[j][r]);
            mx = fmaxf(mx, __shfl_xor(mx, 1));
            mx = fmaxf(mx, __shfl_xor(mx, 2));
            mx = fmaxf(mx, __shfl_xor(mx, 4));
            mx = fmaxf(mx, __shfl_xor(mx, 8));
            float mnew = fmaxf(mold[r], mx);
            alpha[r] = __expf(scale * (mold[r] - mnew));
            float ps = 0.f;
            #pragma unroll
            for (int j = 0; j < NF; j++) {
                p[j][r] = __expf(scale * (s[j][r] - mnew));
                ps += p[j][r];
            }
            ps += __shfl_xor(ps, 1);
            ps += __shfl_xor(ps, 2);
            ps += __shfl_xor(ps, 4);
            ps += __shfl_xor(ps, 8);
            lsum[r] = lsum[r] * alpha[r] + ps;
            mold[r] = mnew;
        }
        if (NCH > 1) {
            #pragma unroll
            for (int j = 0; j < 16; j++) {
                o[j][0] *= alpha[0]; o[j][1] *= alpha[1];
                o[j][2] *= alpha[2]; o[j][3] *= alpha[3];
            }
        }
        // ---- P -> bf16 -> per-wave LDS tile ----
        #pragma unroll
        for (int j = 0; j < NF; j++)
            #pragma unroll
            for (int r = 0; r < 4; r++)
                P_lds[wv][lg * 4 + r][j * 16 + l15] = f2bf(p[j][r]);
        if (KK == 4) {
            #pragma unroll
            for (int r = 0; r < 4; r++)
                P_lds[wv][lg * 4 + r][16 + l15] = 0;
        }
        asm volatile("s_waitcnt lgkmcnt(0)" ::: "memory");
        __builtin_amdgcn_sched_barrier(0);
        // ---- O += P.V ----
        #pragma unroll
        for (int kt = 0; kt < PVK / 32; kt++) {
            bfx8 pf = *(const bfx8*)&P_lds[wv][l15][kt * 32 + lg * 8];
            int tk0 = kt * 32 + lg * 8;   // chunk-local token base of this lane's 8 elems
            #pragma unroll
            for (int j = 0; j < 16; j++) {
                int c = j * 16 + l15;
                const uint_t* drow = (const uint_t*)(vT + (size_t)c * NPIX);
                bfx8 vf;
                if (KK == 4) {
                    int tkm = tk0 & 15;                     // wrap padded tokens (P=0)
                    int pa = pbase + (tkm >> 2) * 16;       // run of 4, then next row
                    uint2 u1 = ld_u4_align(drow, pa);
                    uint2 u2 = ld_u4_align(drow, pa + 16);
                    uint4 u = make_uint4(u1.x, u1.y, u2.x, u2.y);
                    vf = __builtin_bit_cast(bfx8, u);
                } else if (KK == 8) {
                    int tok = c0 + tk0;
                    int pix = pbase + (tok >> 3) * 16;      // tok%8==0, 8-px run
                    uint4 u = ld_u8_align(drow, pix);
                    vf = __builtin_bit_cast(bfx8, u);
                } else {
                    int tok = c0 + tk0;
                    int pix = pbase + (tok >> 4) * 16 + (tok & 15);  // 16B aligned
                    vf = *(const bfx8*)(vT + (size_t)c * NPIX + pix);
                }
                o[j] = __builtin_amdgcn_mfma_f32_16x16x32_bf16(pf, vf, o[j], 0, 0, 0);
            }
        }
    }
    // ---- normalize + write ----
    float inv[4];
    #pragma unroll
    for (int r = 0; r < 4; r++) inv[r] = 1.0f / lsum[r];
    #pragma unroll
    for (int j = 0; j < 16; j++) {
        int c = j * 16 + l15;
        #pragma unroll
        for (int r = 0; r < 4; r++) {
            int n = qbase + lg * 4 + r;
            obuf[((size_t)wrel * T + n) * C_DIM + c] = f2bf(o[j][r] * inv[r]);
        }
    }
}

// ---------------- overlap-add fold (gather, deterministic) ----------------
__global__ __launch_bounds__(256) void fold_add(
    const ushort_t* __restrict__ obuf, const float* __restrict__ xin,
    float* __restrict__ y, int k, int Lh, int Lw, int w0, int w1)
{
    int p = blockIdx.x;
    int c = threadIdx.x;
    int b = p / 272;
    int rem = p - b * 272;
    int yy = rem >> 4, xx = rem & 15;
    int L = Lh * Lw;
    int T = k * k;
    float acc = xin ? xin[(size_t)p * C_DIM + c] : y[(size_t)p * C_DIM + c];
    int lh0 = max(0, yy - k + 1), lh1 = min(Lh - 1, yy);
    int lw0 = max(0, xx - k + 1), lw1 = min(Lw - 1, xx);
    for (int lh = lh0; lh <= lh1; lh++) {
        for (int lw = lw0; lw <= lw1; lw++) {
            int widx = b * L + lh * Lw + lw;
            if (widx < w0 || widx >= w1) continue;
            int n = (yy - lh) * k + (xx - lw);
            acc += bf2f(obuf[((size_t)(widx - w0) * T + n) * C_DIM + c]);
        }
    }
    y[(size_t)p * C_DIM + c] = acc;
}

// ---------------- classifier ----------------
__global__ __launch_bounds__(256) void classifier_k(
    const float* __restrict__ h, const float* __restrict__ cw,
    const float* __restrict__ cb, float* __restrict__ out)
{
    __shared__ float hrow[256];
    int b = blockIdx.x;
    int n = blockIdx.y * 256 + threadIdx.x;
    hrow[threadIdx.x] = h[(size_t)b * 272 * C_DIM + threadIdx.x];
    __syncthreads();
    if (n < 1000) {
        float acc = cb[n];
        const float* wr = cw + (size_t)n * C_DIM;
        for (int c = 0; c < 256; c++) acc += hrow[c] * wr[c];
        out[(size_t)b * 1000 + n] = acc;
    }
}

extern "C" void kernel_launch(void* const* d_in, const int* in_sizes, int n_in,
                              void* d_out, int out_size, void* d_ws, size_t ws_size,
                              hipStream_t stream)
{
    const float* x       = (const float*)d_in[0];
    const float* patch_w = (const float*)d_in[1];
    const float* patch_b = (const float*)d_in[2];
    const float* row_emb = (const float*)d_in[3];
    const float* col_emb = (const float*)d_in[4];
    const float* cls_tok = (const float*)d_in[5];
    const float* ln1_w   = (const float*)d_in[6];
    const float* ln1_b   = (const float*)d_in[7];
    const float* qkv_w   = (const float*)d_in[8];
    const float* ln2_w   = (const float*)d_in[9];
    const float* ln2_b   = (const float*)d_in[10];
    const float* mlp_w1  = (const float*)d_in[11];
    const float* mlp_b1  = (const float*)d_in[12];
    const float* mlp_w2  = (const float*)d_in[13];
    const float* mlp_b2  = (const float*)d_in[14];
    const float* cls_w   = (const float*)d_in[15];
    const float* cls_b   = (const float*)d_in[16];
    float* out = (float*)d_out;

    // workspace layout (all 16B aligned)
    float* xb0  = (float*)d_ws;                          // NPIX*256 f32
    float* xb1  = xb0 + (size_t)NPIX * 256;              // NPIX*256 f32
    ushort_t* lnb = (ushort_t*)(xb1 + (size_t)NPIX * 256);   // NPIX*256 bf16
    ushort_t* qkb = lnb + (size_t)NPIX * 256;            // NPIX*512 bf16 (Q|K)
    ushort_t* vT  = qkb + (size_t)NPIX * 512;            // 256*NPIX bf16
    ushort_t* h1  = vT + (size_t)256 * NPIX;             // NPIX*512 bf16
    ushort_t* wq  = h1 + (size_t)NPIX * 512;             // 7*768*256 bf16
    ushort_t* w1b = wq + (size_t)7 * 768 * 256;          // 7*512*256 bf16
    ushort_t* w2b = w1b + (size_t)7 * 512 * 256;         // 7*256*512 bf16
    ushort_t* obuf = w2b + (size_t)7 * 256 * 512;        // 8M bf16 (16 MB)
    const size_t OBUF_CAP_E = 8u * 1024u * 1024u;

    conv_bf16<<<1024, 256, 0, stream>>>(qkv_w, wq, 7 * 768 * 256);
    conv_bf16<<<1024, 256, 0, stream>>>(mlp_w1, w1b, 7 * 512 * 256);
    conv_bf16<<<1024, 256, 0, stream>>>(mlp_w2, w2b, 7 * 256 * 512);

    patch_embed_k<<<NPIX, 256, 0, stream>>>(x, patch_w, patch_b, row_emb,
                                            col_emb, cls_tok, xb0);

    const int KS[7] = {4, 4, 8, 8, 8, 16, 16};
    float* xcur = xb0;
    float* ybuf = xb1;

    for (int i = 0; i < 7; i++) {
        int k = KS[i];
        int Lh = 18 - k, Lw = 17 - k, L = Lh * Lw, T = k * k;
        float scale = 1.0f / std::sqrt((float)(256 / k));

        layernorm_k<<<NPIX, 256, 0, stream>>>(xcur, ln1_w + i * 256,
                                              ln1_b + i * 256, lnb);
        gemm_bf16<0><<<dim3(68, 12), 256, 0, stream>>>(
            lnb, wq + (size_t)i * 768 * 256, nullptr, nullptr, qkb, vT,
            NPIX, 768, 256);

        int totalW = 16 * L;
        int maxW = (int)(OBUF_CAP_E / (size_t)(T * C_DIM));
        for (int w0 = 0; w0 < totalW; w0 += maxW) {
            int nW = totalW - w0 < maxW ? totalW - w0 : maxW;
            if (k == 4)
                attn_mfma<4><<<(nW + 3) / 4, 256, 0, stream>>>(qkb, vT, obuf, w0, nW, scale);
            else if (k == 8)
                attn_mfma<8><<<nW, 256, 0, stream>>>(qkb, vT, obuf, w0, nW, scale);
            else
                attn_mfma<16><<<nW * 4, 256, 0, stream>>>(qkb, vT, obuf, w0, nW, scale);
            fold_add<<<NPIX, 256, 0, stream>>>(obuf, (w0 == 0) ? xcur : nullptr,
                                               ybuf, k, Lh, Lw, w0, w0 + nW);
        }

        layernorm_k<<<NPIX, 256, 0, stream>>>(ybuf, ln2_w + i * 256,
                                              ln2_b + i * 256, lnb);
        gemm_bf16<2><<<dim3(68, 8), 256, 0, stream>>>(
            lnb, w1b + (size_t)i * 512 * 256, mlp_b1 + i * 512, nullptr, h1, nullptr,
            NPIX, 512, 256);
        gemm_bf16<3><<<dim3(68, 4), 256, 0, stream>>>(
            h1, w2b + (size_t)i * 256 * 512, mlp_b2 + i * 256, ybuf, xcur, nullptr,
            NPIX, 256, 512);
    }

    classifier_k<<<dim3(16, 4), 256, 0, stream>>>(xcur, cls_w, cls_b, out);
}

// Round 4
// 999.332 us; speedup vs baseline: 2.2500x; 1.2428x over previous
//
#include <hip/hip_runtime.h>
#include <cmath>

#define NPIX 4352      // 16 * 17 * 16 pixels (incl. cls row)
#define C_DIM 256

typedef unsigned short ushort_t;
typedef unsigned int uint_t;
typedef float f32x4 __attribute__((ext_vector_type(4)));
typedef __bf16 bfx8 __attribute__((ext_vector_type(8)));

__device__ __forceinline__ ushort_t f2bf(float f) {
    uint_t u = __float_as_uint(f);
    u = (u + 0x7FFFu + ((u >> 16) & 1u)) >> 16;
    return (ushort_t)u;
}
__device__ __forceinline__ float bf2f(ushort_t b) {
    return __uint_as_float(((uint_t)b) << 16);
}
__device__ __forceinline__ float gelu_f(float v) {
    return 0.5f * v * (1.0f + erff(v * 0.70710678118654752f));
}

// ---------------- fp32 -> bf16 converter (all 3 weight tensors, 1 launch) ----------------
__global__ __launch_bounds__(256) void conv3_bf16(
    const float* __restrict__ a, ushort_t* __restrict__ oa, int na,
    const float* __restrict__ b, ushort_t* __restrict__ ob, int nb,
    const float* __restrict__ c, ushort_t* __restrict__ oc, int nc)
{
    int ntot = na + nb + nc;
    for (int i = blockIdx.x * 256 + threadIdx.x; i < ntot; i += gridDim.x * 256) {
        if (i < na)            oa[i] = f2bf(a[i]);
        else if (i < na + nb)  ob[i - na] = f2bf(b[i - na]);
        else                   oc[i - na - nb] = f2bf(c[i - na - nb]);
    }
}

// ---------------- patch embed + pos emb + cls row + LN1(layer0) ----------------
__global__ __launch_bounds__(256) void patch_embed_ln(
    const float* __restrict__ x, const float* __restrict__ pw,
    const float* __restrict__ pb, const float* __restrict__ row_emb,
    const float* __restrict__ col_emb, const float* __restrict__ cls_tok,
    const float* __restrict__ lw, const float* __restrict__ lb,
    float* __restrict__ out, ushort_t* __restrict__ lnout)
{
    __shared__ float red[8];
    int p = blockIdx.x;
    int c = threadIdx.x;
    int b = p / 272;
    int rem = p - b * 272;
    int y = rem >> 4;
    int xw = rem & 15;
    float v;
    if (y == 0) {
        v = cls_tok[c];
    } else {
        int gr = y - 1, gc = xw;
        const float* xb = x + (size_t)b * 3 * 1024;
        const float* wc = pw + (size_t)c * 12;
        float acc = pb[c];
        #pragma unroll
        for (int ci = 0; ci < 3; ci++)
            #pragma unroll
            for (int ph = 0; ph < 2; ph++)
                #pragma unroll
                for (int pq = 0; pq < 2; pq++)
                    acc += xb[ci * 1024 + (2 * gr + ph) * 32 + (2 * gc + pq)]
                         * wc[(ci * 2 + ph) * 2 + pq];
        acc += (c < 128) ? row_emb[gr * 128 + c] : col_emb[gc * 128 + (c - 128)];
        v = acc;
    }
    out[(size_t)p * C_DIM + c] = v;
    // LN epilogue
    float s = v;
    s += __shfl_down(s, 32); s += __shfl_down(s, 16); s += __shfl_down(s, 8);
    s += __shfl_down(s, 4);  s += __shfl_down(s, 2);  s += __shfl_down(s, 1);
    if ((c & 63) == 0) red[c >> 6] = s;
    __syncthreads();
    float mu = (red[0] + red[1] + red[2] + red[3]) * (1.0f / 256.0f);
    float d = v - mu;
    float s2 = d * d;
    s2 += __shfl_down(s2, 32); s2 += __shfl_down(s2, 16); s2 += __shfl_down(s2, 8);
    s2 += __shfl_down(s2, 4);  s2 += __shfl_down(s2, 2);  s2 += __shfl_down(s2, 1);
    if ((c & 63) == 0) red[4 + (c >> 6)] = s2;
    __syncthreads();
    float var = (red[4] + red[5] + red[6] + red[7]) * (1.0f / 256.0f);
    lnout[(size_t)p * C_DIM + c] = f2bf(d * rsqrtf(var + 1e-5f) * lw[c] + lb[c]);
}

// ---------------- standalone layernorm: fp32 in -> bf16 out (LN1, layers 1..6) ----------------
__global__ __launch_bounds__(256) void layernorm_k(
    const float* __restrict__ in, const float* __restrict__ w,
    const float* __restrict__ b, ushort_t* __restrict__ out)
{
    __shared__ float red[8];
    int r = blockIdx.x, c = threadIdx.x;
    float v = in[(size_t)r * C_DIM + c];
    float s = v;
    s += __shfl_down(s, 32); s += __shfl_down(s, 16); s += __shfl_down(s, 8);
    s += __shfl_down(s, 4);  s += __shfl_down(s, 2);  s += __shfl_down(s, 1);
    if ((c & 63) == 0) red[c >> 6] = s;
    __syncthreads();
    float mu = (red[0] + red[1] + red[2] + red[3]) * (1.0f / 256.0f);
    float d = v - mu;
    float s2 = d * d;
    s2 += __shfl_down(s2, 32); s2 += __shfl_down(s2, 16); s2 += __shfl_down(s2, 8);
    s2 += __shfl_down(s2, 4);  s2 += __shfl_down(s2, 2);  s2 += __shfl_down(s2, 1);
    if ((c & 63) == 0) red[4 + (c >> 6)] = s2;
    __syncthreads();
    float var = (red[4] + red[5] + red[6] + red[7]) * (1.0f / 256.0f);
    out[(size_t)r * C_DIM + c] = f2bf(d * rsqrtf(var + 1e-5f) * w[c] + b[c]);
}

// ---------------- bf16 MFMA GEMM: C[M,N] = A[M,K] @ B[N,K]^T ----------------
// MODE 0: qkv split epilogue (Q,K bf16 row-major; V -> vT[c][pixel])
// MODE 2: bias + gelu -> bf16 out
// MODE 3: bias + residual -> fp32 out
template <int MODE>
__global__ __launch_bounds__(256) void gemm_bf16(
    const ushort_t* __restrict__ A, const ushort_t* __restrict__ B,
    const float* __restrict__ bias, const float* __restrict__ res,
    void* __restrict__ outp, ushort_t* __restrict__ vT,
    int M, int N, int K)
{
    int m0 = blockIdx.x * 64, n0 = blockIdx.y * 64;
    int t = threadIdx.x, lane = t & 63, wv = t >> 6;
    int l15 = lane & 15, lg = lane >> 4;
    int ncol = n0 + wv * 16 + l15;
    f32x4 acc[4] = {};
    const ushort_t* Brow = B + (size_t)ncol * K;
    for (int ks = 0; ks < K; ks += 32) {
        bfx8 bf = *(const bfx8*)(Brow + ks + lg * 8);
        #pragma unroll
        for (int i = 0; i < 4; i++) {
            bfx8 af = *(const bfx8*)(A + (size_t)(m0 + 16 * i + l15) * K + ks + lg * 8);
            acc[i] = __builtin_amdgcn_mfma_f32_16x16x32_bf16(af, bf, acc[i], 0, 0, 0);
        }
    }
    if (MODE == 0) {
        if (n0 < 512) {
            #pragma unroll
            for (int i = 0; i < 4; i++) {
                int m = m0 + 16 * i + lg * 4;
                #pragma unroll
                for (int r = 0; r < 4; r++)
                    ((ushort_t*)outp)[(size_t)(m + r) * 512 + ncol] = f2bf(acc[i][r]);
            }
        } else {
            #pragma unroll
            for (int i = 0; i < 4; i++) {
                int m = m0 + 16 * i + lg * 4;
                ushort4 pk;
                pk.x = f2bf(acc[i][0]); pk.y = f2bf(acc[i][1]);
                pk.z = f2bf(acc[i][2]); pk.w = f2bf(acc[i][3]);
                *(ushort4*)&vT[(size_t)(ncol - 512) * NPIX + m] = pk;
            }
        }
    } else if (MODE == 2) {
        float bz = bias[ncol];
        #pragma unroll
        for (int i = 0; i < 4; i++) {
            int m = m0 + 16 * i + lg * 4;
            #pragma unroll
            for (int r = 0; r < 4; r++) {
                float v = gelu_f(acc[i][r] + bz);
                ((ushort_t*)outp)[(size_t)(m + r) * N + ncol] = f2bf(v);
            }
        }
    } else {
        float bz = bias[ncol];
        #pragma unroll
        for (int i = 0; i < 4; i++) {
            int m = m0 + 16 * i + lg * 4;
            #pragma unroll
            for (int r = 0; r < 4; r++) {
                float v = acc[i][r] + bz + res[(size_t)(m + r) * N + ncol];
                ((float*)outp)[(size_t)(m + r) * N + ncol] = v;
            }
        }
    }
}

// unaligned (element-granular) loaders from a dword-aligned row
__device__ __forceinline__ uint2 ld_u4_align(const uint_t* drow, int e0) {
    int d0 = e0 >> 1;
    if (!(e0 & 1)) return make_uint2(drow[d0], drow[d0 + 1]);
    uint_t a = drow[d0], b = drow[d0 + 1], c = drow[d0 + 2];
    return make_uint2((a >> 16) | (b << 16), (b >> 16) | (c << 16));
}
__device__ __forceinline__ uint4 ld_u8_align(const uint_t* drow, int e0) {
    int d0 = e0 >> 1;
    if (!(e0 & 1)) return make_uint4(drow[d0], drow[d0 + 1], drow[d0 + 2], drow[d0 + 3]);
    uint_t a = drow[d0], b = drow[d0 + 1], c = drow[d0 + 2], d = drow[d0 + 3], e = drow[d0 + 4];
    return make_uint4((a >> 16) | (b << 16), (b >> 16) | (c << 16),
                      (c >> 16) | (d << 16), (d >> 16) | (e << 16));
}

// ---------------- MFMA sliding-window attention ----------------
// qk: [pixel][512] bf16 (Q|K). vT: [256][pixel] bf16. obuf: bf16 window outputs.
// No __syncthreads anywhere: each wave owns a 16-query strip independently.
// Per-wave LDS region (union): P tile (stride PVSTR) aliased with O tile (stride 264).
template <int KK>
__global__ __launch_bounds__(256) void attn_mfma(
    const ushort_t* __restrict__ qk, const ushort_t* __restrict__ vT,
    ushort_t* __restrict__ obuf, int w0, int nW, float scale)
{
    constexpr int T = KK * KK;
    constexpr int KC = (KK == 4) ? 16 : 64;   // key-chunk tokens
    constexpr int NCH = T / KC;               // chunks (flash loop)
    constexpr int NF = KC / 16;               // S frags per chunk
    constexpr int PVK = (KC < 32) ? 32 : KC;  // zero-padded k for PV MFMA
    constexpr int PVSTR = PVK + 8;
    constexpr int Lh = 18 - KK, Lw = 17 - KK;
    constexpr int L = Lh * Lw;

    __shared__ ushort_t SH[4][16 * 264];      // per-wave union: P[16][PVSTR] / O[16][264]

    int t = threadIdx.x, lane = t & 63, wv = t >> 6;
    int l15 = lane & 15, lg = lane >> 4;

    int wrel, qbase;
    if (KK == 4)       { wrel = blockIdx.x * 4 + wv; qbase = 0; if (wrel >= nW) return; }
    else if (KK == 8)  { wrel = blockIdx.x; qbase = wv * 16; }
    else               { wrel = blockIdx.x >> 2; qbase = (blockIdx.x & 3) * 64 + wv * 16; }

    int widx = w0 + wrel;
    int b = widx / L, lrem = widx % L;
    int lh = lrem / Lw, lw = lrem % Lw;
    int pbase = b * 272 + lh * 16 + lw;     // pixel index of window token 0

    // hoisted Q fragments (16 rows x 256 ch)
    int qtok = qbase + l15;
    int qpix = pbase + (qtok / KK) * 16 + (qtok % KK);
    bfx8 qf[8];
    #pragma unroll
    for (int cs = 0; cs < 8; cs++)
        qf[cs] = *(const bfx8*)(qk + (size_t)qpix * 512 + cs * 32 + lg * 8);

    f32x4 o[16];
    #pragma unroll
    for (int j = 0; j < 16; j++) o[j] = f32x4{0.f, 0.f, 0.f, 0.f};
    float mold[4] = {-1e30f, -1e30f, -1e30f, -1e30f};
    float lsum[4] = {0.f, 0.f, 0.f, 0.f};

    for (int ch = 0; ch < NCH; ch++) {
        int c0 = ch * KC;
        // ---- S = Q.K^T for this key chunk ----
        f32x4 s[NF];
        #pragma unroll
        for (int j = 0; j < NF; j++) s[j] = f32x4{0.f, 0.f, 0.f, 0.f};
        #pragma unroll
        for (int cs = 0; cs < 8; cs++) {
            #pragma unroll
            for (int j = 0; j < NF; j++) {
                int ktok = c0 + j * 16 + l15;
                int kpix = pbase + (ktok / KK) * 16 + (ktok % KK);
                bfx8 kf = *(const bfx8*)(qk + (size_t)kpix * 512 + 256 + cs * 32 + lg * 8);
                s[j] = __builtin_amdgcn_mfma_f32_16x16x32_bf16(qf[cs], kf, s[j], 0, 0, 0);
            }
        }
        // ---- online softmax (rows r across 16-lane groups) ----
        float alpha[4];
        float p[NF][4];
        #pragma unroll
        for (int r = 0; r < 4; r++) {
            float mx = s[0][r];
            #pragma unroll
            for (int j = 1; j < NF; j++) mx = fmaxf(mx, s[j][r]);
            mx = fmaxf(mx, __shfl_xor(mx, 1));
            mx = fmaxf(mx, __shfl_xor(mx, 2));
            mx = fmaxf(mx, __shfl_xor(mx, 4));
            mx = fmaxf(mx, __shfl_xor(mx, 8));
            float mnew = fmaxf(mold[r], mx);
            alpha[r] = __expf(scale * (mold[r] - mnew));
            float ps = 0.f;
            #pragma unroll
            for (int j = 0; j < NF; j++) {
                p[j][r] = __expf(scale * (s[j][r] - mnew));
                ps += p[j][r];
            }
            ps += __shfl_xor(ps, 1);
            ps += __shfl_xor(ps, 2);
            ps += __shfl_xor(ps, 4);
            ps += __shfl_xor(ps, 8);
            lsum[r] = lsum[r] * alpha[r] + ps;
            mold[r] = mnew;
        }
        if (NCH > 1) {
            #pragma unroll
            for (int j = 0; j < 16; j++) {
                o[j][0] *= alpha[0]; o[j][1] *= alpha[1];
                o[j][2] *= alpha[2]; o[j][3] *= alpha[3];
            }
        }
        // ---- P -> bf16 -> per-wave LDS tile ----
        #pragma unroll
        for (int j = 0; j < NF; j++)
            #pragma unroll
            for (int r = 0; r < 4; r++)
                SH[wv][(lg * 4 + r) * PVSTR + j * 16 + l15] = f2bf(p[j][r]);
        if (KK == 4) {
            #pragma unroll
            for (int r = 0; r < 4; r++)
                SH[wv][(lg * 4 + r) * PVSTR + 16 + l15] = 0;
        }
        asm volatile("s_waitcnt lgkmcnt(0)" ::: "memory");
        __builtin_amdgcn_sched_barrier(0);
        // ---- O += P.V ----
        #pragma unroll
        for (int kt = 0; kt < PVK / 32; kt++) {
            bfx8 pf = *(const bfx8*)&SH[wv][l15 * PVSTR + kt * 32 + lg * 8];
            int tk0 = kt * 32 + lg * 8;   // chunk-local token base of this lane's 8 elems
            #pragma unroll
            for (int j = 0; j < 16; j++) {
                int c = j * 16 + l15;
                const uint_t* drow = (const uint_t*)(vT + (size_t)c * NPIX);
                bfx8 vf;
                if (KK == 4) {
                    int tkm = tk0 & 15;                     // wrap padded tokens (P=0)
                    int pa = pbase + (tkm >> 2) * 16;       // run of 4, then next row
                    uint2 u1 = ld_u4_align(drow, pa);
                    uint2 u2 = ld_u4_align(drow, pa + 16);
                    uint4 u = make_uint4(u1.x, u1.y, u2.x, u2.y);
                    vf = __builtin_bit_cast(bfx8, u);
                } else if (KK == 8) {
                    int tok = c0 + tk0;
                    int pix = pbase + (tok >> 3) * 16;      // tok%8==0, 8-px run
                    uint4 u = ld_u8_align(drow, pix);
                    vf = __builtin_bit_cast(bfx8, u);
                } else {
                    int tok = c0 + tk0;
                    int pix = pbase + (tok >> 4) * 16 + (tok & 15);  // 16B aligned
                    vf = *(const bfx8*)(vT + (size_t)c * NPIX + pix);
                }
                o[j] = __builtin_amdgcn_mfma_f32_16x16x32_bf16(pf, vf, o[j], 0, 0, 0);
            }
        }
        // ensure this chunk's P reads retired before next chunk overwrites P
        asm volatile("s_waitcnt lgkmcnt(0)" ::: "memory");
        __builtin_amdgcn_sched_barrier(0);
    }
    // ---- normalize -> O LDS tile (aliases P region; reads drained above) ----
    float inv[4];
    #pragma unroll
    for (int r = 0; r < 4; r++) inv[r] = 1.0f / lsum[r];
    #pragma unroll
    for (int j = 0; j < 16; j++) {
        #pragma unroll
        for (int r = 0; r < 4; r++)
            SH[wv][(lg * 4 + r) * 264 + j * 16 + l15] = f2bf(o[j][r] * inv[r]);
    }
    // ---- coalesced read-back + 1KB global stores ----
    size_t gbase = ((size_t)wrel * T + qbase) * C_DIM;
    #pragma unroll
    for (int i = 0; i < 8; i++) {
        int off = i * 512 + lane * 8;
        int row = off >> 8, chb = off & 255;
        uint4 v = *(const uint4*)&SH[wv][row * 264 + chb];
        *(uint4*)&obuf[gbase + off] = v;
    }
}

// ---------------- overlap-add fold + residual (+ optional fused LN2) ----------------
__global__ __launch_bounds__(256) void fold_ln(
    const ushort_t* __restrict__ obuf, const float* __restrict__ xin,
    float* __restrict__ y, const float* __restrict__ lw,
    const float* __restrict__ lb, ushort_t* __restrict__ lnout, int do_ln,
    int k, int Lh, int Lw, int w0, int w1)
{
    __shared__ float red[8];
    int p = blockIdx.x;
    int c = threadIdx.x;
    int b = p / 272;
    int rem = p - b * 272;
    int yy = rem >> 4, xx = rem & 15;
    int L = Lh * Lw;
    int T = k * k;
    float acc = xin ? xin[(size_t)p * C_DIM + c] : y[(size_t)p * C_DIM + c];
    int lh0 = max(0, yy - k + 1), lh1 = min(Lh - 1, yy);
    int lw0 = max(0, xx - k + 1), lw1 = min(Lw - 1, xx);
    for (int lh = lh0; lh <= lh1; lh++) {
        for (int lw = lw0; lw <= lw1; lw++) {
            int widx = b * L + lh * Lw + lw;
            if (widx < w0 || widx >= w1) continue;
            int n = (yy - lh) * k + (xx - lw);
            acc += bf2f(obuf[((size_t)(widx - w0) * T + n) * C_DIM + c]);
        }
    }
    y[(size_t)p * C_DIM + c] = acc;
    if (!do_ln) return;
    float s = acc;
    s += __shfl_down(s, 32); s += __shfl_down(s, 16); s += __shfl_down(s, 8);
    s += __shfl_down(s, 4);  s += __shfl_down(s, 2);  s += __shfl_down(s, 1);
    if ((c & 63) == 0) red[c >> 6] = s;
    __syncthreads();
    float mu = (red[0] + red[1] + red[2] + red[3]) * (1.0f / 256.0f);
    float d = acc - mu;
    float s2 = d * d;
    s2 += __shfl_down(s2, 32); s2 += __shfl_down(s2, 16); s2 += __shfl_down(s2, 8);
    s2 += __shfl_down(s2, 4);  s2 += __shfl_down(s2, 2);  s2 += __shfl_down(s2, 1);
    if ((c & 63) == 0) red[4 + (c >> 6)] = s2;
    __syncthreads();
    float var = (red[4] + red[5] + red[6] + red[7]) * (1.0f / 256.0f);
    lnout[(size_t)p * C_DIM + c] = f2bf(d * rsqrtf(var + 1e-5f) * lw[c] + lb[c]);
}

// ---------------- classifier ----------------
__global__ __launch_bounds__(256) void classifier_k(
    const float* __restrict__ h, const float* __restrict__ cw,
    const float* __restrict__ cb, float* __restrict__ out)
{
    __shared__ float hrow[256];
    int b = blockIdx.x;
    int n = blockIdx.y * 256 + threadIdx.x;
    hrow[threadIdx.x] = h[(size_t)b * 272 * C_DIM + threadIdx.x];
    __syncthreads();
    if (n < 1000) {
        float acc = cb[n];
        const float* wr = cw + (size_t)n * C_DIM;
        for (int c = 0; c < 256; c++) acc += hrow[c] * wr[c];
        out[(size_t)b * 1000 + n] = acc;
    }
}

extern "C" void kernel_launch(void* const* d_in, const int* in_sizes, int n_in,
                              void* d_out, int out_size, void* d_ws, size_t ws_size,
                              hipStream_t stream)
{
    const float* x       = (const float*)d_in[0];
    const float* patch_w = (const float*)d_in[1];
    const float* patch_b = (const float*)d_in[2];
    const float* row_emb = (const float*)d_in[3];
    const float* col_emb = (const float*)d_in[4];
    const float* cls_tok = (const float*)d_in[5];
    const float* ln1_w   = (const float*)d_in[6];
    const float* ln1_b   = (const float*)d_in[7];
    const float* qkv_w   = (const float*)d_in[8];
    const float* ln2_w   = (const float*)d_in[9];
    const float* ln2_b   = (const float*)d_in[10];
    const float* mlp_w1  = (const float*)d_in[11];
    const float* mlp_b1  = (const float*)d_in[12];
    const float* mlp_w2  = (const float*)d_in[13];
    const float* mlp_b2  = (const float*)d_in[14];
    const float* cls_w   = (const float*)d_in[15];
    const float* cls_b   = (const float*)d_in[16];
    float* out = (float*)d_out;

    // workspace layout (all 16B aligned)
    float* xb0  = (float*)d_ws;                          // NPIX*256 f32
    float* xb1  = xb0 + (size_t)NPIX * 256;              // NPIX*256 f32
    ushort_t* lnb = (ushort_t*)(xb1 + (size_t)NPIX * 256);   // NPIX*256 bf16
    ushort_t* qkb = lnb + (size_t)NPIX * 256;            // NPIX*512 bf16 (Q|K)
    ushort_t* vT  = qkb + (size_t)NPIX * 512;            // 256*NPIX bf16
    ushort_t* h1  = vT + (size_t)256 * NPIX;             // NPIX*512 bf16
    ushort_t* wq  = h1 + (size_t)NPIX * 512;             // 7*768*256 bf16
    ushort_t* w1b = wq + (size_t)7 * 768 * 256;          // 7*512*256 bf16
    ushort_t* w2b = w1b + (size_t)7 * 512 * 256;         // 7*256*512 bf16
    ushort_t* obuf = w2b + (size_t)7 * 256 * 512;        // rest of ws
    size_t obuf_off_bytes = (size_t)((char*)obuf - (char*)d_ws);
    size_t obuf_cap_e = (ws_size > obuf_off_bytes + 64)
                        ? (ws_size - obuf_off_bytes - 64) / 2 : 0;

    conv3_bf16<<<1024, 256, 0, stream>>>(qkv_w, wq, 7 * 768 * 256,
                                         mlp_w1, w1b, 7 * 512 * 256,
                                         mlp_w2, w2b, 7 * 256 * 512);

    patch_embed_ln<<<NPIX, 256, 0, stream>>>(x, patch_w, patch_b, row_emb,
                                             col_emb, cls_tok, ln1_w, ln1_b,
                                             xb0, lnb);

    const int KS[7] = {4, 4, 8, 8, 8, 16, 16};
    float* xcur = xb0;
    float* ybuf = xb1;

    for (int i = 0; i < 7; i++) {
        int k = KS[i];
        int Lh = 18 - k, Lw = 17 - k, L = Lh * Lw, T = k * k;
        float scale = 1.0f / std::sqrt((float)(256 / k));

        if (i > 0)
            layernorm_k<<<NPIX, 256, 0, stream>>>(xcur, ln1_w + i * 256,
                                                  ln1_b + i * 256, lnb);
        gemm_bf16<0><<<dim3(68, 12), 256, 0, stream>>>(
            lnb, wq + (size_t)i * 768 * 256, nullptr, nullptr, qkb, vT,
            NPIX, 768, 256);

        int totalW = 16 * L;
        size_t perW = (size_t)T * C_DIM;
        int maxW = (int)((obuf_cap_e / perW) < (size_t)totalW
                         ? (obuf_cap_e / perW) : (size_t)totalW);
        if (maxW < 1) maxW = 1;
        for (int w0 = 0; w0 < totalW; w0 += maxW) {
            int nW = totalW - w0 < maxW ? totalW - w0 : maxW;
            if (k == 4)
                attn_mfma<4><<<(nW + 3) / 4, 256, 0, stream>>>(qkb, vT, obuf, w0, nW, scale);
            else if (k == 8)
                attn_mfma<8><<<nW, 256, 0, stream>>>(qkb, vT, obuf, w0, nW, scale);
            else
                attn_mfma<16><<<nW * 4, 256, 0, stream>>>(qkb, vT, obuf, w0, nW, scale);
            int last = (w0 + nW >= totalW);
            fold_ln<<<NPIX, 256, 0, stream>>>(obuf, (w0 == 0) ? xcur : nullptr,
                                              ybuf, ln2_w + i * 256, ln2_b + i * 256,
                                              lnb, last, k, Lh, Lw, w0, w0 + nW);
        }

        gemm_bf16<2><<<dim3(68, 8), 256, 0, stream>>>(
            lnb, w1b + (size_t)i * 512 * 256, mlp_b1 + i * 512, nullptr, h1, nullptr,
            NPIX, 512, 256);
        gemm_bf16<3><<<dim3(68, 4), 256, 0, stream>>>(
            h1, w2b + (size_t)i * 256 * 512, mlp_b2 + i * 256, ybuf, xcur, nullptr,
            NPIX, 256, 512);
    }

    classifier_k<<<dim3(16, 4), 256, 0, stream>>>(xcur, cls_w, cls_b, out);
}

// Round 5
// 907.126 us; speedup vs baseline: 2.4788x; 1.1016x over previous
//
#include <hip/hip_runtime.h>
#include <cmath>

#define NPIX 4352      // 16 * 17 * 16 pixels (incl. cls row)
#define C_DIM 256

typedef unsigned short ushort_t;
typedef unsigned int uint_t;
typedef float f32x4 __attribute__((ext_vector_type(4)));
typedef __bf16 bfx8 __attribute__((ext_vector_type(8)));

__device__ __forceinline__ ushort_t f2bf(float f) {
    uint_t u = __float_as_uint(f);
    u = (u + 0x7FFFu + ((u >> 16) & 1u)) >> 16;
    return (ushort_t)u;
}
__device__ __forceinline__ float bf2f(ushort_t b) {
    return __uint_as_float(((uint_t)b) << 16);
}
__device__ __forceinline__ float gelu_f(float v) {
    return 0.5f * v * (1.0f + erff(v * 0.70710678118654752f));
}

// ---------------- fp32 -> bf16 converter (all 3 weight tensors, 1 launch) ----------------
__global__ __launch_bounds__(256) void conv3_bf16(
    const float* __restrict__ a, ushort_t* __restrict__ oa, int na,
    const float* __restrict__ b, ushort_t* __restrict__ ob, int nb,
    const float* __restrict__ c, ushort_t* __restrict__ oc, int nc)
{
    int ntot = na + nb + nc;
    for (int i = blockIdx.x * 256 + threadIdx.x; i < ntot; i += gridDim.x * 256) {
        if (i < na)            oa[i] = f2bf(a[i]);
        else if (i < na + nb)  ob[i - na] = f2bf(b[i - na]);
        else                   oc[i - na - nb] = f2bf(c[i - na - nb]);
    }
}

// ---------------- patch embed + pos emb + cls row + LN1(layer0) ----------------
__global__ __launch_bounds__(256) void patch_embed_ln(
    const float* __restrict__ x, const float* __restrict__ pw,
    const float* __restrict__ pb, const float* __restrict__ row_emb,
    const float* __restrict__ col_emb, const float* __restrict__ cls_tok,
    const float* __restrict__ lw, const float* __restrict__ lb,
    float* __restrict__ out, ushort_t* __restrict__ lnout)
{
    __shared__ float red[8];
    int p = blockIdx.x;
    int c = threadIdx.x;
    int b = p / 272;
    int rem = p - b * 272;
    int y = rem >> 4;
    int xw = rem & 15;
    float v;
    if (y == 0) {
        v = cls_tok[c];
    } else {
        int gr = y - 1, gc = xw;
        const float* xb = x + (size_t)b * 3 * 1024;
        const float* wc = pw + (size_t)c * 12;
        float acc = pb[c];
        #pragma unroll
        for (int ci = 0; ci < 3; ci++)
            #pragma unroll
            for (int ph = 0; ph < 2; ph++)
                #pragma unroll
                for (int pq = 0; pq < 2; pq++)
                    acc += xb[ci * 1024 + (2 * gr + ph) * 32 + (2 * gc + pq)]
                         * wc[(ci * 2 + ph) * 2 + pq];
        acc += (c < 128) ? row_emb[gr * 128 + c] : col_emb[gc * 128 + (c - 128)];
        v = acc;
    }
    out[(size_t)p * C_DIM + c] = v;
    float s = v;
    s += __shfl_down(s, 32); s += __shfl_down(s, 16); s += __shfl_down(s, 8);
    s += __shfl_down(s, 4);  s += __shfl_down(s, 2);  s += __shfl_down(s, 1);
    if ((c & 63) == 0) red[c >> 6] = s;
    __syncthreads();
    float mu = (red[0] + red[1] + red[2] + red[3]) * (1.0f / 256.0f);
    float d = v - mu;
    float s2 = d * d;
    s2 += __shfl_down(s2, 32); s2 += __shfl_down(s2, 16); s2 += __shfl_down(s2, 8);
    s2 += __shfl_down(s2, 4);  s2 += __shfl_down(s2, 2);  s2 += __shfl_down(s2, 1);
    if ((c & 63) == 0) red[4 + (c >> 6)] = s2;
    __syncthreads();
    float var = (red[4] + red[5] + red[6] + red[7]) * (1.0f / 256.0f);
    lnout[(size_t)p * C_DIM + c] = f2bf(d * rsqrtf(var + 1e-5f) * lw[c] + lb[c]);
}

// ---------------- standalone layernorm: fp32 in -> bf16 out ----------------
__global__ __launch_bounds__(256) void layernorm_k(
    const float* __restrict__ in, const float* __restrict__ w,
    const float* __restrict__ b, ushort_t* __restrict__ out)
{
    __shared__ float red[8];
    int r = blockIdx.x, c = threadIdx.x;
    float v = in[(size_t)r * C_DIM + c];
    float s = v;
    s += __shfl_down(s, 32); s += __shfl_down(s, 16); s += __shfl_down(s, 8);
    s += __shfl_down(s, 4);  s += __shfl_down(s, 2);  s += __shfl_down(s, 1);
    if ((c & 63) == 0) red[c >> 6] = s;
    __syncthreads();
    float mu = (red[0] + red[1] + red[2] + red[3]) * (1.0f / 256.0f);
    float d = v - mu;
    float s2 = d * d;
    s2 += __shfl_down(s2, 32); s2 += __shfl_down(s2, 16); s2 += __shfl_down(s2, 8);
    s2 += __shfl_down(s2, 4);  s2 += __shfl_down(s2, 2);  s2 += __shfl_down(s2, 1);
    if ((c & 63) == 0) red[4 + (c >> 6)] = s2;
    __syncthreads();
    float var = (red[4] + red[5] + red[6] + red[7]) * (1.0f / 256.0f);
    out[(size_t)r * C_DIM + c] = f2bf(d * rsqrtf(var + 1e-5f) * w[c] + b[c]);
}

// ---------------- bf16 MFMA GEMM: C[M,N] = A[M,K] @ B[N,K]^T ----------------
template <int MODE>
__global__ __launch_bounds__(256) void gemm_bf16(
    const ushort_t* __restrict__ A, const ushort_t* __restrict__ B,
    const float* __restrict__ bias, const float* __restrict__ res,
    void* __restrict__ outp, ushort_t* __restrict__ vT,
    int M, int N, int K)
{
    int m0 = blockIdx.x * 64, n0 = blockIdx.y * 64;
    int t = threadIdx.x, lane = t & 63, wv = t >> 6;
    int l15 = lane & 15, lg = lane >> 4;
    int ncol = n0 + wv * 16 + l15;
    f32x4 acc[4] = {};
    const ushort_t* Brow = B + (size_t)ncol * K;
    for (int ks = 0; ks < K; ks += 32) {
        bfx8 bf = *(const bfx8*)(Brow + ks + lg * 8);
        #pragma unroll
        for (int i = 0; i < 4; i++) {
            bfx8 af = *(const bfx8*)(A + (size_t)(m0 + 16 * i + l15) * K + ks + lg * 8);
            acc[i] = __builtin_amdgcn_mfma_f32_16x16x32_bf16(af, bf, acc[i], 0, 0, 0);
        }
    }
    if (MODE == 0) {
        if (n0 < 512) {
            #pragma unroll
            for (int i = 0; i < 4; i++) {
                int m = m0 + 16 * i + lg * 4;
                #pragma unroll
                for (int r = 0; r < 4; r++)
                    ((ushort_t*)outp)[(size_t)(m + r) * 512 + ncol] = f2bf(acc[i][r]);
            }
        } else {
            #pragma unroll
            for (int i = 0; i < 4; i++) {
                int m = m0 + 16 * i + lg * 4;
                ushort4 pk;
                pk.x = f2bf(acc[i][0]); pk.y = f2bf(acc[i][1]);
                pk.z = f2bf(acc[i][2]); pk.w = f2bf(acc[i][3]);
                *(ushort4*)&vT[(size_t)(ncol - 512) * NPIX + m] = pk;
            }
        }
    } else if (MODE == 2) {
        float bz = bias[ncol];
        #pragma unroll
        for (int i = 0; i < 4; i++) {
            int m = m0 + 16 * i + lg * 4;
            #pragma unroll
            for (int r = 0; r < 4; r++) {
                float v = gelu_f(acc[i][r] + bz);
                ((ushort_t*)outp)[(size_t)(m + r) * N + ncol] = f2bf(v);
            }
        }
    } else {
        float bz = bias[ncol];
        #pragma unroll
        for (int i = 0; i < 4; i++) {
            int m = m0 + 16 * i + lg * 4;
            #pragma unroll
            for (int r = 0; r < 4; r++) {
                float v = acc[i][r] + bz + res[(size_t)(m + r) * N + ncol];
                ((float*)outp)[(size_t)(m + r) * N + ncol] = v;
            }
        }
    }
}

// unaligned (element-granular) loaders from a dword-aligned row
__device__ __forceinline__ uint2 ld_u4_align(const uint_t* drow, int e0) {
    int d0 = e0 >> 1;
    if (!(e0 & 1)) return make_uint2(drow[d0], drow[d0 + 1]);
    uint_t a = drow[d0], b = drow[d0 + 1], c = drow[d0 + 2];
    return make_uint2((a >> 16) | (b << 16), (b >> 16) | (c << 16));
}
__device__ __forceinline__ uint4 ld_u8_align(const uint_t* drow, int e0) {
    int d0 = e0 >> 1;
    if (!(e0 & 1)) return make_uint4(drow[d0], drow[d0 + 1], drow[d0 + 2], drow[d0 + 3]);
    uint_t a = drow[d0], b = drow[d0 + 1], c = drow[d0 + 2], d = drow[d0 + 3], e = drow[d0 + 4];
    return make_uint4((a >> 16) | (b << 16), (b >> 16) | (c << 16),
                      (c >> 16) | (d << 16), (d >> 16) | (e << 16));
}

// ---------------- LDS-staged MFMA sliding-window attention ----------------
// K tile [tok][256ch] swizzled chunk^=(row&7); V^T tile [ch][64tok] swizzled
// chunk^=(c&7). Channel-split: each wave computes 128 output channels.
// k=4: block = 2 windows x 2 chalf-waves; k=8: block = (window, chalf), waves
// = 4 query strips; k=16: block = (window, qstrip, chalf), flash over 4 chunks.
template <int KK>
__global__ __launch_bounds__(256) void attn_v2(
    const ushort_t* __restrict__ qk, const ushort_t* __restrict__ vT,
    ushort_t* __restrict__ obuf, int w0, int nW, float scale)
{
    constexpr int T = KK * KK;
    constexpr int Lh = 18 - KK, Lw = 17 - KK, L = Lh * Lw;
    constexpr int NCH  = (KK == 16) ? 4 : 1;   // flash chunks
    constexpr int NF   = (KK == 4) ? 1 : 4;    // S frags per chunk
    constexpr int NJ   = 8;                    // PV channel frags (half ch)
    constexpr int PSTR = (KK == 4) ? 40 : 72;
    constexpr int KROWS = (KK == 4) ? 32 : 64;
    constexpr int VROWS = (KK == 4) ? 256 : 128;
    constexpr int PVKT = (KK == 4) ? 1 : 2;
    constexpr int EOFF = (KK == 4) ? 2048 : 4096;
    constexpr int ESTR = (KK == 4) ? 128 : 134;

    __shared__ ushort_t Klds[KROWS * 256];
    __shared__ ushort_t Vlds[VROWS * 64];
    __shared__ ushort_t Plds[4][16 * PSTR];

    int t = threadIdx.x, lane = t & 63, wv = t >> 6;
    int l15 = lane & 15, lg = lane >> 4;

    int wrel, qbase, chalf, wloc;
    if (KK == 4)      { wrel = blockIdx.x * 2 + (wv & 1); wloc = wv & 1; chalf = wv >> 1; qbase = 0; }
    else if (KK == 8) { wrel = blockIdx.x >> 1; wloc = 0; chalf = blockIdx.x & 1; qbase = wv * 16; }
    else              { wrel = blockIdx.x >> 3; wloc = 0; chalf = blockIdx.x & 1;
                        qbase = ((blockIdx.x >> 1) & 3) * 64 + wv * 16; }
    if (wrel >= nW) wrel = nW - 1;

    int pbs[2];
    #pragma unroll
    for (int w = 0; w < 2; w++) {
        int wi = (KK == 4) ? blockIdx.x * 2 + w : wrel;
        if (wi >= nW) wi = nW - 1;
        wi += w0;
        int b = wi / L, lrem = wi % L;
        pbs[w] = b * 272 + (lrem / Lw) * 16 + (lrem % Lw);
    }

    // hoisted Q fragments (16 queries x 256 ch)
    int qtok = qbase + l15;
    int qpix;
    if (KK == 4)      qpix = pbs[wloc] + ((qtok >> 2) << 4) + (qtok & 3);
    else if (KK == 8) qpix = pbs[0] + ((qtok >> 3) << 4) + (qtok & 7);
    else              qpix = pbs[0] + qtok;
    bfx8 qf[8];
    #pragma unroll
    for (int cs = 0; cs < 8; cs++)
        qf[cs] = *(const bfx8*)(qk + (size_t)qpix * 512 + cs * 32 + lg * 8);

    f32x4 o[NJ] = {};
    float mold[4] = {-1e30f, -1e30f, -1e30f, -1e30f};
    float lsum[4] = {0.f, 0.f, 0.f, 0.f};

    for (int ch = 0; ch < NCH; ch++) {
        int c0 = ch * 64;
        if (ch > 0) __syncthreads();
        // ---- stage K tile (coalesced, swizzled) ----
        for (int g = t; g < KROWS * 32; g += 256) {
            int row = g >> 5, cg = g & 31;
            int pix;
            if (KK == 4)      pix = pbs[row >> 4] + (((row & 15) >> 2) << 4) + (row & 3);
            else if (KK == 8) pix = pbs[0] + ((row >> 3) << 4) + (row & 7);
            else              pix = pbs[0] + c0 + row;
            uint4 v = *(const uint4*)(qk + (size_t)pix * 512 + 256 + cg * 8);
            *(uint4*)(Klds + row * 256 + ((cg ^ (row & 7)) << 3)) = v;
        }
        // ---- stage V^T tile ----
        for (int g = t; g < VROWS * 8; g += 256) {
            int cr = g >> 3, c16 = g & 7;
            int cglob = (KK == 4) ? cr : chalf * 128 + cr;
            const uint_t* drow = (const uint_t*)(vT + (size_t)cglob * NPIX);
            uint4 v;
            if (KK == 4) {
                int w = c16 >> 2, sub = c16 & 3;
                if (sub < 2) {
                    int pix0 = pbs[w] + (sub << 5);
                    uint2 a  = ld_u4_align(drow, pix0);
                    uint2 b2 = ld_u4_align(drow, pix0 + 16);
                    v = make_uint4(a.x, a.y, b2.x, b2.y);
                } else v = make_uint4(0, 0, 0, 0);
            } else if (KK == 8) {
                v = ld_u8_align(drow, pbs[0] + (c16 << 4));
            } else {
                v = *(const uint4*)(vT + (size_t)cglob * NPIX + pbs[0] + c0 + (c16 << 3));
            }
            *(uint4*)(Vlds + cr * 64 + ((c16 ^ (cr & 7)) << 3)) = v;
        }
        __syncthreads();
        // ---- S = Q.K^T ----
        f32x4 s[NF];
        #pragma unroll
        for (int j = 0; j < NF; j++) s[j] = f32x4{0.f, 0.f, 0.f, 0.f};
        #pragma unroll
        for (int cs = 0; cs < 8; cs++) {
            #pragma unroll
            for (int j = 0; j < NF; j++) {
                int krow = (KK == 4) ? (wloc << 4) + l15 : (j << 4) + l15;
                bfx8 kf = *(const bfx8*)(Klds + krow * 256 + ((((cs << 2) + lg) ^ (krow & 7)) << 3));
                s[j] = __builtin_amdgcn_mfma_f32_16x16x32_bf16(qf[cs], kf, s[j], 0, 0, 0);
            }
        }
        // ---- online softmax ----
        float alpha[4];
        float p[NF][4];
        #pragma unroll
        for (int r = 0; r < 4; r++) {
            float mx = s[0][r];
            #pragma unroll
            for (int j = 1; j < NF; j++) mx = fmaxf(mx, s[j][r]);
            mx = fmaxf(mx, __shfl_xor(mx, 1));
            mx = fmaxf(mx, __shfl_xor(mx, 2));
            mx = fmaxf(mx, __shfl_xor(mx, 4));
            mx = fmaxf(mx, __shfl_xor(mx, 8));
            float mnew = fmaxf(mold[r], mx);
            alpha[r] = __expf(scale * (mold[r] - mnew));
            float ps = 0.f;
            #pragma unroll
            for (int j = 0; j < NF; j++) {
                p[j][r] = __expf(scale * (s[j][r] - mnew));
                ps += p[j][r];
            }
            ps += __shfl_xor(ps, 1);
            ps += __shfl_xor(ps, 2);
            ps += __shfl_xor(ps, 4);
            ps += __shfl_xor(ps, 8);
            lsum[r] = lsum[r] * alpha[r] + ps;
            mold[r] = mnew;
        }
        if (NCH > 1) {
            #pragma unroll
            for (int j = 0; j < NJ; j++) {
                o[j][0] *= alpha[0]; o[j][1] *= alpha[1];
                o[j][2] *= alpha[2]; o[j][3] *= alpha[3];
            }
        }
        // ---- P -> bf16 -> per-wave LDS ----
        ushort_t* Pw = Plds[wv];
        #pragma unroll
        for (int j = 0; j < NF; j++)
            #pragma unroll
            for (int r = 0; r < 4; r++)
                Pw[(lg * 4 + r) * PSTR + (j << 4) + l15] = f2bf(p[j][r]);
        if (KK == 4) {
            #pragma unroll
            for (int r = 0; r < 4; r++)
                Pw[(lg * 4 + r) * PSTR + 16 + l15] = 0;
        }
        asm volatile("s_waitcnt lgkmcnt(0)" ::: "memory");
        __builtin_amdgcn_sched_barrier(0);
        // ---- O += P.V ----
        #pragma unroll
        for (int kt = 0; kt < PVKT; kt++) {
            bfx8 pf = *(const bfx8*)(Pw + l15 * PSTR + (kt << 5) + (lg << 3));
            #pragma unroll
            for (int j = 0; j < NJ; j++) {
                int cr = (KK == 4) ? chalf * 128 + (j << 4) + l15 : (j << 4) + l15;
                int c16 = ((KK == 4) ? (wloc << 2) + lg : (kt << 2) + lg) ^ (cr & 7);
                bfx8 vf = *(const bfx8*)(Vlds + cr * 64 + (c16 << 3));
                o[j] = __builtin_amdgcn_mfma_f32_16x16x32_bf16(pf, vf, o[j], 0, 0, 0);
            }
        }
    }
    asm volatile("s_waitcnt lgkmcnt(0)" ::: "memory");
    __syncthreads();   // all waves done with K/V LDS -> reuse as epilogue bounce
    // ---- normalize -> LDS -> coalesced global stores ----
    float inv[4];
    #pragma unroll
    for (int r = 0; r < 4; r++) inv[r] = 1.0f / lsum[r];
    ushort_t* Ep = Klds + wv * EOFF;
    #pragma unroll
    for (int j = 0; j < NJ; j++)
        #pragma unroll
        for (int r = 0; r < 4; r++)
            Ep[(lg * 4 + r) * ESTR + (j << 4) + l15] = f2bf(o[j][r] * inv[r]);
    asm volatile("s_waitcnt lgkmcnt(0)" ::: "memory");
    __builtin_amdgcn_sched_barrier(0);
    size_t gb = ((size_t)wrel * T + qbase) * C_DIM + chalf * 128;
    #pragma unroll
    for (int i = 0; i < 4; i++) {
        int off = i * 512 + lane * 8;
        int row = off >> 7, col = off & 127;
        uint4 v = *(const uint4*)(Ep + row * ESTR + col);
        *(uint4*)(obuf + gb + (size_t)row * C_DIM + col) = v;
    }
}

// ---------------- overlap-add fold + residual (+ optional fused LN2) ----------------
__global__ __launch_bounds__(256) void fold_ln(
    const ushort_t* __restrict__ obuf, const float* __restrict__ xin,
    float* __restrict__ y, const float* __restrict__ lw,
    const float* __restrict__ lb, ushort_t* __restrict__ lnout, int do_ln,
    int k, int Lh, int Lw, int w0, int w1)
{
    __shared__ float red[8];
    int p = blockIdx.x;
    int c = threadIdx.x;
    int b = p / 272;
    int rem = p - b * 272;
    int yy = rem >> 4, xx = rem & 15;
    int L = Lh * Lw;
    int T = k * k;
    float acc = xin ? xin[(size_t)p * C_DIM + c] : y[(size_t)p * C_DIM + c];
    int lh0 = max(0, yy - k + 1), lh1 = min(Lh - 1, yy);
    int lw0 = max(0, xx - k + 1), lw1 = min(Lw - 1, xx);
    for (int lh = lh0; lh <= lh1; lh++) {
        for (int lw = lw0; lw <= lw1; lw++) {
            int widx = b * L + lh * Lw + lw;
            if (widx < w0 || widx >= w1) continue;
            int n = (yy - lh) * k + (xx - lw);
            acc += bf2f(obuf[((size_t)(widx - w0) * T + n) * C_DIM + c]);
        }
    }
    y[(size_t)p * C_DIM + c] = acc;
    if (!do_ln) return;
    float s = acc;
    s += __shfl_down(s, 32); s += __shfl_down(s, 16); s += __shfl_down(s, 8);
    s += __shfl_down(s, 4);  s += __shfl_down(s, 2);  s += __shfl_down(s, 1);
    if ((c & 63) == 0) red[c >> 6] = s;
    __syncthreads();
    float mu = (red[0] + red[1] + red[2] + red[3]) * (1.0f / 256.0f);
    float d = acc - mu;
    float s2 = d * d;
    s2 += __shfl_down(s2, 32); s2 += __shfl_down(s2, 16); s2 += __shfl_down(s2, 8);
    s2 += __shfl_down(s2, 4);  s2 += __shfl_down(s2, 2);  s2 += __shfl_down(s2, 1);
    if ((c & 63) == 0) red[4 + (c >> 6)] = s2;
    __syncthreads();
    float var = (red[4] + red[5] + red[6] + red[7]) * (1.0f / 256.0f);
    lnout[(size_t)p * C_DIM + c] = f2bf(d * rsqrtf(var + 1e-5f) * lw[c] + lb[c]);
}

// ---------------- classifier ----------------
__global__ __launch_bounds__(256) void classifier_k(
    const float* __restrict__ h, const float* __restrict__ cw,
    const float* __restrict__ cb, float* __restrict__ out)
{
    __shared__ float hrow[256];
    int b = blockIdx.x;
    int n = blockIdx.y * 256 + threadIdx.x;
    hrow[threadIdx.x] = h[(size_t)b * 272 * C_DIM + threadIdx.x];
    __syncthreads();
    if (n < 1000) {
        float acc = cb[n];
        const float* wr = cw + (size_t)n * C_DIM;
        for (int c = 0; c < 256; c++) acc += hrow[c] * wr[c];
        out[(size_t)b * 1000 + n] = acc;
    }
}

extern "C" void kernel_launch(void* const* d_in, const int* in_sizes, int n_in,
                              void* d_out, int out_size, void* d_ws, size_t ws_size,
                              hipStream_t stream)
{
    const float* x       = (const float*)d_in[0];
    const float* patch_w = (const float*)d_in[1];
    const float* patch_b = (const float*)d_in[2];
    const float* row_emb = (const float*)d_in[3];
    const float* col_emb = (const float*)d_in[4];
    const float* cls_tok = (const float*)d_in[5];
    const float* ln1_w   = (const float*)d_in[6];
    const float* ln1_b   = (const float*)d_in[7];
    const float* qkv_w   = (const float*)d_in[8];
    const float* ln2_w   = (const float*)d_in[9];
    const float* ln2_b   = (const float*)d_in[10];
    const float* mlp_w1  = (const float*)d_in[11];
    const float* mlp_b1  = (const float*)d_in[12];
    const float* mlp_w2  = (const float*)d_in[13];
    const float* mlp_b2  = (const float*)d_in[14];
    const float* cls_w   = (const float*)d_in[15];
    const float* cls_b   = (const float*)d_in[16];
    float* out = (float*)d_out;

    // workspace layout (all 16B aligned)
    float* xb0  = (float*)d_ws;                          // NPIX*256 f32
    float* xb1  = xb0 + (size_t)NPIX * 256;              // NPIX*256 f32
    ushort_t* lnb = (ushort_t*)(xb1 + (size_t)NPIX * 256);   // NPIX*256 bf16
    ushort_t* qkb = lnb + (size_t)NPIX * 256;            // NPIX*512 bf16 (Q|K)
    ushort_t* vT  = qkb + (size_t)NPIX * 512;            // 256*NPIX bf16
    ushort_t* h1  = vT + (size_t)256 * NPIX;             // NPIX*512 bf16
    ushort_t* wq  = h1 + (size_t)NPIX * 512;             // 7*768*256 bf16
    ushort_t* w1b = wq + (size_t)7 * 768 * 256;          // 7*512*256 bf16
    ushort_t* w2b = w1b + (size_t)7 * 512 * 256;         // 7*256*512 bf16
    ushort_t* obuf = w2b + (size_t)7 * 256 * 512;        // rest of ws
    size_t obuf_off_bytes = (size_t)((char*)obuf - (char*)d_ws);
    size_t obuf_cap_e = (ws_size > obuf_off_bytes + 64)
                        ? (ws_size - obuf_off_bytes - 64) / 2 : 0;

    conv3_bf16<<<1024, 256, 0, stream>>>(qkv_w, wq, 7 * 768 * 256,
                                         mlp_w1, w1b, 7 * 512 * 256,
                                         mlp_w2, w2b, 7 * 256 * 512);

    patch_embed_ln<<<NPIX, 256, 0, stream>>>(x, patch_w, patch_b, row_emb,
                                             col_emb, cls_tok, ln1_w, ln1_b,
                                             xb0, lnb);

    const int KS[7] = {4, 4, 8, 8, 8, 16, 16};
    float* xcur = xb0;
    float* ybuf = xb1;

    for (int i = 0; i < 7; i++) {
        int k = KS[i];
        int Lh = 18 - k, Lw = 17 - k, L = Lh * Lw, T = k * k;
        float scale = 1.0f / std::sqrt((float)(256 / k));

        if (i > 0)
            layernorm_k<<<NPIX, 256, 0, stream>>>(xcur, ln1_w + i * 256,
                                                  ln1_b + i * 256, lnb);
        gemm_bf16<0><<<dim3(68, 12), 256, 0, stream>>>(
            lnb, wq + (size_t)i * 768 * 256, nullptr, nullptr, qkb, vT,
            NPIX, 768, 256);

        int totalW = 16 * L;
        size_t perW = (size_t)T * C_DIM;
        int maxW = (int)((obuf_cap_e / perW) < (size_t)totalW
                         ? (obuf_cap_e / perW) : (size_t)totalW);
        if (maxW < 2) maxW = 2;
        if (k == 4) maxW &= ~1;
        for (int w0 = 0; w0 < totalW; w0 += maxW) {
            int nW = totalW - w0 < maxW ? totalW - w0 : maxW;
            if (k == 4)
                attn_v2<4><<<(nW + 1) / 2, 256, 0, stream>>>(qkb, vT, obuf, w0, nW, scale);
            else if (k == 8)
                attn_v2<8><<<nW * 2, 256, 0, stream>>>(qkb, vT, obuf, w0, nW, scale);
            else
                attn_v2<16><<<nW * 8, 256, 0, stream>>>(qkb, vT, obuf, w0, nW, scale);
            int last = (w0 + nW >= totalW);
            fold_ln<<<NPIX, 256, 0, stream>>>(obuf, (w0 == 0) ? xcur : nullptr,
                                              ybuf, ln2_w + i * 256, ln2_b + i * 256,
                                              lnb, last, k, Lh, Lw, w0, w0 + nW);
        }

        gemm_bf16<2><<<dim3(68, 8), 256, 0, stream>>>(
            lnb, w1b + (size_t)i * 512 * 256, mlp_b1 + i * 512, nullptr, h1, nullptr,
            NPIX, 512, 256);
        gemm_bf16<3><<<dim3(68, 4), 256, 0, stream>>>(
            h1, w2b + (size_t)i * 256 * 512, mlp_b2 + i * 256, ybuf, xcur, nullptr,
            NPIX, 256, 512);
    }

    classifier_k<<<dim3(16, 4), 256, 0, stream>>>(xcur, cls_w, cls_b, out);
}

// Round 7
// 763.288 us; speedup vs baseline: 2.9459x; 1.1884x over previous
//
#include <hip/hip_runtime.h>
#include <cmath>

#define NPIX 4352      // 16 * 17 * 16 pixels (incl. cls row)
#define C_DIM 256

typedef unsigned short ushort_t;
typedef unsigned int uint_t;
typedef float f32x4 __attribute__((ext_vector_type(4)));
typedef __bf16 bfx8 __attribute__((ext_vector_type(8)));

__device__ __forceinline__ ushort_t f2bf(float f) {
    uint_t u = __float_as_uint(f);
    u = (u + 0x7FFFu + ((u >> 16) & 1u)) >> 16;
    return (ushort_t)u;
}
__device__ __forceinline__ float bf2f(ushort_t b) {
    return __uint_as_float(((uint_t)b) << 16);
}
__device__ __forceinline__ float gelu_f(float v) {
    return 0.5f * v * (1.0f + erff(v * 0.70710678118654752f));
}

// ---------------- fp32 -> bf16 converter (all 3 weight tensors, 1 launch) ----------------
__global__ __launch_bounds__(256) void conv3_bf16(
    const float* __restrict__ a, ushort_t* __restrict__ oa, int na,
    const float* __restrict__ b, ushort_t* __restrict__ ob, int nb,
    const float* __restrict__ c, ushort_t* __restrict__ oc, int nc)
{
    int ntot = na + nb + nc;
    for (int i = blockIdx.x * 256 + threadIdx.x; i < ntot; i += gridDim.x * 256) {
        if (i < na)            oa[i] = f2bf(a[i]);
        else if (i < na + nb)  ob[i - na] = f2bf(b[i - na]);
        else                   oc[i - na - nb] = f2bf(c[i - na - nb]);
    }
}

// ---------------- patch embed + pos emb + cls row + LN1(layer0) ----------------
__global__ __launch_bounds__(256) void patch_embed_ln(
    const float* __restrict__ x, const float* __restrict__ pw,
    const float* __restrict__ pb, const float* __restrict__ row_emb,
    const float* __restrict__ col_emb, const float* __restrict__ cls_tok,
    const float* __restrict__ lw, const float* __restrict__ lb,
    float* __restrict__ out, ushort_t* __restrict__ lnout)
{
    __shared__ float red[8];
    int p = blockIdx.x;
    int c = threadIdx.x;
    int b = p / 272;
    int rem = p - b * 272;
    int y = rem >> 4;
    int xw = rem & 15;
    float v;
    if (y == 0) {
        v = cls_tok[c];
    } else {
        int gr = y - 1, gc = xw;
        const float* xb = x + (size_t)b * 3 * 1024;
        const float* wc = pw + (size_t)c * 12;
        float acc = pb[c];
        #pragma unroll
        for (int ci = 0; ci < 3; ci++)
            #pragma unroll
            for (int ph = 0; ph < 2; ph++)
                #pragma unroll
                for (int pq = 0; pq < 2; pq++)
                    acc += xb[ci * 1024 + (2 * gr + ph) * 32 + (2 * gc + pq)]
                         * wc[(ci * 2 + ph) * 2 + pq];
        acc += (c < 128) ? row_emb[gr * 128 + c] : col_emb[gc * 128 + (c - 128)];
        v = acc;
    }
    out[(size_t)p * C_DIM + c] = v;
    float s = v;
    s += __shfl_down(s, 32); s += __shfl_down(s, 16); s += __shfl_down(s, 8);
    s += __shfl_down(s, 4);  s += __shfl_down(s, 2);  s += __shfl_down(s, 1);
    if ((c & 63) == 0) red[c >> 6] = s;
    __syncthreads();
    float mu = (red[0] + red[1] + red[2] + red[3]) * (1.0f / 256.0f);
    float d = v - mu;
    float s2 = d * d;
    s2 += __shfl_down(s2, 32); s2 += __shfl_down(s2, 16); s2 += __shfl_down(s2, 8);
    s2 += __shfl_down(s2, 4);  s2 += __shfl_down(s2, 2);  s2 += __shfl_down(s2, 1);
    if ((c & 63) == 0) red[4 + (c >> 6)] = s2;
    __syncthreads();
    float var = (red[4] + red[5] + red[6] + red[7]) * (1.0f / 256.0f);
    lnout[(size_t)p * C_DIM + c] = f2bf(d * rsqrtf(var + 1e-5f) * lw[c] + lb[c]);
}

// ---------------- standalone layernorm: fp32 in -> bf16 out ----------------
__global__ __launch_bounds__(256) void layernorm_k(
    const float* __restrict__ in, const float* __restrict__ w,
    const float* __restrict__ b, ushort_t* __restrict__ out)
{
    __shared__ float red[8];
    int r = blockIdx.x, c = threadIdx.x;
    float v = in[(size_t)r * C_DIM + c];
    float s = v;
    s += __shfl_down(s, 32); s += __shfl_down(s, 16); s += __shfl_down(s, 8);
    s += __shfl_down(s, 4);  s += __shfl_down(s, 2);  s += __shfl_down(s, 1);
    if ((c & 63) == 0) red[c >> 6] = s;
    __syncthreads();
    float mu = (red[0] + red[1] + red[2] + red[3]) * (1.0f / 256.0f);
    float d = v - mu;
    float s2 = d * d;
    s2 += __shfl_down(s2, 32); s2 += __shfl_down(s2, 16); s2 += __shfl_down(s2, 8);
    s2 += __shfl_down(s2, 4);  s2 += __shfl_down(s2, 2);  s2 += __shfl_down(s2, 1);
    if ((c & 63) == 0) red[4 + (c >> 6)] = s2;
    __syncthreads();
    float var = (red[4] + red[5] + red[6] + red[7]) * (1.0f / 256.0f);
    out[(size_t)r * C_DIM + c] = f2bf(d * rsqrtf(var + 1e-5f) * w[c] + b[c]);
}

// ---------------- LDS-staged double-buffered bf16 MFMA GEMM ----------------
// C[M,N] = A[M,K] @ B[N,K]^T.  2x2 waves, wave tile (BM/2)x(BN/2).
// MODE 0: qkv (n0<512 -> Q|K bf16 via LDS bounce; n0>=512 -> vT transposed)
// MODE 2: bias+gelu -> bf16 out via LDS bounce
// MODE 3: bias+residual -> fp32 out direct
template <int BM, int BN, int MODE>
__global__ __launch_bounds__(256) void gemm_v2(
    const ushort_t* __restrict__ A, const ushort_t* __restrict__ B,
    const float* __restrict__ bias, const float* __restrict__ res,
    void* __restrict__ outp, ushort_t* __restrict__ vT, int K, int ldo)
{
    constexpr int MI = BM / 32, NJ = BN / 32;
    constexpr int AG = BM * 4, BG = BN * 4;   // 16B granules per K-step tile
    constexpr int AU = AG / 256, BU = BG / 256;
    constexpr int HALF = (BM + BN) * 32;      // elements per buffer half
    constexpr int STAGE_E = 2 * HALF;
    constexpr int BOUNCE_E = BM * (BN + 8);
    constexpr int SMEM_E = (STAGE_E > BOUNCE_E) ? STAGE_E : BOUNCE_E;
    __shared__ ushort_t sm[SMEM_E];

    int m0 = blockIdx.x * BM, n0 = blockIdx.y * BN;
    int t = threadIdx.x, lane = t & 63, wv = t >> 6;
    int l15 = lane & 15, lg = lane >> 4;
    int wr = wv >> 1, wc = wv & 1;

    const int nt = K / 32;
    f32x4 acc[MI][NJ] = {};
    uint4 ra[AU], rb[BU];

    // prologue: stage buf0 (A at offset 0, B at offset BM*32)
    #pragma unroll
    for (int u = 0; u < AU; u++) {
        int g = t + u * 256, row = g >> 2, p = g & 3;
        int ps = p ^ ((row >> 1) & 3);
        ra[u] = *(const uint4*)(A + (size_t)(m0 + row) * K + ps * 8);
    }
    #pragma unroll
    for (int u = 0; u < BU; u++) {
        int g = t + u * 256, col = g >> 2, p = g & 3;
        int ps = p ^ ((col >> 1) & 3);
        rb[u] = *(const uint4*)(B + (size_t)(n0 + col) * K + ps * 8);
    }
    #pragma unroll
    for (int u = 0; u < AU; u++) *(uint4*)(sm + (t + u * 256) * 8) = ra[u];
    #pragma unroll
    for (int u = 0; u < BU; u++) *(uint4*)(sm + BM * 32 + (t + u * 256) * 8) = rb[u];
    __syncthreads();

    for (int ks = 0; ks < nt; ks++) {
        int coff = (ks & 1) * HALF, noff = ((ks & 1) ^ 1) * HALF;
        if (ks + 1 < nt) {
            int k1 = (ks + 1) * 32;
            #pragma unroll
            for (int u = 0; u < AU; u++) {
                int g = t + u * 256, row = g >> 2, p = g & 3;
                int ps = p ^ ((row >> 1) & 3);
                ra[u] = *(const uint4*)(A + (size_t)(m0 + row) * K + k1 + ps * 8);
            }
            #pragma unroll
            for (int u = 0; u < BU; u++) {
                int g = t + u * 256, col = g >> 2, p = g & 3;
                int ps = p ^ ((col >> 1) & 3);
                rb[u] = *(const uint4*)(B + (size_t)(n0 + col) * K + k1 + ps * 8);
            }
        }
        bfx8 af[MI], bf[NJ];
        #pragma unroll
        for (int i = 0; i < MI; i++) {
            int row = wr * (BM / 2) + i * 16 + l15;
            af[i] = *(const bfx8*)(sm + coff + row * 32 + ((lg ^ ((row >> 1) & 3)) << 3));
        }
        #pragma unroll
        for (int j = 0; j < NJ; j++) {
            int col = wc * (BN / 2) + j * 16 + l15;
            bf[j] = *(const bfx8*)(sm + coff + BM * 32 + col * 32 + ((lg ^ ((col >> 1) & 3)) << 3));
        }
        #pragma unroll
        for (int i = 0; i < MI; i++)
            #pragma unroll
            for (int j = 0; j < NJ; j++)
                acc[i][j] = __builtin_amdgcn_mfma_f32_16x16x32_bf16(af[i], bf[j], acc[i][j], 0, 0, 0);
        if (ks + 1 < nt) {
            #pragma unroll
            for (int u = 0; u < AU; u++) *(uint4*)(sm + noff + (t + u * 256) * 8) = ra[u];
            #pragma unroll
            for (int u = 0; u < BU; u++) *(uint4*)(sm + noff + BM * 32 + (t + u * 256) * 8) = rb[u];
        }
        __syncthreads();
    }

    if (MODE == 0 && n0 >= 512) {
        // V -> vT[c][pixel] (transposed, vectorized over rows)
        #pragma unroll
        for (int i = 0; i < MI; i++) {
            int mb = m0 + wr * (BM / 2) + i * 16 + lg * 4;
            #pragma unroll
            for (int j = 0; j < NJ; j++) {
                int nv = n0 - 512 + wc * (BN / 2) + j * 16 + l15;
                ushort4 pk;
                pk.x = f2bf(acc[i][j][0]); pk.y = f2bf(acc[i][j][1]);
                pk.z = f2bf(acc[i][j][2]); pk.w = f2bf(acc[i][j][3]);
                *(ushort4*)&vT[(size_t)nv * NPIX + mb] = pk;
            }
        }
        return;
    }
    if (MODE == 3) {
        float* o = (float*)outp;
        #pragma unroll
        for (int i = 0; i < MI; i++) {
            #pragma unroll
            for (int j = 0; j < NJ; j++) {
                int col = n0 + wc * (BN / 2) + j * 16 + l15;
                float bz = bias[col];
                #pragma unroll
                for (int r = 0; r < 4; r++) {
                    int row = m0 + wr * (BM / 2) + i * 16 + lg * 4 + r;
                    o[(size_t)row * ldo + col] = acc[i][j][r] + bz + res[(size_t)row * ldo + col];
                }
            }
        }
        return;
    }
    // bf16 out via LDS bounce (MODE 0 Q|K and MODE 2)
    __syncthreads();
    #pragma unroll
    for (int i = 0; i < MI; i++) {
        #pragma unroll
        for (int j = 0; j < NJ; j++) {
            int cl = wc * (BN / 2) + j * 16 + l15;
            float bz = (MODE == 2) ? bias[n0 + cl] : 0.0f;
            #pragma unroll
            for (int r = 0; r < 4; r++) {
                int rl = wr * (BM / 2) + i * 16 + lg * 4 + r;
                float v = acc[i][j][r];
                if (MODE == 2) v = gelu_f(v + bz);
                sm[rl * (BN + 8) + cl] = f2bf(v);
            }
        }
    }
    __syncthreads();
    ushort_t* ob = (ushort_t*)outp;
    #pragma unroll
    for (int e = 0; e < BM * BN; e += 2048) {
        int idx = e + t * 8;
        int rl = idx / BN, cl = idx % BN;
        uint4 v = *(const uint4*)(sm + rl * (BN + 8) + cl);
        *(uint4*)&ob[(size_t)(m0 + rl) * ldo + n0 + cl] = v;
    }
}

// unaligned (element-granular) loaders from a dword-aligned row
__device__ __forceinline__ uint2 ld_u4_align(const uint_t* drow, int e0) {
    int d0 = e0 >> 1;
    if (!(e0 & 1)) return make_uint2(drow[d0], drow[d0 + 1]);
    uint_t a = drow[d0], b = drow[d0 + 1], c = drow[d0 + 2];
    return make_uint2((a >> 16) | (b << 16), (b >> 16) | (c << 16));
}
__device__ __forceinline__ uint4 ld_u8_align(const uint_t* drow, int e0) {
    int d0 = e0 >> 1;
    if (!(e0 & 1)) return make_uint4(drow[d0], drow[d0 + 1], drow[d0 + 2], drow[d0 + 3]);
    uint_t a = drow[d0], b = drow[d0 + 1], c = drow[d0 + 2], d = drow[d0 + 3], e = drow[d0 + 4];
    return make_uint4((a >> 16) | (b << 16), (b >> 16) | (c << 16),
                      (c >> 16) | (d << 16), (d >> 16) | (e << 16));
}

// ---------------- LDS-staged MFMA sliding-window attention ----------------
template <int KK>
__global__ __launch_bounds__(256) void attn_v2(
    const ushort_t* __restrict__ qk, const ushort_t* __restrict__ vT,
    ushort_t* __restrict__ obuf, int w0, int nW, float scale)
{
    constexpr int T = KK * KK;
    constexpr int Lh = 18 - KK, Lw = 17 - KK, L = Lh * Lw;
    constexpr int NCH  = (KK == 16) ? 4 : 1;
    constexpr int NF   = (KK == 4) ? 1 : 4;
    constexpr int NJ   = 8;
    constexpr int PSTR = (KK == 4) ? 40 : 72;
    constexpr int KROWS = (KK == 4) ? 32 : 64;
    constexpr int VROWS = (KK == 4) ? 256 : 128;
    constexpr int PVKT = (KK == 4) ? 1 : 2;
    constexpr int EOFF = (KK == 4) ? 2048 : 4096;
    constexpr int ESTR = (KK == 4) ? 128 : 134;

    __shared__ ushort_t Klds[KROWS * 256];
    __shared__ ushort_t Vlds[VROWS * 64];
    __shared__ ushort_t Plds[4][16 * PSTR];

    int t = threadIdx.x, lane = t & 63, wv = t >> 6;
    int l15 = lane & 15, lg = lane >> 4;

    int wrel, qbase, chalf, wloc;
    if (KK == 4)      { wrel = blockIdx.x * 2 + (wv & 1); wloc = wv & 1; chalf = wv >> 1; qbase = 0; }
    else if (KK == 8) { wrel = blockIdx.x >> 1; wloc = 0; chalf = blockIdx.x & 1; qbase = wv * 16; }
    else              { wrel = blockIdx.x >> 3; wloc = 0; chalf = blockIdx.x & 1;
                        qbase = ((blockIdx.x >> 1) & 3) * 64 + wv * 16; }
    if (wrel >= nW) wrel = nW - 1;

    int pbs[2];
    #pragma unroll
    for (int w = 0; w < 2; w++) {
        int wi = (KK == 4) ? blockIdx.x * 2 + w : wrel;
        if (wi >= nW) wi = nW - 1;
        wi += w0;
        int b = wi / L, lrem = wi % L;
        pbs[w] = b * 272 + (lrem / Lw) * 16 + (lrem % Lw);
    }

    int qtok = qbase + l15;
    int qpix;
    if (KK == 4)      qpix = pbs[wloc] + ((qtok >> 2) << 4) + (qtok & 3);
    else if (KK == 8) qpix = pbs[0] + ((qtok >> 3) << 4) + (qtok & 7);
    else              qpix = pbs[0] + qtok;
    bfx8 qf[8];
    #pragma unroll
    for (int cs = 0; cs < 8; cs++)
        qf[cs] = *(const bfx8*)(qk + (size_t)qpix * 512 + cs * 32 + lg * 8);

    f32x4 o[NJ] = {};
    float mold[4] = {-1e30f, -1e30f, -1e30f, -1e30f};
    float lsum[4] = {0.f, 0.f, 0.f, 0.f};

    for (int ch = 0; ch < NCH; ch++) {
        int c0 = ch * 64;
        if (ch > 0) __syncthreads();
        for (int g = t; g < KROWS * 32; g += 256) {
            int row = g >> 5, cg = g & 31;
            int pix;
            if (KK == 4)      pix = pbs[row >> 4] + (((row & 15) >> 2) << 4) + (row & 3);
            else if (KK == 8) pix = pbs[0] + ((row >> 3) << 4) + (row & 7);
            else              pix = pbs[0] + c0 + row;
            uint4 v = *(const uint4*)(qk + (size_t)pix * 512 + 256 + cg * 8);
            *(uint4*)(Klds + row * 256 + ((cg ^ (row & 7)) << 3)) = v;
        }
        for (int g = t; g < VROWS * 8; g += 256) {
            int cr = g >> 3, c16 = g & 7;
            int cglob = (KK == 4) ? cr : chalf * 128 + cr;
            const uint_t* drow = (const uint_t*)(vT + (size_t)cglob * NPIX);
            uint4 v;
            if (KK == 4) {
                int w = c16 >> 2, sub = c16 & 3;
                if (sub < 2) {
                    int pix0 = pbs[w] + (sub << 5);
                    uint2 a  = ld_u4_align(drow, pix0);
                    uint2 b2 = ld_u4_align(drow, pix0 + 16);
                    v = make_uint4(a.x, a.y, b2.x, b2.y);
                } else v = make_uint4(0, 0, 0, 0);
            } else if (KK == 8) {
                v = ld_u8_align(drow, pbs[0] + (c16 << 4));
            } else {
                v = *(const uint4*)(vT + (size_t)cglob * NPIX + pbs[0] + c0 + (c16 << 3));
            }
            *(uint4*)(Vlds + cr * 64 + ((c16 ^ (cr & 7)) << 3)) = v;
        }
        __syncthreads();
        f32x4 s[NF];
        #pragma unroll
        for (int j = 0; j < NF; j++) s[j] = f32x4{0.f, 0.f, 0.f, 0.f};
        #pragma unroll
        for (int cs = 0; cs < 8; cs++) {
            #pragma unroll
            for (int j = 0; j < NF; j++) {
                int krow = (KK == 4) ? (wloc << 4) + l15 : (j << 4) + l15;
                bfx8 kf = *(const bfx8*)(Klds + krow * 256 + ((((cs << 2) + lg) ^ (krow & 7)) << 3));
                s[j] = __builtin_amdgcn_mfma_f32_16x16x32_bf16(qf[cs], kf, s[j], 0, 0, 0);
            }
        }
        float alpha[4];
        float p[NF][4];
        #pragma unroll
        for (int r = 0; r < 4; r++) {
            float mx = s[0][r];
            #pragma unroll
            for (int j = 1; j < NF; j++) mx = fmaxf(mx, s[j][r]);
            mx = fmaxf(mx, __shfl_xor(mx, 1));
            mx = fmaxf(mx, __shfl_xor(mx, 2));
            mx = fmaxf(mx, __shfl_xor(mx, 4));
            mx = fmaxf(mx, __shfl_xor(mx, 8));
            float mnew = fmaxf(mold[r], mx);
            alpha[r] = __expf(scale * (mold[r] - mnew));
            float ps = 0.f;
            #pragma unroll
            for (int j = 0; j < NF; j++) {
                p[j][r] = __expf(scale * (s[j][r] - mnew));
                ps += p[j][r];
            }
            ps += __shfl_xor(ps, 1);
            ps += __shfl_xor(ps, 2);
            ps += __shfl_xor(ps, 4);
            ps += __shfl_xor(ps, 8);
            lsum[r] = lsum[r] * alpha[r] + ps;
            mold[r] = mnew;
        }
        if (NCH > 1) {
            #pragma unroll
            for (int j = 0; j < NJ; j++) {
                o[j][0] *= alpha[0]; o[j][1] *= alpha[1];
                o[j][2] *= alpha[2]; o[j][3] *= alpha[3];
            }
        }
        ushort_t* Pw = Plds[wv];
        #pragma unroll
        for (int j = 0; j < NF; j++)
            #pragma unroll
            for (int r = 0; r < 4; r++)
                Pw[(lg * 4 + r) * PSTR + (j << 4) + l15] = f2bf(p[j][r]);
        if (KK == 4) {
            #pragma unroll
            for (int r = 0; r < 4; r++)
                Pw[(lg * 4 + r) * PSTR + 16 + l15] = 0;
        }
        asm volatile("s_waitcnt lgkmcnt(0)" ::: "memory");
        __builtin_amdgcn_sched_barrier(0);
        #pragma unroll
        for (int kt = 0; kt < PVKT; kt++) {
            bfx8 pf = *(const bfx8*)(Pw + l15 * PSTR + (kt << 5) + (lg << 3));
            #pragma unroll
            for (int j = 0; j < NJ; j++) {
                int cr = (KK == 4) ? chalf * 128 + (j << 4) + l15 : (j << 4) + l15;
                int c16 = ((KK == 4) ? (wloc << 2) + lg : (kt << 2) + lg) ^ (cr & 7);
                bfx8 vf = *(const bfx8*)(Vlds + cr * 64 + (c16 << 3));
                o[j] = __builtin_amdgcn_mfma_f32_16x16x32_bf16(pf, vf, o[j], 0, 0, 0);
            }
        }
    }
    asm volatile("s_waitcnt lgkmcnt(0)" ::: "memory");
    __syncthreads();
    float inv[4];
    #pragma unroll
    for (int r = 0; r < 4; r++) inv[r] = 1.0f / lsum[r];
    ushort_t* Ep = Klds + wv * EOFF;
    #pragma unroll
    for (int j = 0; j < NJ; j++)
        #pragma unroll
        for (int r = 0; r < 4; r++)
            Ep[(lg * 4 + r) * ESTR + (j << 4) + l15] = f2bf(o[j][r] * inv[r]);
    asm volatile("s_waitcnt lgkmcnt(0)" ::: "memory");
    __builtin_amdgcn_sched_barrier(0);
    size_t gb = ((size_t)wrel * T + qbase) * C_DIM + chalf * 128;
    #pragma unroll
    for (int i = 0; i < 4; i++) {
        int off = i * 512 + lane * 8;
        int row = off >> 7, col = off & 127;
        uint4 v = *(const uint4*)(Ep + row * ESTR + col);
        *(uint4*)(obuf + gb + (size_t)row * C_DIM + col) = v;
    }
}

// ---------------- overlap-add fold + residual (+ optional fused LN2) ----------------
__global__ __launch_bounds__(256) void fold_ln(
    const ushort_t* __restrict__ obuf, const float* __restrict__ xin,
    float* __restrict__ y, const float* __restrict__ lw,
    const float* __restrict__ lb, ushort_t* __restrict__ lnout, int do_ln,
    int k, int Lh, int Lw, int w0, int w1)
{
    __shared__ float red[8];
    int p = blockIdx.x;
    int c = threadIdx.x;
    int b = p / 272;
    int rem = p - b * 272;
    int yy = rem >> 4, xx = rem & 15;
    int L = Lh * Lw;
    int T = k * k;
    float acc = xin ? xin[(size_t)p * C_DIM + c] : y[(size_t)p * C_DIM + c];
    int lh0 = max(0, yy - k + 1), lh1 = min(Lh - 1, yy);
    int lw0 = max(0, xx - k + 1), lw1 = min(Lw - 1, xx);
    for (int lh = lh0; lh <= lh1; lh++) {
        for (int lw = lw0; lw <= lw1; lw++) {
            int widx = b * L + lh * Lw + lw;
            if (widx < w0 || widx >= w1) continue;
            int n = (yy - lh) * k + (xx - lw);
            acc += bf2f(obuf[((size_t)(widx - w0) * T + n) * C_DIM + c]);
        }
    }
    y[(size_t)p * C_DIM + c] = acc;
    if (!do_ln) return;
    float s = acc;
    s += __shfl_down(s, 32); s += __shfl_down(s, 16); s += __shfl_down(s, 8);
    s += __shfl_down(s, 4);  s += __shfl_down(s, 2);  s += __shfl_down(s, 1);
    if ((c & 63) == 0) red[c >> 6] = s;
    __syncthreads();
    float mu = (red[0] + red[1] + red[2] + red[3]) * (1.0f / 256.0f);
    float d = acc - mu;
    float s2 = d * d;
    s2 += __shfl_down(s2, 32); s2 += __shfl_down(s2, 16); s2 += __shfl_down(s2, 8);
    s2 += __shfl_down(s2, 4);  s2 += __shfl_down(s2, 2);  s2 += __shfl_down(s2, 1);
    if ((c & 63) == 0) red[4 + (c >> 6)] = s2;
    __syncthreads();
    float var = (red[4] + red[5] + red[6] + red[7]) * (1.0f / 256.0f);
    lnout[(size_t)p * C_DIM + c] = f2bf(d * rsqrtf(var + 1e-5f) * lw[c] + lb[c]);
}

// ---------------- classifier ----------------
__global__ __launch_bounds__(256) void classifier_k(
    const float* __restrict__ h, const float* __restrict__ cw,
    const float* __restrict__ cb, float* __restrict__ out)
{
    __shared__ float hrow[256];
    int b = blockIdx.x;
    int n = blockIdx.y * 256 + threadIdx.x;
    hrow[threadIdx.x] = h[(size_t)b * 272 * C_DIM + threadIdx.x];
    __syncthreads();
    if (n < 1000) {
        float acc = cb[n];
        const float* wr = cw + (size_t)n * C_DIM;
        for (int c = 0; c < 256; c++) acc += hrow[c] * wr[c];
        out[(size_t)b * 1000 + n] = acc;
    }
}

extern "C" void kernel_launch(void* const* d_in, const int* in_sizes, int n_in,
                              void* d_out, int out_size, void* d_ws, size_t ws_size,
                              hipStream_t stream)
{
    const float* x       = (const float*)d_in[0];
    const float* patch_w = (const float*)d_in[1];
    const float* patch_b = (const float*)d_in[2];
    const float* row_emb = (const float*)d_in[3];
    const float* col_emb = (const float*)d_in[4];
    const float* cls_tok = (const float*)d_in[5];
    const float* ln1_w   = (const float*)d_in[6];
    const float* ln1_b   = (const float*)d_in[7];
    const float* qkv_w   = (const float*)d_in[8];
    const float* ln2_w   = (const float*)d_in[9];
    const float* ln2_b   = (const float*)d_in[10];
    const float* mlp_w1  = (const float*)d_in[11];
    const float* mlp_b1  = (const float*)d_in[12];
    const float* mlp_w2  = (const float*)d_in[13];
    const float* mlp_b2  = (const float*)d_in[14];
    const float* cls_w   = (const float*)d_in[15];
    const float* cls_b   = (const float*)d_in[16];
    float* out = (float*)d_out;

    // workspace layout (all 16B aligned)
    float* xb0  = (float*)d_ws;                          // NPIX*256 f32
    float* xb1  = xb0 + (size_t)NPIX * 256;              // NPIX*256 f32
    ushort_t* lnb = (ushort_t*)(xb1 + (size_t)NPIX * 256);   // NPIX*256 bf16
    ushort_t* qkb = lnb + (size_t)NPIX * 256;            // NPIX*512 bf16 (Q|K)
    ushort_t* vT  = qkb + (size_t)NPIX * 512;            // 256*NPIX bf16
    ushort_t* h1  = vT + (size_t)256 * NPIX;             // NPIX*512 bf16
    ushort_t* wq  = h1 + (size_t)NPIX * 512;             // 7*768*256 bf16
    ushort_t* w1b = wq + (size_t)7 * 768 * 256;          // 7*512*256 bf16
    ushort_t* w2b = w1b + (size_t)7 * 512 * 256;         // 7*256*512 bf16
    ushort_t* obuf = w2b + (size_t)7 * 256 * 512;        // rest of ws
    size_t obuf_off_bytes = (size_t)((char*)obuf - (char*)d_ws);
    size_t obuf_cap_e = (ws_size > obuf_off_bytes + 64)
                        ? (ws_size - obuf_off_bytes - 64) / 2 : 0;

    conv3_bf16<<<1024, 256, 0, stream>>>(qkv_w, wq, 7 * 768 * 256,
                                         mlp_w1, w1b, 7 * 512 * 256,
                                         mlp_w2, w2b, 7 * 256 * 512);

    patch_embed_ln<<<NPIX, 256, 0, stream>>>(x, patch_w, patch_b, row_emb,
                                             col_emb, cls_tok, ln1_w, ln1_b,
                                             xb0, lnb);

    const int KS[7] = {4, 4, 8, 8, 8, 16, 16};
    float* xcur = xb0;
    float* ybuf = xb1;

    for (int i = 0; i < 7; i++) {
        int k = KS[i];
        int Lh = 18 - k, Lw = 17 - k, L = Lh * Lw, T = k * k;
        float scale = 1.0f / std::sqrt((float)(256 / k));

        if (i > 0)
            layernorm_k<<<NPIX, 256, 0, stream>>>(xcur, ln1_w + i * 256,
                                                  ln1_b + i * 256, lnb);
        // QKV GEMM: M=NPIX, N=768, K=256
        gemm_v2<128, 128, 0><<<dim3(NPIX / 128, 6), 256, 0, stream>>>(
            lnb, wq + (size_t)i * 768 * 256, nullptr, nullptr, qkb, vT, 256, 512);

        int totalW = 16 * L;
        size_t perW = (size_t)T * C_DIM;
        int maxW = (int)((obuf_cap_e / perW) < (size_t)totalW
                         ? (obuf_cap_e / perW) : (size_t)totalW);
        if (maxW < 2) maxW = 2;
        if (k == 4) maxW &= ~1;
        for (int w0 = 0; w0 < totalW; w0 += maxW) {
            int nW = totalW - w0 < maxW ? totalW - w0 : maxW;
            if (k == 4)
                attn_v2<4><<<(nW + 1) / 2, 256, 0, stream>>>(qkb, vT, obuf, w0, nW, scale);
            else if (k == 8)
                attn_v2<8><<<nW * 2, 256, 0, stream>>>(qkb, vT, obuf, w0, nW, scale);
            else
                attn_v2<16><<<nW * 8, 256, 0, stream>>>(qkb, vT, obuf, w0, nW, scale);
            int last = (w0 + nW >= totalW);
            fold_ln<<<NPIX, 256, 0, stream>>>(obuf, (w0 == 0) ? xcur : nullptr,
                                              ybuf, ln2_w + i * 256, ln2_b + i * 256,
                                              lnb, last, k, Lh, Lw, w0, w0 + nW);
        }

        // MLP1 + gelu: M=NPIX, N=512, K=256
        gemm_v2<64, 128, 2><<<dim3(NPIX / 64, 4), 256, 0, stream>>>(
            lnb, w1b + (size_t)i * 512 * 256, mlp_b1 + i * 512, nullptr, h1, nullptr, 256, 512);
        // MLP2 + bias + residual: M=NPIX, N=256, K=512 -> fp32 xcur
        gemm_v2<64, 64, 3><<<dim3(NPIX / 64, 4), 256, 0, stream>>>(
            h1, w2b + (size_t)i * 256 * 512, mlp_b2 + i * 256, ybuf, xcur, nullptr, 512, 256);
    }

    classifier_k<<<dim3(16, 4), 256, 0, stream>>>(xcur, cls_w, cls_b, out);
}

// Round 8
// 725.584 us; speedup vs baseline: 3.0989x; 1.0520x over previous
//
#include <hip/hip_runtime.h>
#include <cmath>

#define NPIX 4352      // 16 * 17 * 16 pixels (incl. cls row)
#define C_DIM 256

typedef unsigned short ushort_t;
typedef unsigned int uint_t;
typedef float f32x4 __attribute__((ext_vector_type(4)));
typedef __bf16 bfx8 __attribute__((ext_vector_type(8)));

__device__ __forceinline__ ushort_t f2bf(float f) {
    uint_t u = __float_as_uint(f);
    u = (u + 0x7FFFu + ((u >> 16) & 1u)) >> 16;
    return (ushort_t)u;
}
__device__ __forceinline__ float bf2f(ushort_t b) {
    return __uint_as_float(((uint_t)b) << 16);
}
__device__ __forceinline__ float gelu_f(float v) {
    return 0.5f * v * (1.0f + erff(v * 0.70710678118654752f));
}

// ---------------- fp32 -> bf16 converter (all 3 weight tensors, 1 launch) ----------------
__global__ __launch_bounds__(256) void conv3_bf16(
    const float* __restrict__ a, ushort_t* __restrict__ oa, int na,
    const float* __restrict__ b, ushort_t* __restrict__ ob, int nb,
    const float* __restrict__ c, ushort_t* __restrict__ oc, int nc)
{
    int ntot = na + nb + nc;
    for (int i = blockIdx.x * 256 + threadIdx.x; i < ntot; i += gridDim.x * 256) {
        if (i < na)            oa[i] = f2bf(a[i]);
        else if (i < na + nb)  ob[i - na] = f2bf(b[i - na]);
        else                   oc[i - na - nb] = f2bf(c[i - na - nb]);
    }
}

// ---------------- patch embed + pos emb + cls row + LN1(layer0) ----------------
__global__ __launch_bounds__(256) void patch_embed_ln(
    const float* __restrict__ x, const float* __restrict__ pw,
    const float* __restrict__ pb, const float* __restrict__ row_emb,
    const float* __restrict__ col_emb, const float* __restrict__ cls_tok,
    const float* __restrict__ lw, const float* __restrict__ lb,
    float* __restrict__ out, ushort_t* __restrict__ lnout)
{
    __shared__ float red[8];
    int p = blockIdx.x;
    int c = threadIdx.x;
    int b = p / 272;
    int rem = p - b * 272;
    int y = rem >> 4;
    int xw = rem & 15;
    float v;
    if (y == 0) {
        v = cls_tok[c];
    } else {
        int gr = y - 1, gc = xw;
        const float* xb = x + (size_t)b * 3 * 1024;
        const float* wc = pw + (size_t)c * 12;
        float acc = pb[c];
        #pragma unroll
        for (int ci = 0; ci < 3; ci++)
            #pragma unroll
            for (int ph = 0; ph < 2; ph++)
                #pragma unroll
                for (int pq = 0; pq < 2; pq++)
                    acc += xb[ci * 1024 + (2 * gr + ph) * 32 + (2 * gc + pq)]
                         * wc[(ci * 2 + ph) * 2 + pq];
        acc += (c < 128) ? row_emb[gr * 128 + c] : col_emb[gc * 128 + (c - 128)];
        v = acc;
    }
    out[(size_t)p * C_DIM + c] = v;
    float s = v;
    s += __shfl_down(s, 32); s += __shfl_down(s, 16); s += __shfl_down(s, 8);
    s += __shfl_down(s, 4);  s += __shfl_down(s, 2);  s += __shfl_down(s, 1);
    if ((c & 63) == 0) red[c >> 6] = s;
    __syncthreads();
    float mu = (red[0] + red[1] + red[2] + red[3]) * (1.0f / 256.0f);
    float d = v - mu;
    float s2 = d * d;
    s2 += __shfl_down(s2, 32); s2 += __shfl_down(s2, 16); s2 += __shfl_down(s2, 8);
    s2 += __shfl_down(s2, 4);  s2 += __shfl_down(s2, 2);  s2 += __shfl_down(s2, 1);
    if ((c & 63) == 0) red[4 + (c >> 6)] = s2;
    __syncthreads();
    float var = (red[4] + red[5] + red[6] + red[7]) * (1.0f / 256.0f);
    lnout[(size_t)p * C_DIM + c] = f2bf(d * rsqrtf(var + 1e-5f) * lw[c] + lb[c]);
}

// ---------------- standalone layernorm: fp32 in -> bf16 out ----------------
__global__ __launch_bounds__(256) void layernorm_k(
    const float* __restrict__ in, const float* __restrict__ w,
    const float* __restrict__ b, ushort_t* __restrict__ out)
{
    __shared__ float red[8];
    int r = blockIdx.x, c = threadIdx.x;
    float v = in[(size_t)r * C_DIM + c];
    float s = v;
    s += __shfl_down(s, 32); s += __shfl_down(s, 16); s += __shfl_down(s, 8);
    s += __shfl_down(s, 4);  s += __shfl_down(s, 2);  s += __shfl_down(s, 1);
    if ((c & 63) == 0) red[c >> 6] = s;
    __syncthreads();
    float mu = (red[0] + red[1] + red[2] + red[3]) * (1.0f / 256.0f);
    float d = v - mu;
    float s2 = d * d;
    s2 += __shfl_down(s2, 32); s2 += __shfl_down(s2, 16); s2 += __shfl_down(s2, 8);
    s2 += __shfl_down(s2, 4);  s2 += __shfl_down(s2, 2);  s2 += __shfl_down(s2, 1);
    if ((c & 63) == 0) red[4 + (c >> 6)] = s2;
    __syncthreads();
    float var = (red[4] + red[5] + red[6] + red[7]) * (1.0f / 256.0f);
    out[(size_t)r * C_DIM + c] = f2bf(d * rsqrtf(var + 1e-5f) * w[c] + b[c]);
}

// ---------------- LDS-staged double-buffered bf16 MFMA GEMM ----------------
template <int BM, int BN, int MODE>
__global__ __launch_bounds__(256) void gemm_v2(
    const ushort_t* __restrict__ A, const ushort_t* __restrict__ B,
    const float* __restrict__ bias, const float* __restrict__ res,
    void* __restrict__ outp, ushort_t* __restrict__ vT, int K, int ldo)
{
    constexpr int MI = BM / 32, NJ = BN / 32;
    constexpr int AG = BM * 4, BG = BN * 4;
    constexpr int AU = AG / 256, BU = BG / 256;
    constexpr int HALF = (BM + BN) * 32;
    constexpr int STAGE_E = 2 * HALF;
    constexpr int BOUNCE_E = BM * (BN + 8);
    constexpr int SMEM_E = (STAGE_E > BOUNCE_E) ? STAGE_E : BOUNCE_E;
    __shared__ ushort_t sm[SMEM_E];

    int m0 = blockIdx.x * BM, n0 = blockIdx.y * BN;
    int t = threadIdx.x, lane = t & 63, wv = t >> 6;
    int l15 = lane & 15, lg = lane >> 4;
    int wr = wv >> 1, wc = wv & 1;

    const int nt = K / 32;
    f32x4 acc[MI][NJ] = {};
    uint4 ra[AU], rb[BU];

    #pragma unroll
    for (int u = 0; u < AU; u++) {
        int g = t + u * 256, row = g >> 2, p = g & 3;
        int ps = p ^ ((row >> 1) & 3);
        ra[u] = *(const uint4*)(A + (size_t)(m0 + row) * K + ps * 8);
    }
    #pragma unroll
    for (int u = 0; u < BU; u++) {
        int g = t + u * 256, col = g >> 2, p = g & 3;
        int ps = p ^ ((col >> 1) & 3);
        rb[u] = *(const uint4*)(B + (size_t)(n0 + col) * K + ps * 8);
    }
    #pragma unroll
    for (int u = 0; u < AU; u++) *(uint4*)(sm + (t + u * 256) * 8) = ra[u];
    #pragma unroll
    for (int u = 0; u < BU; u++) *(uint4*)(sm + BM * 32 + (t + u * 256) * 8) = rb[u];
    __syncthreads();

    for (int ks = 0; ks < nt; ks++) {
        int coff = (ks & 1) * HALF, noff = ((ks & 1) ^ 1) * HALF;
        if (ks + 1 < nt) {
            int k1 = (ks + 1) * 32;
            #pragma unroll
            for (int u = 0; u < AU; u++) {
                int g = t + u * 256, row = g >> 2, p = g & 3;
                int ps = p ^ ((row >> 1) & 3);
                ra[u] = *(const uint4*)(A + (size_t)(m0 + row) * K + k1 + ps * 8);
            }
            #pragma unroll
            for (int u = 0; u < BU; u++) {
                int g = t + u * 256, col = g >> 2, p = g & 3;
                int ps = p ^ ((col >> 1) & 3);
                rb[u] = *(const uint4*)(B + (size_t)(n0 + col) * K + k1 + ps * 8);
            }
        }
        bfx8 af[MI], bf[NJ];
        #pragma unroll
        for (int i = 0; i < MI; i++) {
            int row = wr * (BM / 2) + i * 16 + l15;
            af[i] = *(const bfx8*)(sm + coff + row * 32 + ((lg ^ ((row >> 1) & 3)) << 3));
        }
        #pragma unroll
        for (int j = 0; j < NJ; j++) {
            int col = wc * (BN / 2) + j * 16 + l15;
            bf[j] = *(const bfx8*)(sm + coff + BM * 32 + col * 32 + ((lg ^ ((col >> 1) & 3)) << 3));
        }
        #pragma unroll
        for (int i = 0; i < MI; i++)
            #pragma unroll
            for (int j = 0; j < NJ; j++)
                acc[i][j] = __builtin_amdgcn_mfma_f32_16x16x32_bf16(af[i], bf[j], acc[i][j], 0, 0, 0);
        if (ks + 1 < nt) {
            #pragma unroll
            for (int u = 0; u < AU; u++) *(uint4*)(sm + noff + (t + u * 256) * 8) = ra[u];
            #pragma unroll
            for (int u = 0; u < BU; u++) *(uint4*)(sm + noff + BM * 32 + (t + u * 256) * 8) = rb[u];
        }
        __syncthreads();
    }

    if (MODE == 0 && n0 >= 512) {
        #pragma unroll
        for (int i = 0; i < MI; i++) {
            int mb = m0 + wr * (BM / 2) + i * 16 + lg * 4;
            #pragma unroll
            for (int j = 0; j < NJ; j++) {
                int nv = n0 - 512 + wc * (BN / 2) + j * 16 + l15;
                ushort4 pk;
                pk.x = f2bf(acc[i][j][0]); pk.y = f2bf(acc[i][j][1]);
                pk.z = f2bf(acc[i][j][2]); pk.w = f2bf(acc[i][j][3]);
                *(ushort4*)&vT[(size_t)nv * NPIX + mb] = pk;
            }
        }
        return;
    }
    if (MODE == 3) {
        float* o = (float*)outp;
        #pragma unroll
        for (int i = 0; i < MI; i++) {
            #pragma unroll
            for (int j = 0; j < NJ; j++) {
                int col = n0 + wc * (BN / 2) + j * 16 + l15;
                float bz = bias[col];
                #pragma unroll
                for (int r = 0; r < 4; r++) {
                    int row = m0 + wr * (BM / 2) + i * 16 + lg * 4 + r;
                    o[(size_t)row * ldo + col] = acc[i][j][r] + bz + res[(size_t)row * ldo + col];
                }
            }
        }
        return;
    }
    __syncthreads();
    #pragma unroll
    for (int i = 0; i < MI; i++) {
        #pragma unroll
        for (int j = 0; j < NJ; j++) {
            int cl = wc * (BN / 2) + j * 16 + l15;
            float bz = (MODE == 2) ? bias[n0 + cl] : 0.0f;
            #pragma unroll
            for (int r = 0; r < 4; r++) {
                int rl = wr * (BM / 2) + i * 16 + lg * 4 + r;
                float v = acc[i][j][r];
                if (MODE == 2) v = gelu_f(v + bz);
                sm[rl * (BN + 8) + cl] = f2bf(v);
            }
        }
    }
    __syncthreads();
    ushort_t* ob = (ushort_t*)outp;
    #pragma unroll
    for (int e = 0; e < BM * BN; e += 2048) {
        int idx = e + t * 8;
        int rl = idx / BN, cl = idx % BN;
        uint4 v = *(const uint4*)(sm + rl * (BN + 8) + cl);
        *(uint4*)&ob[(size_t)(m0 + rl) * ldo + n0 + cl] = v;
    }
}

// unaligned (element-granular) loaders from a dword-aligned row
__device__ __forceinline__ uint2 ld_u4_align(const uint_t* drow, int e0) {
    int d0 = e0 >> 1;
    if (!(e0 & 1)) return make_uint2(drow[d0], drow[d0 + 1]);
    uint_t a = drow[d0], b = drow[d0 + 1], c = drow[d0 + 2];
    return make_uint2((a >> 16) | (b << 16), (b >> 16) | (c << 16));
}
__device__ __forceinline__ uint4 ld_u8_align(const uint_t* drow, int e0) {
    int d0 = e0 >> 1;
    if (!(e0 & 1)) return make_uint4(drow[d0], drow[d0 + 1], drow[d0 + 2], drow[d0 + 3]);
    uint_t a = drow[d0], b = drow[d0 + 1], c = drow[d0 + 2], d = drow[d0 + 3], e = drow[d0 + 4];
    return make_uint4((a >> 16) | (b << 16), (b >> 16) | (c << 16),
                      (c >> 16) | (d << 16), (d >> 16) | (e << 16));
}

// ---------------- k=4 LDS-staged attention (unchanged from R5/R6, KK=4 only) ----------------
template <int KK>
__global__ __launch_bounds__(256) void attn_v2(
    const ushort_t* __restrict__ qk, const ushort_t* __restrict__ vT,
    ushort_t* __restrict__ obuf, int w0, int nW, float scale)
{
    constexpr int T = KK * KK;
    constexpr int Lh = 18 - KK, Lw = 17 - KK, L = Lh * Lw;
    constexpr int NF   = 1;
    constexpr int NJ   = 8;
    constexpr int PSTR = 40;
    constexpr int KROWS = 32;
    constexpr int VROWS = 256;
    constexpr int EOFF = 2048;
    constexpr int ESTR = 128;

    __shared__ ushort_t Klds[KROWS * 256];
    __shared__ ushort_t Vlds[VROWS * 64];
    __shared__ ushort_t Plds[4][16 * PSTR];

    int t = threadIdx.x, lane = t & 63, wv = t >> 6;
    int l15 = lane & 15, lg = lane >> 4;

    int wrel = blockIdx.x * 2 + (wv & 1);
    int wloc = wv & 1, chalf = wv >> 1, qbase = 0;
    if (wrel >= nW) wrel = nW - 1;

    int pbs[2];
    #pragma unroll
    for (int w = 0; w < 2; w++) {
        int wi = blockIdx.x * 2 + w;
        if (wi >= nW) wi = nW - 1;
        wi += w0;
        int b = wi / L, lrem = wi % L;
        pbs[w] = b * 272 + (lrem / Lw) * 16 + (lrem % Lw);
    }

    int qtok = qbase + l15;
    int qpix = pbs[wloc] + ((qtok >> 2) << 4) + (qtok & 3);
    bfx8 qf[8];
    #pragma unroll
    for (int cs = 0; cs < 8; cs++)
        qf[cs] = *(const bfx8*)(qk + (size_t)qpix * 512 + cs * 32 + lg * 8);

    f32x4 o[NJ] = {};
    float lsum[4] = {0.f, 0.f, 0.f, 0.f};

    for (int g = t; g < KROWS * 32; g += 256) {
        int row = g >> 5, cg = g & 31;
        int pix = pbs[row >> 4] + (((row & 15) >> 2) << 4) + (row & 3);
        uint4 v = *(const uint4*)(qk + (size_t)pix * 512 + 256 + cg * 8);
        *(uint4*)(Klds + row * 256 + ((cg ^ (row & 7)) << 3)) = v;
    }
    for (int g = t; g < VROWS * 8; g += 256) {
        int cr = g >> 3, c16 = g & 7;
        const uint_t* drow = (const uint_t*)(vT + (size_t)cr * NPIX);
        uint4 v;
        int w = c16 >> 2, sub = c16 & 3;
        if (sub < 2) {
            int pix0 = pbs[w] + (sub << 5);
            uint2 a  = ld_u4_align(drow, pix0);
            uint2 b2 = ld_u4_align(drow, pix0 + 16);
            v = make_uint4(a.x, a.y, b2.x, b2.y);
        } else v = make_uint4(0, 0, 0, 0);
        *(uint4*)(Vlds + cr * 64 + ((c16 ^ (cr & 7)) << 3)) = v;
    }
    __syncthreads();
    f32x4 s[NF];
    #pragma unroll
    for (int j = 0; j < NF; j++) s[j] = f32x4{0.f, 0.f, 0.f, 0.f};
    #pragma unroll
    for (int cs = 0; cs < 8; cs++) {
        int krow = (wloc << 4) + l15;
        bfx8 kf = *(const bfx8*)(Klds + krow * 256 + ((((cs << 2) + lg) ^ (krow & 7)) << 3));
        s[0] = __builtin_amdgcn_mfma_f32_16x16x32_bf16(qf[cs], kf, s[0], 0, 0, 0);
    }
    float p[NF][4];
    #pragma unroll
    for (int r = 0; r < 4; r++) {
        float mx = s[0][r];
        mx = fmaxf(mx, __shfl_xor(mx, 1));
        mx = fmaxf(mx, __shfl_xor(mx, 2));
        mx = fmaxf(mx, __shfl_xor(mx, 4));
        mx = fmaxf(mx, __shfl_xor(mx, 8));
        float ps = 0.f;
        p[0][r] = __expf(scale * (s[0][r] - mx));
        ps += p[0][r];
        ps += __shfl_xor(ps, 1);
        ps += __shfl_xor(ps, 2);
        ps += __shfl_xor(ps, 4);
        ps += __shfl_xor(ps, 8);
        lsum[r] = ps;
    }
    ushort_t* Pw = Plds[wv];
    #pragma unroll
    for (int r = 0; r < 4; r++) {
        Pw[(lg * 4 + r) * PSTR + l15] = f2bf(p[0][r]);
        Pw[(lg * 4 + r) * PSTR + 16 + l15] = 0;
    }
    asm volatile("s_waitcnt lgkmcnt(0)" ::: "memory");
    __builtin_amdgcn_sched_barrier(0);
    {
        bfx8 pf = *(const bfx8*)(Pw + l15 * PSTR + (lg << 3));
        #pragma unroll
        for (int j = 0; j < NJ; j++) {
            int cr = chalf * 128 + (j << 4) + l15;
            int c16 = ((wloc << 2) + lg) ^ (cr & 7);
            bfx8 vf = *(const bfx8*)(Vlds + cr * 64 + (c16 << 3));
            o[j] = __builtin_amdgcn_mfma_f32_16x16x32_bf16(pf, vf, o[j], 0, 0, 0);
        }
    }
    asm volatile("s_waitcnt lgkmcnt(0)" ::: "memory");
    __syncthreads();
    float inv[4];
    #pragma unroll
    for (int r = 0; r < 4; r++) inv[r] = 1.0f / lsum[r];
    ushort_t* Ep = Klds + wv * EOFF;
    #pragma unroll
    for (int j = 0; j < NJ; j++)
        #pragma unroll
        for (int r = 0; r < 4; r++)
            Ep[(lg * 4 + r) * ESTR + (j << 4) + l15] = f2bf(o[j][r] * inv[r]);
    asm volatile("s_waitcnt lgkmcnt(0)" ::: "memory");
    __builtin_amdgcn_sched_barrier(0);
    size_t gb = ((size_t)wrel * T + qbase) * C_DIM + chalf * 128;
    #pragma unroll
    for (int i = 0; i < 4; i++) {
        int off = i * 512 + lane * 8;
        int row = off >> 7, col = off & 127;
        uint4 v = *(const uint4*)(Ep + row * ESTR + col);
        *(uint4*)(obuf + gb + (size_t)row * C_DIM + col) = v;
    }
}

// ---------------- k=8 attention v3: one block per window, full 256 ch ----------------
// SH: K [64][256] @0 (16384 el), V^T [256][64] @16384 (16384 el).
// P overlays K region after the post-QK barrier. Epilogue overlays everything.
__global__ __launch_bounds__(256) void attn_v3(
    const ushort_t* __restrict__ qk, const ushort_t* __restrict__ vT,
    ushort_t* __restrict__ obuf, int w0, float scale)
{
    __shared__ ushort_t SH[32768];    // 64 KB
    const int Lw = 9, L = 90;
    int t = threadIdx.x, lane = t & 63, wv = t >> 6;
    int l15 = lane & 15, lg = lane >> 4;
    int wrel = blockIdx.x;
    int widx = w0 + wrel;
    int b = widx / L, lrem = widx % L;
    int pbase = b * 272 + (lrem / Lw) * 16 + (lrem % Lw);
    int qbase = wv * 16;

    // Q fragments (16 queries x 256 ch)
    int qtok = qbase + l15;
    int qpix = pbase + ((qtok >> 3) << 4) + (qtok & 7);
    bfx8 qf[8];
    #pragma unroll
    for (int cs = 0; cs < 8; cs++)
        qf[cs] = *(const bfx8*)(qk + (size_t)qpix * 512 + cs * 32 + lg * 8);

    // stage K [64][256] swizzled
    for (int g = t; g < 64 * 32; g += 256) {
        int row = g >> 5, cg = g & 31;
        int pix = pbase + ((row >> 3) << 4) + (row & 7);
        uint4 v = *(const uint4*)(qk + (size_t)pix * 512 + 256 + cg * 8);
        *(uint4*)(SH + row * 256 + ((cg ^ (row & 7)) << 3)) = v;
    }
    // stage V^T [256][64] swizzled
    for (int g = t; g < 256 * 8; g += 256) {
        int cr = g >> 3, c16 = g & 7;
        const uint_t* drow = (const uint_t*)(vT + (size_t)cr * NPIX);
        uint4 v = ld_u8_align(drow, pbase + (c16 << 4));
        *(uint4*)(SH + 16384 + cr * 64 + ((c16 ^ (cr & 7)) << 3)) = v;
    }
    __syncthreads();

    // S = Q.K^T : S[16 q][64 k]
    f32x4 s[4];
    #pragma unroll
    for (int j = 0; j < 4; j++) s[j] = f32x4{0.f, 0.f, 0.f, 0.f};
    #pragma unroll
    for (int cs = 0; cs < 8; cs++) {
        #pragma unroll
        for (int j = 0; j < 4; j++) {
            int krow = (j << 4) + l15;
            bfx8 kf = *(const bfx8*)(SH + krow * 256 + ((((cs << 2) + lg) ^ (krow & 7)) << 3));
            s[j] = __builtin_amdgcn_mfma_f32_16x16x32_bf16(qf[cs], kf, s[j], 0, 0, 0);
        }
    }
    // softmax (per q row r, across 16-lane key groups)
    float p[4][4], lsum[4];
    #pragma unroll
    for (int r = 0; r < 4; r++) {
        float mx = s[0][r];
        #pragma unroll
        for (int j = 1; j < 4; j++) mx = fmaxf(mx, s[j][r]);
        mx = fmaxf(mx, __shfl_xor(mx, 1));
        mx = fmaxf(mx, __shfl_xor(mx, 2));
        mx = fmaxf(mx, __shfl_xor(mx, 4));
        mx = fmaxf(mx, __shfl_xor(mx, 8));
        float ps = 0.f;
        #pragma unroll
        for (int j = 0; j < 4; j++) {
            p[j][r] = __expf(scale * (s[j][r] - mx));
            ps += p[j][r];
        }
        ps += __shfl_xor(ps, 1);
        ps += __shfl_xor(ps, 2);
        ps += __shfl_xor(ps, 4);
        ps += __shfl_xor(ps, 8);
        lsum[r] = ps;
    }
    __syncthreads();   // all waves done reading K -> P overlays K region
    // P -> LDS (per-wave region, PSTR=68)
    ushort_t* Pw = SH + wv * 1088;
    #pragma unroll
    for (int j = 0; j < 4; j++)
        #pragma unroll
        for (int r = 0; r < 4; r++)
            Pw[(lg * 4 + r) * 68 + (j << 4) + l15] = f2bf(p[j][r]);
    asm volatile("s_waitcnt lgkmcnt(0)" ::: "memory");
    __builtin_amdgcn_sched_barrier(0);
    // O += P.V  (16 channel frags = full 256 ch)
    f32x4 o[16] = {};
    #pragma unroll
    for (int kt = 0; kt < 2; kt++) {
        bfx8 pf = *(const bfx8*)(Pw + l15 * 68 + (kt << 5) + (lg << 3));
        #pragma unroll
        for (int j = 0; j < 16; j++) {
            int cr = (j << 4) + l15;
            int c16 = ((kt << 2) + lg) ^ (cr & 7);
            bfx8 vf = *(const bfx8*)(SH + 16384 + cr * 64 + (c16 << 3));
            o[j] = __builtin_amdgcn_mfma_f32_16x16x32_bf16(pf, vf, o[j], 0, 0, 0);
        }
    }
    asm volatile("s_waitcnt lgkmcnt(0)" ::: "memory");
    __syncthreads();   // all PV done -> epilogue bounce overlays SH
    float inv[4];
    #pragma unroll
    for (int r = 0; r < 4; r++) inv[r] = 1.0f / lsum[r];
    ushort_t* Ep = SH + wv * 4224;   // 16 rows x ESTR 260
    #pragma unroll
    for (int j = 0; j < 16; j++)
        #pragma unroll
        for (int r = 0; r < 4; r++)
            Ep[(lg * 4 + r) * 260 + (j << 4) + l15] = f2bf(o[j][r] * inv[r]);
    asm volatile("s_waitcnt lgkmcnt(0)" ::: "memory");
    __builtin_amdgcn_sched_barrier(0);
    size_t gb = ((size_t)wrel * 64 + qbase) * C_DIM;
    #pragma unroll
    for (int i = 0; i < 8; i++) {
        int off = i * 512 + lane * 8;
        int row = off >> 8, col = off & 255;
        uint4 v = *(const uint4*)(Ep + row * 260 + col);
        *(uint4*)(obuf + gb + off) = v;
    }
}

// ---------------- k=16 attention as 3 batched-GEMM passes over 32 dense seqs ----------------
// PASS 0: S[seq][256 q][256 k] fp32 = Q.K^T   (A=qkb rows, B=qkb K rows)
// PASS 1: O[seq][256 q][256 c] bf16 = P.V^T with 1/lsum row scale -> obuf
template <int PASS>
__global__ __launch_bounds__(256) void gemm_seq(
    const ushort_t* __restrict__ A, const ushort_t* __restrict__ B,
    const float* __restrict__ linv, void* __restrict__ outp)
{
    __shared__ ushort_t sm[8192];    // dbuf stage 2*(64+64)*32; bounce 64*72=4608
    int m0 = blockIdx.x * 64, n0 = blockIdx.y * 64;
    int seq = blockIdx.z;
    int pbase = (seq >> 1) * 272 + (seq & 1) * 16;
    int t = threadIdx.x, lane = t & 63, wv = t >> 6;
    int l15 = lane & 15, lg = lane >> 4;
    int wr = wv >> 1, wc = wv & 1;

    f32x4 acc[2][2] = {};
    uint4 ra, rb;

    int g_row = t >> 2, g_p = t & 3;
    int g_ps = g_p ^ ((g_row >> 1) & 3);

    // per-thread source addresses (row = g_row)
    const ushort_t* Asrc;
    const ushort_t* Bsrc;
    if (PASS == 0) {
        Asrc = A + (size_t)(pbase + m0 + g_row) * 512 + g_ps * 8;
        Bsrc = B + (size_t)(pbase + n0 + g_row) * 512 + 256 + g_ps * 8;
    } else {
        Asrc = A + (size_t)seq * 65536 + (size_t)(m0 + g_row) * 256 + g_ps * 8;
        Bsrc = B + (size_t)(n0 + g_row) * NPIX + pbase + g_ps * 8;
    }

    ra = *(const uint4*)(Asrc);
    rb = *(const uint4*)(Bsrc);
    *(uint4*)(sm + t * 8) = ra;
    *(uint4*)(sm + 2048 + t * 8) = rb;
    __syncthreads();

    for (int ks = 0; ks < 8; ks++) {
        int coff = (ks & 1) * 4096, noff = ((ks & 1) ^ 1) * 4096;
        if (ks + 1 < 8) {
            int k1 = (ks + 1) * 32;
            ra = *(const uint4*)(Asrc + k1);
            rb = *(const uint4*)(Bsrc + k1);
        }
        bfx8 af[2], bf[2];
        #pragma unroll
        for (int i = 0; i < 2; i++) {
            int row = wr * 32 + i * 16 + l15;
            af[i] = *(const bfx8*)(sm + coff + row * 32 + ((lg ^ ((row >> 1) & 3)) << 3));
        }
        #pragma unroll
        for (int j = 0; j < 2; j++) {
            int col = wc * 32 + j * 16 + l15;
            bf[j] = *(const bfx8*)(sm + coff + 2048 + col * 32 + ((lg ^ ((col >> 1) & 3)) << 3));
        }
        #pragma unroll
        for (int i = 0; i < 2; i++)
            #pragma unroll
            for (int j = 0; j < 2; j++)
                acc[i][j] = __builtin_amdgcn_mfma_f32_16x16x32_bf16(af[i], bf[j], acc[i][j], 0, 0, 0);
        if (ks + 1 < 8) {
            *(uint4*)(sm + noff + t * 8) = ra;
            *(uint4*)(sm + noff + 2048 + t * 8) = rb;
        }
        __syncthreads();
    }

    if (PASS == 0) {
        float* S = (float*)outp + (size_t)seq * 65536;
        #pragma unroll
        for (int i = 0; i < 2; i++) {
            #pragma unroll
            for (int j = 0; j < 2; j++) {
                int col = n0 + wc * 32 + j * 16 + l15;
                #pragma unroll
                for (int r = 0; r < 4; r++) {
                    int row = m0 + wr * 32 + i * 16 + lg * 4 + r;
                    S[(size_t)row * 256 + col] = acc[i][j][r];
                }
            }
        }
        return;
    }
    // PASS 1: scale by linv, bf16 bounce, coalesced store to obuf
    ushort_t* ob = (ushort_t*)outp;
    #pragma unroll
    for (int i = 0; i < 2; i++) {
        #pragma unroll
        for (int j = 0; j < 2; j++) {
            int cl = wc * 32 + j * 16 + l15;
            #pragma unroll
            for (int r = 0; r < 4; r++) {
                int rl = wr * 32 + i * 16 + lg * 4 + r;
                float v = acc[i][j][r] * linv[seq * 256 + m0 + rl];
                sm[rl * 72 + cl] = f2bf(v);
            }
        }
    }
    __syncthreads();
    #pragma unroll
    for (int e = 0; e < 4096; e += 2048) {
        int idx = e + t * 8;
        int rl = idx >> 6, cl = idx & 63;
        uint4 v = *(const uint4*)(sm + rl * 72 + cl);
        *(uint4*)&ob[(size_t)seq * 65536 + (size_t)(m0 + rl) * 256 + n0 + cl] = v;
    }
}

// row softmax: S fp32 [8192 rows][256] -> P bf16 + 1/lsum
__global__ __launch_bounds__(256) void rowsm(
    const float* __restrict__ sbuf, ushort_t* __restrict__ pbuf,
    float* __restrict__ linv, float scale)
{
    __shared__ float red[8];
    int r = blockIdx.x, t = threadIdx.x;
    float s = sbuf[(size_t)r * 256 + t];
    float m = s;
    m = fmaxf(m, __shfl_down(m, 32)); m = fmaxf(m, __shfl_down(m, 16));
    m = fmaxf(m, __shfl_down(m, 8));  m = fmaxf(m, __shfl_down(m, 4));
    m = fmaxf(m, __shfl_down(m, 2));  m = fmaxf(m, __shfl_down(m, 1));
    if ((t & 63) == 0) red[t >> 6] = m;
    __syncthreads();
    m = fmaxf(fmaxf(red[0], red[1]), fmaxf(red[2], red[3]));
    float p = __expf(scale * (s - m));
    float ps = p;
    ps += __shfl_down(ps, 32); ps += __shfl_down(ps, 16); ps += __shfl_down(ps, 8);
    ps += __shfl_down(ps, 4);  ps += __shfl_down(ps, 2);  ps += __shfl_down(ps, 1);
    if ((t & 63) == 0) red[4 + (t >> 6)] = ps;
    __syncthreads();
    float sum = red[4] + red[5] + red[6] + red[7];
    pbuf[(size_t)r * 256 + t] = f2bf(p);
    if (t == 0) linv[r] = 1.0f / sum;
}

// ---------------- overlap-add fold + residual (+ optional fused LN2) ----------------
__global__ __launch_bounds__(256) void fold_ln(
    const ushort_t* __restrict__ obuf, const float* __restrict__ xin,
    float* __restrict__ y, const float* __restrict__ lw,
    const float* __restrict__ lb, ushort_t* __restrict__ lnout, int do_ln,
    int k, int Lh, int Lw, int w0, int w1)
{
    __shared__ float red[8];
    int p = blockIdx.x;
    int c = threadIdx.x;
    int b = p / 272;
    int rem = p - b * 272;
    int yy = rem >> 4, xx = rem & 15;
    int L = Lh * Lw;
    int T = k * k;
    float acc = xin ? xin[(size_t)p * C_DIM + c] : y[(size_t)p * C_DIM + c];
    int lh0 = max(0, yy - k + 1), lh1 = min(Lh - 1, yy);
    int lw0 = max(0, xx - k + 1), lw1 = min(Lw - 1, xx);
    for (int lh = lh0; lh <= lh1; lh++) {
        for (int lw = lw0; lw <= lw1; lw++) {
            int widx = b * L + lh * Lw + lw;
            if (widx < w0 || widx >= w1) continue;
            int n = (yy - lh) * k + (xx - lw);
            acc += bf2f(obuf[((size_t)(widx - w0) * T + n) * C_DIM + c]);
        }
    }
    y[(size_t)p * C_DIM + c] = acc;
    if (!do_ln) return;
    float s = acc;
    s += __shfl_down(s, 32); s += __shfl_down(s, 16); s += __shfl_down(s, 8);
    s += __shfl_down(s, 4);  s += __shfl_down(s, 2);  s += __shfl_down(s, 1);
    if ((c & 63) == 0) red[c >> 6] = s;
    __syncthreads();
    float mu = (red[0] + red[1] + red[2] + red[3]) * (1.0f / 256.0f);
    float d = acc - mu;
    float s2 = d * d;
    s2 += __shfl_down(s2, 32); s2 += __shfl_down(s2, 16); s2 += __shfl_down(s2, 8);
    s2 += __shfl_down(s2, 4);  s2 += __shfl_down(s2, 2);  s2 += __shfl_down(s2, 1);
    if ((c & 63) == 0) red[4 + (c >> 6)] = s2;
    __syncthreads();
    float var = (red[4] + red[5] + red[6] + red[7]) * (1.0f / 256.0f);
    lnout[(size_t)p * C_DIM + c] = f2bf(d * rsqrtf(var + 1e-5f) * lw[c] + lb[c]);
}

// ---------------- classifier ----------------
__global__ __launch_bounds__(256) void classifier_k(
    const float* __restrict__ h, const float* __restrict__ cw,
    const float* __restrict__ cb, float* __restrict__ out)
{
    __shared__ float hrow[256];
    int b = blockIdx.x;
    int n = blockIdx.y * 256 + threadIdx.x;
    hrow[threadIdx.x] = h[(size_t)b * 272 * C_DIM + threadIdx.x];
    __syncthreads();
    if (n < 1000) {
        float acc = cb[n];
        const float* wr = cw + (size_t)n * C_DIM;
        for (int c = 0; c < 256; c++) acc += hrow[c] * wr[c];
        out[(size_t)b * 1000 + n] = acc;
    }
}

extern "C" void kernel_launch(void* const* d_in, const int* in_sizes, int n_in,
                              void* d_out, int out_size, void* d_ws, size_t ws_size,
                              hipStream_t stream)
{
    const float* x       = (const float*)d_in[0];
    const float* patch_w = (const float*)d_in[1];
    const float* patch_b = (const float*)d_in[2];
    const float* row_emb = (const float*)d_in[3];
    const float* col_emb = (const float*)d_in[4];
    const float* cls_tok = (const float*)d_in[5];
    const float* ln1_w   = (const float*)d_in[6];
    const float* ln1_b   = (const float*)d_in[7];
    const float* qkv_w   = (const float*)d_in[8];
    const float* ln2_w   = (const float*)d_in[9];
    const float* ln2_b   = (const float*)d_in[10];
    const float* mlp_w1  = (const float*)d_in[11];
    const float* mlp_b1  = (const float*)d_in[12];
    const float* mlp_w2  = (const float*)d_in[13];
    const float* mlp_b2  = (const float*)d_in[14];
    const float* cls_w   = (const float*)d_in[15];
    const float* cls_b   = (const float*)d_in[16];
    float* out = (float*)d_out;

    // workspace layout (all 16B aligned)
    float* xb0  = (float*)d_ws;                          // NPIX*256 f32
    float* xb1  = xb0 + (size_t)NPIX * 256;              // NPIX*256 f32
    ushort_t* lnb = (ushort_t*)(xb1 + (size_t)NPIX * 256);   // NPIX*256 bf16
    ushort_t* qkb = lnb + (size_t)NPIX * 256;            // NPIX*512 bf16 (Q|K)
    ushort_t* vT  = qkb + (size_t)NPIX * 512;            // 256*NPIX bf16
    ushort_t* h1  = vT + (size_t)256 * NPIX;             // NPIX*512 bf16
    ushort_t* wq  = h1 + (size_t)NPIX * 512;             // 7*768*256 bf16
    ushort_t* w1b = wq + (size_t)7 * 768 * 256;          // 7*512*256 bf16
    ushort_t* w2b = w1b + (size_t)7 * 512 * 256;         // 7*256*512 bf16
    float* sbuf   = (float*)(w2b + (size_t)7 * 256 * 512);   // 32*65536 f32 (8 MB)
    ushort_t* pbuf = (ushort_t*)(sbuf + (size_t)32 * 65536); // 32*65536 bf16 (4 MB)
    float* linv   = (float*)(pbuf + (size_t)32 * 65536);     // 8192 f32
    ushort_t* obuf = (ushort_t*)(linv + 8192);               // rest of ws
    size_t obuf_off_bytes = (size_t)((char*)obuf - (char*)d_ws);
    size_t obuf_cap_e = (ws_size > obuf_off_bytes + 64)
                        ? (ws_size - obuf_off_bytes - 64) / 2 : 0;

    conv3_bf16<<<1024, 256, 0, stream>>>(qkv_w, wq, 7 * 768 * 256,
                                         mlp_w1, w1b, 7 * 512 * 256,
                                         mlp_w2, w2b, 7 * 256 * 512);

    patch_embed_ln<<<NPIX, 256, 0, stream>>>(x, patch_w, patch_b, row_emb,
                                             col_emb, cls_tok, ln1_w, ln1_b,
                                             xb0, lnb);

    const int KS[7] = {4, 4, 8, 8, 8, 16, 16};
    float* xcur = xb0;
    float* ybuf = xb1;

    for (int i = 0; i < 7; i++) {
        int k = KS[i];
        int Lh = 18 - k, Lw = 17 - k, L = Lh * Lw, T = k * k;
        float scale = 1.0f / std::sqrt((float)(256 / k));

        if (i > 0)
            layernorm_k<<<NPIX, 256, 0, stream>>>(xcur, ln1_w + i * 256,
                                                  ln1_b + i * 256, lnb);
        // QKV GEMM: M=NPIX, N=768, K=256
        gemm_v2<128, 128, 0><<<dim3(NPIX / 128, 6), 256, 0, stream>>>(
            lnb, wq + (size_t)i * 768 * 256, nullptr, nullptr, qkb, vT, 256, 512);

        if (k == 16) {
            // dense attention over 32 contiguous 256-token sequences
            gemm_seq<0><<<dim3(4, 4, 32), 256, 0, stream>>>(qkb, qkb, nullptr, sbuf);
            rowsm<<<8192, 256, 0, stream>>>(sbuf, pbuf, linv, scale);
            gemm_seq<1><<<dim3(4, 4, 32), 256, 0, stream>>>(pbuf, vT, linv, obuf);
            fold_ln<<<NPIX, 256, 0, stream>>>(obuf, xcur, ybuf,
                                              ln2_w + i * 256, ln2_b + i * 256,
                                              lnb, 1, k, Lh, Lw, 0, 32);
        } else {
            int totalW = 16 * L;
            size_t perW = (size_t)T * C_DIM;
            int maxW = (int)((obuf_cap_e / perW) < (size_t)totalW
                             ? (obuf_cap_e / perW) : (size_t)totalW);
            if (maxW < 2) maxW = 2;
            if (k == 4) maxW &= ~1;
            for (int w0 = 0; w0 < totalW; w0 += maxW) {
                int nW = totalW - w0 < maxW ? totalW - w0 : maxW;
                if (k == 4)
                    attn_v2<4><<<(nW + 1) / 2, 256, 0, stream>>>(qkb, vT, obuf, w0, nW, scale);
                else
                    attn_v3<<<nW, 256, 0, stream>>>(qkb, vT, obuf, w0, scale);
                int last = (w0 + nW >= totalW);
                fold_ln<<<NPIX, 256, 0, stream>>>(obuf, (w0 == 0) ? xcur : nullptr,
                                                  ybuf, ln2_w + i * 256, ln2_b + i * 256,
                                                  lnb, last, k, Lh, Lw, w0, w0 + nW);
            }
        }

        // MLP1 + gelu: M=NPIX, N=512, K=256
        gemm_v2<64, 128, 2><<<dim3(NPIX / 64, 4), 256, 0, stream>>>(
            lnb, w1b + (size_t)i * 512 * 256, mlp_b1 + i * 512, nullptr, h1, nullptr, 256, 512);
        // MLP2 + bias + residual: M=NPIX, N=256, K=512 -> fp32 xcur
        gemm_v2<64, 64, 3><<<dim3(NPIX / 64, 4), 256, 0, stream>>>(
            h1, w2b + (size_t)i * 256 * 512, mlp_b2 + i * 256, ybuf, xcur, nullptr, 512, 256);
    }

    classifier_k<<<dim3(16, 4), 256, 0, stream>>>(xcur, cls_w, cls_b, out);
}

// Round 9
// 644.197 us; speedup vs baseline: 3.4905x; 1.1263x over previous
//
#include <hip/hip_runtime.h>
#include <cmath>

#define NPIX 4352      // 16 * 17 * 16 pixels (incl. cls row)
#define C_DIM 256

typedef unsigned short ushort_t;
typedef unsigned int uint_t;
typedef float f32x4 __attribute__((ext_vector_type(4)));
typedef __bf16 bfx8 __attribute__((ext_vector_type(8)));

__device__ __forceinline__ ushort_t f2bf(float f) {
    uint_t u = __float_as_uint(f);
    u = (u + 0x7FFFu + ((u >> 16) & 1u)) >> 16;
    return (ushort_t)u;
}
__device__ __forceinline__ float bf2f(ushort_t b) {
    return __uint_as_float(((uint_t)b) << 16);
}
__device__ __forceinline__ float gelu_f(float v) {
    return 0.5f * v * (1.0f + erff(v * 0.70710678118654752f));
}

// ---------------- fp32 -> bf16 converter (all 3 weight tensors, 1 launch) ----------------
__global__ __launch_bounds__(256) void conv3_bf16(
    const float* __restrict__ a, ushort_t* __restrict__ oa, int na,
    const float* __restrict__ b, ushort_t* __restrict__ ob, int nb,
    const float* __restrict__ c, ushort_t* __restrict__ oc, int nc)
{
    int ntot = na + nb + nc;
    for (int i = blockIdx.x * 256 + threadIdx.x; i < ntot; i += gridDim.x * 256) {
        if (i < na)            oa[i] = f2bf(a[i]);
        else if (i < na + nb)  ob[i - na] = f2bf(b[i - na]);
        else                   oc[i - na - nb] = f2bf(c[i - na - nb]);
    }
}

// ---------------- patch embed + pos emb + cls row + LN1(layer0) ----------------
__global__ __launch_bounds__(256) void patch_embed_ln(
    const float* __restrict__ x, const float* __restrict__ pw,
    const float* __restrict__ pb, const float* __restrict__ row_emb,
    const float* __restrict__ col_emb, const float* __restrict__ cls_tok,
    const float* __restrict__ lw, const float* __restrict__ lb,
    float* __restrict__ out, ushort_t* __restrict__ lnout)
{
    __shared__ float red[8];
    int p = blockIdx.x;
    int c = threadIdx.x;
    int b = p / 272;
    int rem = p - b * 272;
    int y = rem >> 4;
    int xw = rem & 15;
    float v;
    if (y == 0) {
        v = cls_tok[c];
    } else {
        int gr = y - 1, gc = xw;
        const float* xb = x + (size_t)b * 3 * 1024;
        const float* wc = pw + (size_t)c * 12;
        float acc = pb[c];
        #pragma unroll
        for (int ci = 0; ci < 3; ci++)
            #pragma unroll
            for (int ph = 0; ph < 2; ph++)
                #pragma unroll
                for (int pq = 0; pq < 2; pq++)
                    acc += xb[ci * 1024 + (2 * gr + ph) * 32 + (2 * gc + pq)]
                         * wc[(ci * 2 + ph) * 2 + pq];
        acc += (c < 128) ? row_emb[gr * 128 + c] : col_emb[gc * 128 + (c - 128)];
        v = acc;
    }
    out[(size_t)p * C_DIM + c] = v;
    float s = v;
    s += __shfl_down(s, 32); s += __shfl_down(s, 16); s += __shfl_down(s, 8);
    s += __shfl_down(s, 4);  s += __shfl_down(s, 2);  s += __shfl_down(s, 1);
    if ((c & 63) == 0) red[c >> 6] = s;
    __syncthreads();
    float mu = (red[0] + red[1] + red[2] + red[3]) * (1.0f / 256.0f);
    float d = v - mu;
    float s2 = d * d;
    s2 += __shfl_down(s2, 32); s2 += __shfl_down(s2, 16); s2 += __shfl_down(s2, 8);
    s2 += __shfl_down(s2, 4);  s2 += __shfl_down(s2, 2);  s2 += __shfl_down(s2, 1);
    if ((c & 63) == 0) red[4 + (c >> 6)] = s2;
    __syncthreads();
    float var = (red[4] + red[5] + red[6] + red[7]) * (1.0f / 256.0f);
    lnout[(size_t)p * C_DIM + c] = f2bf(d * rsqrtf(var + 1e-5f) * lw[c] + lb[c]);
}

// ---------------- standalone layernorm: fp32 in -> bf16 out ----------------
__global__ __launch_bounds__(256) void layernorm_k(
    const float* __restrict__ in, const float* __restrict__ w,
    const float* __restrict__ b, ushort_t* __restrict__ out)
{
    __shared__ float red[8];
    int r = blockIdx.x, c = threadIdx.x;
    float v = in[(size_t)r * C_DIM + c];
    float s = v;
    s += __shfl_down(s, 32); s += __shfl_down(s, 16); s += __shfl_down(s, 8);
    s += __shfl_down(s, 4);  s += __shfl_down(s, 2);  s += __shfl_down(s, 1);
    if ((c & 63) == 0) red[c >> 6] = s;
    __syncthreads();
    float mu = (red[0] + red[1] + red[2] + red[3]) * (1.0f / 256.0f);
    float d = v - mu;
    float s2 = d * d;
    s2 += __shfl_down(s2, 32); s2 += __shfl_down(s2, 16); s2 += __shfl_down(s2, 8);
    s2 += __shfl_down(s2, 4);  s2 += __shfl_down(s2, 2);  s2 += __shfl_down(s2, 1);
    if ((c & 63) == 0) red[4 + (c >> 6)] = s2;
    __syncthreads();
    float var = (red[4] + red[5] + red[6] + red[7]) * (1.0f / 256.0f);
    out[(size_t)r * C_DIM + c] = f2bf(d * rsqrtf(var + 1e-5f) * w[c] + b[c]);
}

// ---------------- LDS-staged double-buffered bf16 MFMA GEMM ----------------
template <int BM, int BN, int MODE>
__global__ __launch_bounds__(256) void gemm_v2(
    const ushort_t* __restrict__ A, const ushort_t* __restrict__ B,
    const float* __restrict__ bias, const float* __restrict__ res,
    void* __restrict__ outp, ushort_t* __restrict__ vT, int K, int ldo)
{
    constexpr int MI = BM / 32, NJ = BN / 32;
    constexpr int AG = BM * 4, BG = BN * 4;
    constexpr int AU = AG / 256, BU = BG / 256;
    constexpr int HALF = (BM + BN) * 32;
    constexpr int STAGE_E = 2 * HALF;
    constexpr int BOUNCE_E = BM * (BN + 8);
    constexpr int SMEM_E = (STAGE_E > BOUNCE_E) ? STAGE_E : BOUNCE_E;
    __shared__ ushort_t sm[SMEM_E];

    int m0 = blockIdx.x * BM, n0 = blockIdx.y * BN;
    int t = threadIdx.x, lane = t & 63, wv = t >> 6;
    int l15 = lane & 15, lg = lane >> 4;
    int wr = wv >> 1, wc = wv & 1;

    const int nt = K / 32;
    f32x4 acc[MI][NJ] = {};
    uint4 ra[AU], rb[BU];

    #pragma unroll
    for (int u = 0; u < AU; u++) {
        int g = t + u * 256, row = g >> 2, p = g & 3;
        int ps = p ^ ((row >> 1) & 3);
        ra[u] = *(const uint4*)(A + (size_t)(m0 + row) * K + ps * 8);
    }
    #pragma unroll
    for (int u = 0; u < BU; u++) {
        int g = t + u * 256, col = g >> 2, p = g & 3;
        int ps = p ^ ((col >> 1) & 3);
        rb[u] = *(const uint4*)(B + (size_t)(n0 + col) * K + ps * 8);
    }
    #pragma unroll
    for (int u = 0; u < AU; u++) *(uint4*)(sm + (t + u * 256) * 8) = ra[u];
    #pragma unroll
    for (int u = 0; u < BU; u++) *(uint4*)(sm + BM * 32 + (t + u * 256) * 8) = rb[u];
    __syncthreads();

    for (int ks = 0; ks < nt; ks++) {
        int coff = (ks & 1) * HALF, noff = ((ks & 1) ^ 1) * HALF;
        if (ks + 1 < nt) {
            int k1 = (ks + 1) * 32;
            #pragma unroll
            for (int u = 0; u < AU; u++) {
                int g = t + u * 256, row = g >> 2, p = g & 3;
                int ps = p ^ ((row >> 1) & 3);
                ra[u] = *(const uint4*)(A + (size_t)(m0 + row) * K + k1 + ps * 8);
            }
            #pragma unroll
            for (int u = 0; u < BU; u++) {
                int g = t + u * 256, col = g >> 2, p = g & 3;
                int ps = p ^ ((col >> 1) & 3);
                rb[u] = *(const uint4*)(B + (size_t)(n0 + col) * K + k1 + ps * 8);
            }
        }
        bfx8 af[MI], bf[NJ];
        #pragma unroll
        for (int i = 0; i < MI; i++) {
            int row = wr * (BM / 2) + i * 16 + l15;
            af[i] = *(const bfx8*)(sm + coff + row * 32 + ((lg ^ ((row >> 1) & 3)) << 3));
        }
        #pragma unroll
        for (int j = 0; j < NJ; j++) {
            int col = wc * (BN / 2) + j * 16 + l15;
            bf[j] = *(const bfx8*)(sm + coff + BM * 32 + col * 32 + ((lg ^ ((col >> 1) & 3)) << 3));
        }
        #pragma unroll
        for (int i = 0; i < MI; i++)
            #pragma unroll
            for (int j = 0; j < NJ; j++)
                acc[i][j] = __builtin_amdgcn_mfma_f32_16x16x32_bf16(af[i], bf[j], acc[i][j], 0, 0, 0);
        if (ks + 1 < nt) {
            #pragma unroll
            for (int u = 0; u < AU; u++) *(uint4*)(sm + noff + (t + u * 256) * 8) = ra[u];
            #pragma unroll
            for (int u = 0; u < BU; u++) *(uint4*)(sm + noff + BM * 32 + (t + u * 256) * 8) = rb[u];
        }
        __syncthreads();
    }

    if (MODE == 0 && n0 >= 512) {
        #pragma unroll
        for (int i = 0; i < MI; i++) {
            int mb = m0 + wr * (BM / 2) + i * 16 + lg * 4;
            #pragma unroll
            for (int j = 0; j < NJ; j++) {
                int nv = n0 - 512 + wc * (BN / 2) + j * 16 + l15;
                ushort4 pk;
                pk.x = f2bf(acc[i][j][0]); pk.y = f2bf(acc[i][j][1]);
                pk.z = f2bf(acc[i][j][2]); pk.w = f2bf(acc[i][j][3]);
                *(ushort4*)&vT[(size_t)nv * NPIX + mb] = pk;
            }
        }
        return;
    }
    if (MODE == 3) {
        float* o = (float*)outp;
        #pragma unroll
        for (int i = 0; i < MI; i++) {
            #pragma unroll
            for (int j = 0; j < NJ; j++) {
                int col = n0 + wc * (BN / 2) + j * 16 + l15;
                float bz = bias[col];
                #pragma unroll
                for (int r = 0; r < 4; r++) {
                    int row = m0 + wr * (BM / 2) + i * 16 + lg * 4 + r;
                    o[(size_t)row * ldo + col] = acc[i][j][r] + bz + res[(size_t)row * ldo + col];
                }
            }
        }
        return;
    }
    __syncthreads();
    #pragma unroll
    for (int i = 0; i < MI; i++) {
        #pragma unroll
        for (int j = 0; j < NJ; j++) {
            int cl = wc * (BN / 2) + j * 16 + l15;
            float bz = (MODE == 2) ? bias[n0 + cl] : 0.0f;
            #pragma unroll
            for (int r = 0; r < 4; r++) {
                int rl = wr * (BM / 2) + i * 16 + lg * 4 + r;
                float v = acc[i][j][r];
                if (MODE == 2) v = gelu_f(v + bz);
                sm[rl * (BN + 8) + cl] = f2bf(v);
            }
        }
    }
    __syncthreads();
    ushort_t* ob = (ushort_t*)outp;
    #pragma unroll
    for (int e = 0; e < BM * BN; e += 2048) {
        int idx = e + t * 8;
        int rl = idx / BN, cl = idx % BN;
        uint4 v = *(const uint4*)(sm + rl * (BN + 8) + cl);
        *(uint4*)&ob[(size_t)(m0 + rl) * ldo + n0 + cl] = v;
    }
}

// unaligned (element-granular) loaders from a dword-aligned row
__device__ __forceinline__ uint2 ld_u4_align(const uint_t* drow, int e0) {
    int d0 = e0 >> 1;
    if (!(e0 & 1)) return make_uint2(drow[d0], drow[d0 + 1]);
    uint_t a = drow[d0], b = drow[d0 + 1], c = drow[d0 + 2];
    return make_uint2((a >> 16) | (b << 16), (b >> 16) | (c << 16));
}
__device__ __forceinline__ uint4 ld_u8_align(const uint_t* drow, int e0) {
    int d0 = e0 >> 1;
    if (!(e0 & 1)) return make_uint4(drow[d0], drow[d0 + 1], drow[d0 + 2], drow[d0 + 3]);
    uint_t a = drow[d0], b = drow[d0 + 1], c = drow[d0 + 2], d = drow[d0 + 3], e = drow[d0 + 4];
    return make_uint4((a >> 16) | (b << 16), (b >> 16) | (c << 16),
                      (c >> 16) | (d << 16), (d >> 16) | (e << 16));
}

// ---------------- k=4 LDS-staged attention ----------------
template <int KK>
__global__ __launch_bounds__(256) void attn_v2(
    const ushort_t* __restrict__ qk, const ushort_t* __restrict__ vT,
    ushort_t* __restrict__ obuf, int w0, int nW, float scale)
{
    constexpr int T = KK * KK;
    constexpr int Lh = 18 - KK, Lw = 17 - KK, L = Lh * Lw;
    constexpr int NF   = 1;
    constexpr int NJ   = 8;
    constexpr int PSTR = 40;
    constexpr int KROWS = 32;
    constexpr int VROWS = 256;
    constexpr int EOFF = 2048;
    constexpr int ESTR = 128;

    __shared__ ushort_t Klds[KROWS * 256];
    __shared__ ushort_t Vlds[VROWS * 64];
    __shared__ ushort_t Plds[4][16 * PSTR];

    int t = threadIdx.x, lane = t & 63, wv = t >> 6;
    int l15 = lane & 15, lg = lane >> 4;

    int wrel = blockIdx.x * 2 + (wv & 1);
    int wloc = wv & 1, chalf = wv >> 1, qbase = 0;
    if (wrel >= nW) wrel = nW - 1;

    int pbs[2];
    #pragma unroll
    for (int w = 0; w < 2; w++) {
        int wi = blockIdx.x * 2 + w;
        if (wi >= nW) wi = nW - 1;
        wi += w0;
        int b = wi / L, lrem = wi % L;
        pbs[w] = b * 272 + (lrem / Lw) * 16 + (lrem % Lw);
    }

    int qtok = qbase + l15;
    int qpix = pbs[wloc] + ((qtok >> 2) << 4) + (qtok & 3);
    bfx8 qf[8];
    #pragma unroll
    for (int cs = 0; cs < 8; cs++)
        qf[cs] = *(const bfx8*)(qk + (size_t)qpix * 512 + cs * 32 + lg * 8);

    f32x4 o[NJ] = {};
    float lsum[4] = {0.f, 0.f, 0.f, 0.f};

    for (int g = t; g < KROWS * 32; g += 256) {
        int row = g >> 5, cg = g & 31;
        int pix = pbs[row >> 4] + (((row & 15) >> 2) << 4) + (row & 3);
        uint4 v = *(const uint4*)(qk + (size_t)pix * 512 + 256 + cg * 8);
        *(uint4*)(Klds + row * 256 + ((cg ^ (row & 7)) << 3)) = v;
    }
    for (int g = t; g < VROWS * 8; g += 256) {
        int cr = g >> 3, c16 = g & 7;
        const uint_t* drow = (const uint_t*)(vT + (size_t)cr * NPIX);
        uint4 v;
        int w = c16 >> 2, sub = c16 & 3;
        if (sub < 2) {
            int pix0 = pbs[w] + (sub << 5);
            uint2 a  = ld_u4_align(drow, pix0);
            uint2 b2 = ld_u4_align(drow, pix0 + 16);
            v = make_uint4(a.x, a.y, b2.x, b2.y);
        } else v = make_uint4(0, 0, 0, 0);
        *(uint4*)(Vlds + cr * 64 + ((c16 ^ (cr & 7)) << 3)) = v;
    }
    __syncthreads();
    f32x4 s[NF];
    #pragma unroll
    for (int j = 0; j < NF; j++) s[j] = f32x4{0.f, 0.f, 0.f, 0.f};
    #pragma unroll
    for (int cs = 0; cs < 8; cs++) {
        int krow = (wloc << 4) + l15;
        bfx8 kf = *(const bfx8*)(Klds + krow * 256 + ((((cs << 2) + lg) ^ (krow & 7)) << 3));
        s[0] = __builtin_amdgcn_mfma_f32_16x16x32_bf16(qf[cs], kf, s[0], 0, 0, 0);
    }
    float p[NF][4];
    #pragma unroll
    for (int r = 0; r < 4; r++) {
        float mx = s[0][r];
        mx = fmaxf(mx, __shfl_xor(mx, 1));
        mx = fmaxf(mx, __shfl_xor(mx, 2));
        mx = fmaxf(mx, __shfl_xor(mx, 4));
        mx = fmaxf(mx, __shfl_xor(mx, 8));
        float ps = 0.f;
        p[0][r] = __expf(scale * (s[0][r] - mx));
        ps += p[0][r];
        ps += __shfl_xor(ps, 1);
        ps += __shfl_xor(ps, 2);
        ps += __shfl_xor(ps, 4);
        ps += __shfl_xor(ps, 8);
        lsum[r] = ps;
    }
    ushort_t* Pw = Plds[wv];
    #pragma unroll
    for (int r = 0; r < 4; r++) {
        Pw[(lg * 4 + r) * PSTR + l15] = f2bf(p[0][r]);
        Pw[(lg * 4 + r) * PSTR + 16 + l15] = 0;
    }
    asm volatile("s_waitcnt lgkmcnt(0)" ::: "memory");
    __builtin_amdgcn_sched_barrier(0);
    {
        bfx8 pf = *(const bfx8*)(Pw + l15 * PSTR + (lg << 3));
        #pragma unroll
        for (int j = 0; j < NJ; j++) {
            int cr = chalf * 128 + (j << 4) + l15;
            int c16 = ((wloc << 2) + lg) ^ (cr & 7);
            bfx8 vf = *(const bfx8*)(Vlds + cr * 64 + (c16 << 3));
            o[j] = __builtin_amdgcn_mfma_f32_16x16x32_bf16(pf, vf, o[j], 0, 0, 0);
        }
    }
    asm volatile("s_waitcnt lgkmcnt(0)" ::: "memory");
    __syncthreads();
    float inv[4];
    #pragma unroll
    for (int r = 0; r < 4; r++) inv[r] = 1.0f / lsum[r];
    ushort_t* Ep = Klds + wv * EOFF;
    #pragma unroll
    for (int j = 0; j < NJ; j++)
        #pragma unroll
        for (int r = 0; r < 4; r++)
            Ep[(lg * 4 + r) * ESTR + (j << 4) + l15] = f2bf(o[j][r] * inv[r]);
    asm volatile("s_waitcnt lgkmcnt(0)" ::: "memory");
    __builtin_amdgcn_sched_barrier(0);
    size_t gb = ((size_t)wrel * T + qbase) * C_DIM + chalf * 128;
    #pragma unroll
    for (int i = 0; i < 4; i++) {
        int off = i * 512 + lane * 8;
        int row = off >> 7, col = off & 127;
        uint4 v = *(const uint4*)(Ep + row * ESTR + col);
        *(uint4*)(obuf + gb + (size_t)row * C_DIM + col) = v;
    }
}

// ---------------- k=8 attention v3: one block per window, full 256 ch ----------------
__global__ __launch_bounds__(256) void attn_v3(
    const ushort_t* __restrict__ qk, const ushort_t* __restrict__ vT,
    ushort_t* __restrict__ obuf, int w0, float scale)
{
    __shared__ ushort_t SH[32768];    // 64 KB
    const int Lw = 9, L = 90;
    int t = threadIdx.x, lane = t & 63, wv = t >> 6;
    int l15 = lane & 15, lg = lane >> 4;
    int wrel = blockIdx.x;
    int widx = w0 + wrel;
    int b = widx / L, lrem = widx % L;
    int pbase = b * 272 + (lrem / Lw) * 16 + (lrem % Lw);
    int qbase = wv * 16;

    int qtok = qbase + l15;
    int qpix = pbase + ((qtok >> 3) << 4) + (qtok & 7);
    bfx8 qf[8];
    #pragma unroll
    for (int cs = 0; cs < 8; cs++)
        qf[cs] = *(const bfx8*)(qk + (size_t)qpix * 512 + cs * 32 + lg * 8);

    for (int g = t; g < 64 * 32; g += 256) {
        int row = g >> 5, cg = g & 31;
        int pix = pbase + ((row >> 3) << 4) + (row & 7);
        uint4 v = *(const uint4*)(qk + (size_t)pix * 512 + 256 + cg * 8);
        *(uint4*)(SH + row * 256 + ((cg ^ (row & 7)) << 3)) = v;
    }
    for (int g = t; g < 256 * 8; g += 256) {
        int cr = g >> 3, c16 = g & 7;
        const uint_t* drow = (const uint_t*)(vT + (size_t)cr * NPIX);
        uint4 v = ld_u8_align(drow, pbase + (c16 << 4));
        *(uint4*)(SH + 16384 + cr * 64 + ((c16 ^ (cr & 7)) << 3)) = v;
    }
    __syncthreads();

    f32x4 s[4];
    #pragma unroll
    for (int j = 0; j < 4; j++) s[j] = f32x4{0.f, 0.f, 0.f, 0.f};
    #pragma unroll
    for (int cs = 0; cs < 8; cs++) {
        #pragma unroll
        for (int j = 0; j < 4; j++) {
            int krow = (j << 4) + l15;
            bfx8 kf = *(const bfx8*)(SH + krow * 256 + ((((cs << 2) + lg) ^ (krow & 7)) << 3));
            s[j] = __builtin_amdgcn_mfma_f32_16x16x32_bf16(qf[cs], kf, s[j], 0, 0, 0);
        }
    }
    float p[4][4], lsum[4];
    #pragma unroll
    for (int r = 0; r < 4; r++) {
        float mx = s[0][r];
        #pragma unroll
        for (int j = 1; j < 4; j++) mx = fmaxf(mx, s[j][r]);
        mx = fmaxf(mx, __shfl_xor(mx, 1));
        mx = fmaxf(mx, __shfl_xor(mx, 2));
        mx = fmaxf(mx, __shfl_xor(mx, 4));
        mx = fmaxf(mx, __shfl_xor(mx, 8));
        float ps = 0.f;
        #pragma unroll
        for (int j = 0; j < 4; j++) {
            p[j][r] = __expf(scale * (s[j][r] - mx));
            ps += p[j][r];
        }
        ps += __shfl_xor(ps, 1);
        ps += __shfl_xor(ps, 2);
        ps += __shfl_xor(ps, 4);
        ps += __shfl_xor(ps, 8);
        lsum[r] = ps;
    }
    __syncthreads();
    ushort_t* Pw = SH + wv * 1088;
    #pragma unroll
    for (int j = 0; j < 4; j++)
        #pragma unroll
        for (int r = 0; r < 4; r++)
            Pw[(lg * 4 + r) * 68 + (j << 4) + l15] = f2bf(p[j][r]);
    asm volatile("s_waitcnt lgkmcnt(0)" ::: "memory");
    __builtin_amdgcn_sched_barrier(0);
    f32x4 o[16] = {};
    #pragma unroll
    for (int kt = 0; kt < 2; kt++) {
        bfx8 pf = *(const bfx8*)(Pw + l15 * 68 + (kt << 5) + (lg << 3));
        #pragma unroll
        for (int j = 0; j < 16; j++) {
            int cr = (j << 4) + l15;
            int c16 = ((kt << 2) + lg) ^ (cr & 7);
            bfx8 vf = *(const bfx8*)(SH + 16384 + cr * 64 + (c16 << 3));
            o[j] = __builtin_amdgcn_mfma_f32_16x16x32_bf16(pf, vf, o[j], 0, 0, 0);
        }
    }
    asm volatile("s_waitcnt lgkmcnt(0)" ::: "memory");
    __syncthreads();
    float inv[4];
    #pragma unroll
    for (int r = 0; r < 4; r++) inv[r] = 1.0f / lsum[r];
    ushort_t* Ep = SH + wv * 4224;
    #pragma unroll
    for (int j = 0; j < 16; j++)
        #pragma unroll
        for (int r = 0; r < 4; r++)
            Ep[(lg * 4 + r) * 260 + (j << 4) + l15] = f2bf(o[j][r] * inv[r]);
    asm volatile("s_waitcnt lgkmcnt(0)" ::: "memory");
    __builtin_amdgcn_sched_barrier(0);
    size_t gb = ((size_t)wrel * 64 + qbase) * C_DIM;
    #pragma unroll
    for (int i = 0; i < 8; i++) {
        int off = i * 512 + lane * 8;
        int row = off >> 8, col = off & 255;
        uint4 v = *(const uint4*)(Ep + row * 260 + col);
        *(uint4*)(obuf + gb + off) = v;
    }
}

// ---------------- k=16 attention as batched-GEMM passes over 32 dense seqs ----------------
template <int PASS>
__global__ __launch_bounds__(256) void gemm_seq(
    const ushort_t* __restrict__ A, const ushort_t* __restrict__ B,
    const float* __restrict__ linv, void* __restrict__ outp)
{
    __shared__ ushort_t sm[8192];
    int m0 = blockIdx.x * 64, n0 = blockIdx.y * 64;
    int seq = blockIdx.z;
    int pbase = (seq >> 1) * 272 + (seq & 1) * 16;
    int t = threadIdx.x, lane = t & 63, wv = t >> 6;
    int l15 = lane & 15, lg = lane >> 4;
    int wr = wv >> 1, wc = wv & 1;

    f32x4 acc[2][2] = {};
    uint4 ra, rb;

    int g_row = t >> 2, g_p = t & 3;
    int g_ps = g_p ^ ((g_row >> 1) & 3);

    const ushort_t* Asrc;
    const ushort_t* Bsrc;
    if (PASS == 0) {
        Asrc = A + (size_t)(pbase + m0 + g_row) * 512 + g_ps * 8;
        Bsrc = B + (size_t)(pbase + n0 + g_row) * 512 + 256 + g_ps * 8;
    } else {
        Asrc = A + (size_t)seq * 65536 + (size_t)(m0 + g_row) * 256 + g_ps * 8;
        Bsrc = B + (size_t)(n0 + g_row) * NPIX + pbase + g_ps * 8;
    }

    ra = *(const uint4*)(Asrc);
    rb = *(const uint4*)(Bsrc);
    *(uint4*)(sm + t * 8) = ra;
    *(uint4*)(sm + 2048 + t * 8) = rb;
    __syncthreads();

    for (int ks = 0; ks < 8; ks++) {
        int coff = (ks & 1) * 4096, noff = ((ks & 1) ^ 1) * 4096;
        if (ks + 1 < 8) {
            int k1 = (ks + 1) * 32;
            ra = *(const uint4*)(Asrc + k1);
            rb = *(const uint4*)(Bsrc + k1);
        }
        bfx8 af[2], bf[2];
        #pragma unroll
        for (int i = 0; i < 2; i++) {
            int row = wr * 32 + i * 16 + l15;
            af[i] = *(const bfx8*)(sm + coff + row * 32 + ((lg ^ ((row >> 1) & 3)) << 3));
        }
        #pragma unroll
        for (int j = 0; j < 2; j++) {
            int col = wc * 32 + j * 16 + l15;
            bf[j] = *(const bfx8*)(sm + coff + 2048 + col * 32 + ((lg ^ ((col >> 1) & 3)) << 3));
        }
        #pragma unroll
        for (int i = 0; i < 2; i++)
            #pragma unroll
            for (int j = 0; j < 2; j++)
                acc[i][j] = __builtin_amdgcn_mfma_f32_16x16x32_bf16(af[i], bf[j], acc[i][j], 0, 0, 0);
        if (ks + 1 < 8) {
            *(uint4*)(sm + noff + t * 8) = ra;
            *(uint4*)(sm + noff + 2048 + t * 8) = rb;
        }
        __syncthreads();
    }

    if (PASS == 0) {
        float* S = (float*)outp + (size_t)seq * 65536;
        #pragma unroll
        for (int i = 0; i < 2; i++) {
            #pragma unroll
            for (int j = 0; j < 2; j++) {
                int col = n0 + wc * 32 + j * 16 + l15;
                #pragma unroll
                for (int r = 0; r < 4; r++) {
                    int row = m0 + wr * 32 + i * 16 + lg * 4 + r;
                    S[(size_t)row * 256 + col] = acc[i][j][r];
                }
            }
        }
        return;
    }
    ushort_t* ob = (ushort_t*)outp;
    #pragma unroll
    for (int i = 0; i < 2; i++) {
        #pragma unroll
        for (int j = 0; j < 2; j++) {
            int cl = wc * 32 + j * 16 + l15;
            #pragma unroll
            for (int r = 0; r < 4; r++) {
                int rl = wr * 32 + i * 16 + lg * 4 + r;
                float v = acc[i][j][r] * linv[seq * 256 + m0 + rl];
                sm[rl * 72 + cl] = f2bf(v);
            }
        }
    }
    __syncthreads();
    #pragma unroll
    for (int e = 0; e < 4096; e += 2048) {
        int idx = e + t * 8;
        int rl = idx >> 6, cl = idx & 63;
        uint4 v = *(const uint4*)(sm + rl * 72 + cl);
        *(uint4*)&ob[(size_t)seq * 65536 + (size_t)(m0 + rl) * 256 + n0 + cl] = v;
    }
}

// row softmax: S fp32 [8192 rows][256] -> P bf16 + 1/lsum
__global__ __launch_bounds__(256) void rowsm(
    const float* __restrict__ sbuf, ushort_t* __restrict__ pbuf,
    float* __restrict__ linv, float scale)
{
    __shared__ float red[8];
    int r = blockIdx.x, t = threadIdx.x;
    float s = sbuf[(size_t)r * 256 + t];
    float m = s;
    m = fmaxf(m, __shfl_down(m, 32)); m = fmaxf(m, __shfl_down(m, 16));
    m = fmaxf(m, __shfl_down(m, 8));  m = fmaxf(m, __shfl_down(m, 4));
    m = fmaxf(m, __shfl_down(m, 2));  m = fmaxf(m, __shfl_down(m, 1));
    if ((t & 63) == 0) red[t >> 6] = m;
    __syncthreads();
    m = fmaxf(fmaxf(red[0], red[1]), fmaxf(red[2], red[3]));
    float p = __expf(scale * (s - m));
    float ps = p;
    ps += __shfl_down(ps, 32); ps += __shfl_down(ps, 16); ps += __shfl_down(ps, 8);
    ps += __shfl_down(ps, 4);  ps += __shfl_down(ps, 2);  ps += __shfl_down(ps, 1);
    if ((t & 63) == 0) red[4 + (t >> 6)] = ps;
    __syncthreads();
    float sum = red[4] + red[5] + red[6] + red[7];
    pbuf[(size_t)r * 256 + t] = f2bf(p);
    if (t == 0) linv[r] = 1.0f / sum;
}

// ---------------- separable fold stage A: horizontal overlap-add ----------------
// rowsum[b][lh][dy][x][c] = sum_dx obuf[(b*L + lh*Lw + lw)][dy*K+dx][c], x = lw+dx
template <int K>
__global__ __launch_bounds__(256) void foldA(
    const ushort_t* __restrict__ obuf, float* __restrict__ rowsum)
{
    constexpr int Lh = 18 - K, Lw = 17 - K, L = Lh * Lw, T = K * K;
    int c = threadIdx.x;
    int bid = blockIdx.x;            // ((b*Lh + lh)*K + dy)
    int dy = bid % K;
    int blh = bid / K;
    int lh = blh % Lh;
    int b = blh / Lh;
    float acc[16];
    #pragma unroll
    for (int x = 0; x < 16; x++) acc[x] = 0.f;
    const ushort_t* base = obuf + ((size_t)(b * L + lh * Lw) * T + dy * K) * C_DIM + c;
    #pragma unroll
    for (int lw = 0; lw < Lw; lw++)
        #pragma unroll
        for (int dx = 0; dx < K; dx++)
            acc[lw + dx] += bf2f(base[((size_t)lw * T + dx) * C_DIM]);
    float* orow = rowsum + (size_t)bid * 16 * C_DIM + c;
    #pragma unroll
    for (int x = 0; x < 16; x++) orow[(size_t)x * C_DIM] = acc[x];
}

// ---------------- separable fold stage B: vertical + residual + fused LN2 ----------------
template <int K>
__global__ __launch_bounds__(256) void foldB(
    const float* __restrict__ rowsum, const float* __restrict__ xin,
    float* __restrict__ y, const float* __restrict__ lw_,
    const float* __restrict__ lb_, ushort_t* __restrict__ lnout)
{
    constexpr int Lh = 18 - K;
    __shared__ float red[8];
    int p = blockIdx.x, c = threadIdx.x;
    int b = p / 272, rem = p - b * 272;
    int yy = rem >> 4, xx = rem & 15;
    float acc = xin[(size_t)p * C_DIM + c];
    #pragma unroll
    for (int dy = 0; dy < K; dy++) {
        int lh = yy - dy;
        if (lh >= 0 && lh < Lh)
            acc += rowsum[(((size_t)(b * Lh + lh) * K + dy) * 16 + xx) * C_DIM + c];
    }
    y[(size_t)p * C_DIM + c] = acc;
    float s = acc;
    s += __shfl_down(s, 32); s += __shfl_down(s, 16); s += __shfl_down(s, 8);
    s += __shfl_down(s, 4);  s += __shfl_down(s, 2);  s += __shfl_down(s, 1);
    if ((c & 63) == 0) red[c >> 6] = s;
    __syncthreads();
    float mu = (red[0] + red[1] + red[2] + red[3]) * (1.0f / 256.0f);
    float d = acc - mu;
    float s2 = d * d;
    s2 += __shfl_down(s2, 32); s2 += __shfl_down(s2, 16); s2 += __shfl_down(s2, 8);
    s2 += __shfl_down(s2, 4);  s2 += __shfl_down(s2, 2);  s2 += __shfl_down(s2, 1);
    if ((c & 63) == 0) red[4 + (c >> 6)] = s2;
    __syncthreads();
    float var = (red[4] + red[5] + red[6] + red[7]) * (1.0f / 256.0f);
    lnout[(size_t)p * C_DIM + c] = f2bf(d * rsqrtf(var + 1e-5f) * lw_[c] + lb_[c]);
}

// ---------------- overlap-add fold + residual (+ optional fused LN2) — k=16 / fallback ----------------
__global__ __launch_bounds__(256) void fold_ln(
    const ushort_t* __restrict__ obuf, const float* __restrict__ xin,
    float* __restrict__ y, const float* __restrict__ lw,
    const float* __restrict__ lb, ushort_t* __restrict__ lnout, int do_ln,
    int k, int Lh, int Lw, int w0, int w1)
{
    __shared__ float red[8];
    int p = blockIdx.x;
    int c = threadIdx.x;
    int b = p / 272;
    int rem = p - b * 272;
    int yy = rem >> 4, xx = rem & 15;
    int L = Lh * Lw;
    int T = k * k;
    float acc = xin ? xin[(size_t)p * C_DIM + c] : y[(size_t)p * C_DIM + c];
    int lh0 = max(0, yy - k + 1), lh1 = min(Lh - 1, yy);
    int lw0 = max(0, xx - k + 1), lw1 = min(Lw - 1, xx);
    for (int lh = lh0; lh <= lh1; lh++) {
        for (int lw = lw0; lw <= lw1; lw++) {
            int widx = b * L + lh * Lw + lw;
            if (widx < w0 || widx >= w1) continue;
            int n = (yy - lh) * k + (xx - lw);
            acc += bf2f(obuf[((size_t)(widx - w0) * T + n) * C_DIM + c]);
        }
    }
    y[(size_t)p * C_DIM + c] = acc;
    if (!do_ln) return;
    float s = acc;
    s += __shfl_down(s, 32); s += __shfl_down(s, 16); s += __shfl_down(s, 8);
    s += __shfl_down(s, 4);  s += __shfl_down(s, 2);  s += __shfl_down(s, 1);
    if ((c & 63) == 0) red[c >> 6] = s;
    __syncthreads();
    float mu = (red[0] + red[1] + red[2] + red[3]) * (1.0f / 256.0f);
    float d = acc - mu;
    float s2 = d * d;
    s2 += __shfl_down(s2, 32); s2 += __shfl_down(s2, 16); s2 += __shfl_down(s2, 8);
    s2 += __shfl_down(s2, 4);  s2 += __shfl_down(s2, 2);  s2 += __shfl_down(s2, 1);
    if ((c & 63) == 0) red[4 + (c >> 6)] = s2;
    __syncthreads();
    float var = (red[4] + red[5] + red[6] + red[7]) * (1.0f / 256.0f);
    lnout[(size_t)p * C_DIM + c] = f2bf(d * rsqrtf(var + 1e-5f) * lw[c] + lb[c]);
}

// ---------------- classifier ----------------
__global__ __launch_bounds__(256) void classifier_k(
    const float* __restrict__ h, const float* __restrict__ cw,
    const float* __restrict__ cb, float* __restrict__ out)
{
    __shared__ float hrow[256];
    int b = blockIdx.x;
    int n = blockIdx.y * 256 + threadIdx.x;
    hrow[threadIdx.x] = h[(size_t)b * 272 * C_DIM + threadIdx.x];
    __syncthreads();
    if (n < 1000) {
        float acc = cb[n];
        const float* wr = cw + (size_t)n * C_DIM;
        for (int c = 0; c < 256; c++) acc += hrow[c] * wr[c];
        out[(size_t)b * 1000 + n] = acc;
    }
}

extern "C" void kernel_launch(void* const* d_in, const int* in_sizes, int n_in,
                              void* d_out, int out_size, void* d_ws, size_t ws_size,
                              hipStream_t stream)
{
    const float* x       = (const float*)d_in[0];
    const float* patch_w = (const float*)d_in[1];
    const float* patch_b = (const float*)d_in[2];
    const float* row_emb = (const float*)d_in[3];
    const float* col_emb = (const float*)d_in[4];
    const float* cls_tok = (const float*)d_in[5];
    const float* ln1_w   = (const float*)d_in[6];
    const float* ln1_b   = (const float*)d_in[7];
    const float* qkv_w   = (const float*)d_in[8];
    const float* ln2_w   = (const float*)d_in[9];
    const float* ln2_b   = (const float*)d_in[10];
    const float* mlp_w1  = (const float*)d_in[11];
    const float* mlp_b1  = (const float*)d_in[12];
    const float* mlp_w2  = (const float*)d_in[13];
    const float* mlp_b2  = (const float*)d_in[14];
    const float* cls_w   = (const float*)d_in[15];
    const float* cls_b   = (const float*)d_in[16];
    float* out = (float*)d_out;

    // workspace layout (all 16B aligned)
    float* xb0  = (float*)d_ws;                          // NPIX*256 f32
    float* xb1  = xb0 + (size_t)NPIX * 256;              // NPIX*256 f32
    ushort_t* lnb = (ushort_t*)(xb1 + (size_t)NPIX * 256);   // NPIX*256 bf16
    ushort_t* qkb = lnb + (size_t)NPIX * 256;            // NPIX*512 bf16 (Q|K)
    ushort_t* vT  = qkb + (size_t)NPIX * 512;            // 256*NPIX bf16
    ushort_t* h1  = vT + (size_t)256 * NPIX;             // NPIX*512 bf16
    ushort_t* wq  = h1 + (size_t)NPIX * 512;             // 7*768*256 bf16
    ushort_t* w1b = wq + (size_t)7 * 768 * 256;          // 7*512*256 bf16
    ushort_t* w2b = w1b + (size_t)7 * 512 * 256;         // 7*256*512 bf16
    // scratch region: rowsum (k<=8 separable fold, fp32, max 16*10*8*16*256 = 5.24M)
    // aliased with sbuf/pbuf/linv (k=16 dense path, 12.03MB < 21MB)
    float* scratch = (float*)(w2b + (size_t)7 * 256 * 512);
    float* rowsum  = scratch;                                 // 5,242,880 f32 (21MB)
    float* sbuf    = scratch;                                 // 32*65536 f32 (8MB)
    ushort_t* pbuf = (ushort_t*)(sbuf + (size_t)32 * 65536);  // 32*65536 bf16 (4MB)
    float* linv    = (float*)(pbuf + (size_t)32 * 65536);     // 8192 f32
    ushort_t* obuf = (ushort_t*)(rowsum + 5242880);           // rest of ws
    size_t obuf_off_bytes = (size_t)((char*)obuf - (char*)d_ws);
    size_t obuf_cap_e = (ws_size > obuf_off_bytes + 64)
                        ? (ws_size - obuf_off_bytes - 64) / 2 : 0;

    conv3_bf16<<<1024, 256, 0, stream>>>(qkv_w, wq, 7 * 768 * 256,
                                         mlp_w1, w1b, 7 * 512 * 256,
                                         mlp_w2, w2b, 7 * 256 * 512);

    patch_embed_ln<<<NPIX, 256, 0, stream>>>(x, patch_w, patch_b, row_emb,
                                             col_emb, cls_tok, ln1_w, ln1_b,
                                             xb0, lnb);

    const int KS[7] = {4, 4, 8, 8, 8, 16, 16};
    float* xcur = xb0;
    float* ybuf = xb1;

    for (int i = 0; i < 7; i++) {
        int k = KS[i];
        int Lh = 18 - k, Lw = 17 - k, L = Lh * Lw, T = k * k;
        float scale = 1.0f / std::sqrt((float)(256 / k));

        if (i > 0)
            layernorm_k<<<NPIX, 256, 0, stream>>>(xcur, ln1_w + i * 256,
                                                  ln1_b + i * 256, lnb);
        // QKV GEMM: M=NPIX, N=768, K=256
        gemm_v2<128, 128, 0><<<dim3(NPIX / 128, 6), 256, 0, stream>>>(
            lnb, wq + (size_t)i * 768 * 256, nullptr, nullptr, qkb, vT, 256, 512);

        int totalW = 16 * L;
        if (k == 16) {
            // dense attention over 32 contiguous 256-token sequences
            gemm_seq<0><<<dim3(4, 4, 32), 256, 0, stream>>>(qkb, qkb, nullptr, sbuf);
            rowsm<<<8192, 256, 0, stream>>>(sbuf, pbuf, linv, scale);
            gemm_seq<1><<<dim3(4, 4, 32), 256, 0, stream>>>(pbuf, vT, linv, obuf);
            fold_ln<<<NPIX, 256, 0, stream>>>(obuf, xcur, ybuf,
                                              ln2_w + i * 256, ln2_b + i * 256,
                                              lnb, 1, k, Lh, Lw, 0, 32);
        } else if ((size_t)totalW * T * C_DIM <= obuf_cap_e) {
            // single-chunk attention + separable fold
            if (k == 4) {
                attn_v2<4><<<(totalW + 1) / 2, 256, 0, stream>>>(qkb, vT, obuf, 0, totalW, scale);
                foldA<4><<<16 * 14 * 4, 256, 0, stream>>>(obuf, rowsum);
                foldB<4><<<NPIX, 256, 0, stream>>>(rowsum, xcur, ybuf,
                                                   ln2_w + i * 256, ln2_b + i * 256, lnb);
            } else {
                attn_v3<<<totalW, 256, 0, stream>>>(qkb, vT, obuf, 0, scale);
                foldA<8><<<16 * 10 * 8, 256, 0, stream>>>(obuf, rowsum);
                foldB<8><<<NPIX, 256, 0, stream>>>(rowsum, xcur, ybuf,
                                                   ln2_w + i * 256, ln2_b + i * 256, lnb);
            }
        } else {
            // fallback: chunked attention + direct fold
            size_t perW = (size_t)T * C_DIM;
            int maxW = (int)(obuf_cap_e / perW);
            if (maxW < 2) maxW = 2;
            if (k == 4) maxW &= ~1;
            for (int w0 = 0; w0 < totalW; w0 += maxW) {
                int nW = totalW - w0 < maxW ? totalW - w0 : maxW;
                if (k == 4)
                    attn_v2<4><<<(nW + 1) / 2, 256, 0, stream>>>(qkb, vT, obuf, w0, nW, scale);
                else
                    attn_v3<<<nW, 256, 0, stream>>>(qkb, vT, obuf, w0, scale);
                int last = (w0 + nW >= totalW);
                fold_ln<<<NPIX, 256, 0, stream>>>(obuf, (w0 == 0) ? xcur : nullptr,
                                                  ybuf, ln2_w + i * 256, ln2_b + i * 256,
                                                  lnb, last, k, Lh, Lw, w0, w0 + nW);
            }
        }

        // MLP1 + gelu: M=NPIX, N=512, K=256
        gemm_v2<64, 128, 2><<<dim3(NPIX / 64, 4), 256, 0, stream>>>(
            lnb, w1b + (size_t)i * 512 * 256, mlp_b1 + i * 512, nullptr, h1, nullptr, 256, 512);
        // MLP2 + bias + residual: M=NPIX, N=256, K=512 -> fp32 xcur
        gemm_v2<64, 64, 3><<<dim3(NPIX / 64, 4), 256, 0, stream>>>(
            h1, w2b + (size_t)i * 256 * 512, mlp_b2 + i * 256, ybuf, xcur, nullptr, 512, 256);
    }

    classifier_k<<<dim3(16, 4), 256, 0, stream>>>(xcur, cls_w, cls_b, out);
}

// Round 10
// 633.401 us; speedup vs baseline: 3.5500x; 1.0170x over previous
//
#include <hip/hip_runtime.h>
#include <cmath>

#define NPIX 4352      // 16 * 17 * 16 pixels (incl. cls row)
#define C_DIM 256

typedef unsigned short ushort_t;
typedef unsigned int uint_t;
typedef float f32x4 __attribute__((ext_vector_type(4)));
typedef __bf16 bfx8 __attribute__((ext_vector_type(8)));

__device__ __forceinline__ ushort_t f2bf(float f) {
    uint_t u = __float_as_uint(f);
    u = (u + 0x7FFFu + ((u >> 16) & 1u)) >> 16;
    return (ushort_t)u;
}
__device__ __forceinline__ float bf2f(ushort_t b) {
    return __uint_as_float(((uint_t)b) << 16);
}
__device__ __forceinline__ float gelu_f(float v) {
    return 0.5f * v * (1.0f + erff(v * 0.70710678118654752f));
}

// ---------------- fp32 -> bf16 converter (all 3 weight tensors, 1 launch) ----------------
__global__ __launch_bounds__(256) void conv3_bf16(
    const float* __restrict__ a, ushort_t* __restrict__ oa, int na,
    const float* __restrict__ b, ushort_t* __restrict__ ob, int nb,
    const float* __restrict__ c, ushort_t* __restrict__ oc, int nc)
{
    int ntot = na + nb + nc;
    for (int i = blockIdx.x * 256 + threadIdx.x; i < ntot; i += gridDim.x * 256) {
        if (i < na)            oa[i] = f2bf(a[i]);
        else if (i < na + nb)  ob[i - na] = f2bf(b[i - na]);
        else                   oc[i - na - nb] = f2bf(c[i - na - nb]);
    }
}

// ---------------- patch embed + pos emb + cls row + LN1(layer0) ----------------
__global__ __launch_bounds__(256) void patch_embed_ln(
    const float* __restrict__ x, const float* __restrict__ pw,
    const float* __restrict__ pb, const float* __restrict__ row_emb,
    const float* __restrict__ col_emb, const float* __restrict__ cls_tok,
    const float* __restrict__ lw, const float* __restrict__ lb,
    float* __restrict__ out, ushort_t* __restrict__ lnout)
{
    __shared__ float red[8];
    int p = blockIdx.x;
    int c = threadIdx.x;
    int b = p / 272;
    int rem = p - b * 272;
    int y = rem >> 4;
    int xw = rem & 15;
    float v;
    if (y == 0) {
        v = cls_tok[c];
    } else {
        int gr = y - 1, gc = xw;
        const float* xb = x + (size_t)b * 3 * 1024;
        const float* wc = pw + (size_t)c * 12;
        float acc = pb[c];
        #pragma unroll
        for (int ci = 0; ci < 3; ci++)
            #pragma unroll
            for (int ph = 0; ph < 2; ph++)
                #pragma unroll
                for (int pq = 0; pq < 2; pq++)
                    acc += xb[ci * 1024 + (2 * gr + ph) * 32 + (2 * gc + pq)]
                         * wc[(ci * 2 + ph) * 2 + pq];
        acc += (c < 128) ? row_emb[gr * 128 + c] : col_emb[gc * 128 + (c - 128)];
        v = acc;
    }
    out[(size_t)p * C_DIM + c] = v;
    float s = v;
    s += __shfl_down(s, 32); s += __shfl_down(s, 16); s += __shfl_down(s, 8);
    s += __shfl_down(s, 4);  s += __shfl_down(s, 2);  s += __shfl_down(s, 1);
    if ((c & 63) == 0) red[c >> 6] = s;
    __syncthreads();
    float mu = (red[0] + red[1] + red[2] + red[3]) * (1.0f / 256.0f);
    float d = v - mu;
    float s2 = d * d;
    s2 += __shfl_down(s2, 32); s2 += __shfl_down(s2, 16); s2 += __shfl_down(s2, 8);
    s2 += __shfl_down(s2, 4);  s2 += __shfl_down(s2, 2);  s2 += __shfl_down(s2, 1);
    if ((c & 63) == 0) red[4 + (c >> 6)] = s2;
    __syncthreads();
    float var = (red[4] + red[5] + red[6] + red[7]) * (1.0f / 256.0f);
    lnout[(size_t)p * C_DIM + c] = f2bf(d * rsqrtf(var + 1e-5f) * lw[c] + lb[c]);
}

// ---------------- standalone layernorm: fp32 in -> bf16 out ----------------
__global__ __launch_bounds__(256) void layernorm_k(
    const float* __restrict__ in, const float* __restrict__ w,
    const float* __restrict__ b, ushort_t* __restrict__ out)
{
    __shared__ float red[8];
    int r = blockIdx.x, c = threadIdx.x;
    float v = in[(size_t)r * C_DIM + c];
    float s = v;
    s += __shfl_down(s, 32); s += __shfl_down(s, 16); s += __shfl_down(s, 8);
    s += __shfl_down(s, 4);  s += __shfl_down(s, 2);  s += __shfl_down(s, 1);
    if ((c & 63) == 0) red[c >> 6] = s;
    __syncthreads();
    float mu = (red[0] + red[1] + red[2] + red[3]) * (1.0f / 256.0f);
    float d = v - mu;
    float s2 = d * d;
    s2 += __shfl_down(s2, 32); s2 += __shfl_down(s2, 16); s2 += __shfl_down(s2, 8);
    s2 += __shfl_down(s2, 4);  s2 += __shfl_down(s2, 2);  s2 += __shfl_down(s2, 1);
    if ((c & 63) == 0) red[4 + (c >> 6)] = s2;
    __syncthreads();
    float var = (red[4] + red[5] + red[6] + red[7]) * (1.0f / 256.0f);
    out[(size_t)r * C_DIM + c] = f2bf(d * rsqrtf(var + 1e-5f) * w[c] + b[c]);
}

// ---------------- LDS-staged double-buffered bf16 MFMA GEMM ----------------
template <int BM, int BN, int MODE>
__global__ __launch_bounds__(256) void gemm_v2(
    const ushort_t* __restrict__ A, const ushort_t* __restrict__ B,
    const float* __restrict__ bias, const float* __restrict__ res,
    void* __restrict__ outp, ushort_t* __restrict__ vT, int K, int ldo)
{
    constexpr int MI = BM / 32, NJ = BN / 32;
    constexpr int AG = BM * 4, BG = BN * 4;
    constexpr int AU = AG / 256, BU = BG / 256;
    constexpr int HALF = (BM + BN) * 32;
    constexpr int STAGE_E = 2 * HALF;
    constexpr int BOUNCE_E = BM * (BN + 8);
    constexpr int SMEM_E = (STAGE_E > BOUNCE_E) ? STAGE_E : BOUNCE_E;
    __shared__ ushort_t sm[SMEM_E];

    int m0 = blockIdx.x * BM, n0 = blockIdx.y * BN;
    int t = threadIdx.x, lane = t & 63, wv = t >> 6;
    int l15 = lane & 15, lg = lane >> 4;
    int wr = wv >> 1, wc = wv & 1;

    const int nt = K / 32;
    f32x4 acc[MI][NJ] = {};
    uint4 ra[AU], rb[BU];

    #pragma unroll
    for (int u = 0; u < AU; u++) {
        int g = t + u * 256, row = g >> 2, p = g & 3;
        int ps = p ^ ((row >> 1) & 3);
        ra[u] = *(const uint4*)(A + (size_t)(m0 + row) * K + ps * 8);
    }
    #pragma unroll
    for (int u = 0; u < BU; u++) {
        int g = t + u * 256, col = g >> 2, p = g & 3;
        int ps = p ^ ((col >> 1) & 3);
        rb[u] = *(const uint4*)(B + (size_t)(n0 + col) * K + ps * 8);
    }
    #pragma unroll
    for (int u = 0; u < AU; u++) *(uint4*)(sm + (t + u * 256) * 8) = ra[u];
    #pragma unroll
    for (int u = 0; u < BU; u++) *(uint4*)(sm + BM * 32 + (t + u * 256) * 8) = rb[u];
    __syncthreads();

    for (int ks = 0; ks < nt; ks++) {
        int coff = (ks & 1) * HALF, noff = ((ks & 1) ^ 1) * HALF;
        if (ks + 1 < nt) {
            int k1 = (ks + 1) * 32;
            #pragma unroll
            for (int u = 0; u < AU; u++) {
                int g = t + u * 256, row = g >> 2, p = g & 3;
                int ps = p ^ ((row >> 1) & 3);
                ra[u] = *(const uint4*)(A + (size_t)(m0 + row) * K + k1 + ps * 8);
            }
            #pragma unroll
            for (int u = 0; u < BU; u++) {
                int g = t + u * 256, col = g >> 2, p = g & 3;
                int ps = p ^ ((col >> 1) & 3);
                rb[u] = *(const uint4*)(B + (size_t)(n0 + col) * K + k1 + ps * 8);
            }
        }
        bfx8 af[MI], bf[NJ];
        #pragma unroll
        for (int i = 0; i < MI; i++) {
            int row = wr * (BM / 2) + i * 16 + l15;
            af[i] = *(const bfx8*)(sm + coff + row * 32 + ((lg ^ ((row >> 1) & 3)) << 3));
        }
        #pragma unroll
        for (int j = 0; j < NJ; j++) {
            int col = wc * (BN / 2) + j * 16 + l15;
            bf[j] = *(const bfx8*)(sm + coff + BM * 32 + col * 32 + ((lg ^ ((col >> 1) & 3)) << 3));
        }
        #pragma unroll
        for (int i = 0; i < MI; i++)
            #pragma unroll
            for (int j = 0; j < NJ; j++)
                acc[i][j] = __builtin_amdgcn_mfma_f32_16x16x32_bf16(af[i], bf[j], acc[i][j], 0, 0, 0);
        if (ks + 1 < nt) {
            #pragma unroll
            for (int u = 0; u < AU; u++) *(uint4*)(sm + noff + (t + u * 256) * 8) = ra[u];
            #pragma unroll
            for (int u = 0; u < BU; u++) *(uint4*)(sm + noff + BM * 32 + (t + u * 256) * 8) = rb[u];
        }
        __syncthreads();
    }

    if (MODE == 0 && n0 >= 512) {
        #pragma unroll
        for (int i = 0; i < MI; i++) {
            int mb = m0 + wr * (BM / 2) + i * 16 + lg * 4;
            #pragma unroll
            for (int j = 0; j < NJ; j++) {
                int nv = n0 - 512 + wc * (BN / 2) + j * 16 + l15;
                ushort4 pk;
                pk.x = f2bf(acc[i][j][0]); pk.y = f2bf(acc[i][j][1]);
                pk.z = f2bf(acc[i][j][2]); pk.w = f2bf(acc[i][j][3]);
                *(ushort4*)&vT[(size_t)nv * NPIX + mb] = pk;
            }
        }
        return;
    }
    if (MODE == 3) {
        float* o = (float*)outp;
        #pragma unroll
        for (int i = 0; i < MI; i++) {
            #pragma unroll
            for (int j = 0; j < NJ; j++) {
                int col = n0 + wc * (BN / 2) + j * 16 + l15;
                float bz = bias[col];
                #pragma unroll
                for (int r = 0; r < 4; r++) {
                    int row = m0 + wr * (BM / 2) + i * 16 + lg * 4 + r;
                    o[(size_t)row * ldo + col] = acc[i][j][r] + bz + res[(size_t)row * ldo + col];
                }
            }
        }
        return;
    }
    __syncthreads();
    #pragma unroll
    for (int i = 0; i < MI; i++) {
        #pragma unroll
        for (int j = 0; j < NJ; j++) {
            int cl = wc * (BN / 2) + j * 16 + l15;
            float bz = (MODE == 2) ? bias[n0 + cl] : 0.0f;
            #pragma unroll
            for (int r = 0; r < 4; r++) {
                int rl = wr * (BM / 2) + i * 16 + lg * 4 + r;
                float v = acc[i][j][r];
                if (MODE == 2) v = gelu_f(v + bz);
                sm[rl * (BN + 8) + cl] = f2bf(v);
            }
        }
    }
    __syncthreads();
    ushort_t* ob = (ushort_t*)outp;
    #pragma unroll
    for (int e = 0; e < BM * BN; e += 2048) {
        int idx = e + t * 8;
        int rl = idx / BN, cl = idx % BN;
        uint4 v = *(const uint4*)(sm + rl * (BN + 8) + cl);
        *(uint4*)&ob[(size_t)(m0 + rl) * ldo + n0 + cl] = v;
    }
}

// unaligned (element-granular) loaders from a dword-aligned row
__device__ __forceinline__ uint2 ld_u4_align(const uint_t* drow, int e0) {
    int d0 = e0 >> 1;
    if (!(e0 & 1)) return make_uint2(drow[d0], drow[d0 + 1]);
    uint_t a = drow[d0], b = drow[d0 + 1], c = drow[d0 + 2];
    return make_uint2((a >> 16) | (b << 16), (b >> 16) | (c << 16));
}
__device__ __forceinline__ uint4 ld_u8_align(const uint_t* drow, int e0) {
    int d0 = e0 >> 1;
    if (!(e0 & 1)) return make_uint4(drow[d0], drow[d0 + 1], drow[d0 + 2], drow[d0 + 3]);
    uint_t a = drow[d0], b = drow[d0 + 1], c = drow[d0 + 2], d = drow[d0 + 3], e = drow[d0 + 4];
    return make_uint4((a >> 16) | (b << 16), (b >> 16) | (c << 16),
                      (c >> 16) | (d << 16), (d >> 16) | (e << 16));
}

// ---------------- k=4 attention v4: 2 windows/block, shared-token V, 42KB LDS ----------------
// SH: K [32 tok][256 ch] swz @0 (8192 el); V [256 c][32 tok pad40] @8192 (10240 el);
// P 4 waves x [16 q][40] @18432 (2560 el). Window selection via P zero-padding.
__global__ __launch_bounds__(256) void attn_v4(
    const ushort_t* __restrict__ qk, const ushort_t* __restrict__ vT,
    ushort_t* __restrict__ obuf, int w0, int nW, float scale)
{
    __shared__ ushort_t SH[20992];   // 41984 B
    const int Lw = 13, L = 182;
    int t = threadIdx.x, lane = t & 63, wv = t >> 6;
    int l15 = lane & 15, lg = lane >> 4;
    int wloc = wv & 1, chalf = wv >> 1;
    int wrel = blockIdx.x * 2 + wloc;
    if (wrel >= nW) wrel = nW - 1;

    int pbs[2];
    #pragma unroll
    for (int w = 0; w < 2; w++) {
        int wi = blockIdx.x * 2 + w;
        if (wi >= nW) wi = nW - 1;
        wi += w0;
        int b = wi / L, lrem = wi % L;
        pbs[w] = b * 272 + (lrem / Lw) * 16 + (lrem % Lw);
    }

    // Q fragments (16 queries of this wave's window)
    int qpix = pbs[wloc] + ((l15 >> 2) << 4) + (l15 & 3);
    bfx8 qf[8];
    #pragma unroll
    for (int cs = 0; cs < 8; cs++)
        qf[cs] = *(const bfx8*)(qk + (size_t)qpix * 512 + cs * 32 + lg * 8);

    // stage K: rows 0-15 = win0 tokens, 16-31 = win1 tokens; [row][256] swizzled
    for (int g = t; g < 32 * 32; g += 256) {
        int row = g >> 5, cg = g & 31;
        int pix = pbs[row >> 4] + (((row & 15) >> 2) << 4) + (row & 3);
        uint4 v = *(const uint4*)(qk + (size_t)pix * 512 + 256 + cg * 8);
        *(uint4*)(SH + row * 256 + ((cg ^ (row & 7)) << 3)) = v;
    }
    // stage V: [c][32 tokens] (win0 0-15, win1 16-31), row stride 40 (bank-spread)
    for (int g = t; g < 256 * 4; g += 256) {
        int cr = g >> 2, q8 = g & 3;
        int w = q8 >> 1, sub = q8 & 1;
        const uint_t* drow = (const uint_t*)(vT + (size_t)cr * NPIX);
        int pix0 = pbs[w] + (sub << 5);
        uint2 a  = ld_u4_align(drow, pix0);
        uint2 b2 = ld_u4_align(drow, pix0 + 16);
        uint4 v = make_uint4(a.x, a.y, b2.x, b2.y);
        *(uint4*)(SH + 8192 + cr * 40 + q8 * 8) = v;
    }
    __syncthreads();

    // S = Q.K^T (16x16), krow = wloc*16 + l15
    f32x4 s0 = {};
    #pragma unroll
    for (int cs = 0; cs < 8; cs++) {
        int krow = (wloc << 4) + l15;
        bfx8 kf = *(const bfx8*)(SH + krow * 256 + ((((cs << 2) + lg) ^ (krow & 7)) << 3));
        s0 = __builtin_amdgcn_mfma_f32_16x16x32_bf16(qf[cs], kf, s0, 0, 0, 0);
    }
    float p4[4], lsum[4];
    #pragma unroll
    for (int r = 0; r < 4; r++) {
        float mx = s0[r];
        mx = fmaxf(mx, __shfl_xor(mx, 1));
        mx = fmaxf(mx, __shfl_xor(mx, 2));
        mx = fmaxf(mx, __shfl_xor(mx, 4));
        mx = fmaxf(mx, __shfl_xor(mx, 8));
        p4[r] = __expf(scale * (s0[r] - mx));
        float ps = p4[r];
        ps += __shfl_xor(ps, 1);
        ps += __shfl_xor(ps, 2);
        ps += __shfl_xor(ps, 4);
        ps += __shfl_xor(ps, 8);
        lsum[r] = ps;
    }
    // P: per-wave [16 q][40]; this window's keys at cols wloc*16..+15, other half zero
    ushort_t* Pw = SH + 18432 + wv * 640;
    #pragma unroll
    for (int r = 0; r < 4; r++) {
        Pw[(lg * 4 + r) * 40 + (wloc << 4) + l15] = f2bf(p4[r]);
        Pw[(lg * 4 + r) * 40 + ((wloc ^ 1) << 4) + l15] = 0;
    }
    asm volatile("s_waitcnt lgkmcnt(0)" ::: "memory");
    __builtin_amdgcn_sched_barrier(0);
    // O += P.V over shared 32-token V (zero-padded P selects the window)
    f32x4 o[8] = {};
    {
        bfx8 pf = *(const bfx8*)(Pw + l15 * 40 + (lg << 3));
        #pragma unroll
        for (int j = 0; j < 8; j++) {
            int c = chalf * 128 + (j << 4) + l15;
            bfx8 vf = *(const bfx8*)(SH + 8192 + c * 40 + (lg << 3));
            o[j] = __builtin_amdgcn_mfma_f32_16x16x32_bf16(pf, vf, o[j], 0, 0, 0);
        }
    }
    asm volatile("s_waitcnt lgkmcnt(0)" ::: "memory");
    __syncthreads();
    float inv[4];
    #pragma unroll
    for (int r = 0; r < 4; r++) inv[r] = 1.0f / lsum[r];
    ushort_t* Ep = SH + wv * 2176;    // 16 rows x 136 (272B, 16B-aligned)
    #pragma unroll
    for (int j = 0; j < 8; j++)
        #pragma unroll
        for (int r = 0; r < 4; r++)
            Ep[(lg * 4 + r) * 136 + (j << 4) + l15] = f2bf(o[j][r] * inv[r]);
    asm volatile("s_waitcnt lgkmcnt(0)" ::: "memory");
    __builtin_amdgcn_sched_barrier(0);
    size_t gb = ((size_t)wrel * 16) * C_DIM + chalf * 128;
    #pragma unroll
    for (int i = 0; i < 4; i++) {
        int off = i * 512 + lane * 8;
        int row = off >> 7, col = off & 127;
        uint4 v = *(const uint4*)(Ep + row * 136 + col);
        *(uint4*)(obuf + gb + (size_t)row * C_DIM + col) = v;
    }
}

// ---------------- k=8 attention v3b: two-pass K staging, 48KB LDS ----------------
// SH: K-half [64 tok][128 ch] swz @0 (8192 el); V [256 c][64 tok] swz @8192 (16384 el).
__global__ __launch_bounds__(256) void attn_v3(
    const ushort_t* __restrict__ qk, const ushort_t* __restrict__ vT,
    ushort_t* __restrict__ obuf, int w0, float scale)
{
    __shared__ ushort_t SH[24576];    // 48 KB
    const int Lw = 9, L = 90;
    int t = threadIdx.x, lane = t & 63, wv = t >> 6;
    int l15 = lane & 15, lg = lane >> 4;
    int wrel = blockIdx.x;
    int widx = w0 + wrel;
    int b = widx / L, lrem = widx % L;
    int pbase = b * 272 + (lrem / Lw) * 16 + (lrem % Lw);
    int qbase = wv * 16;

    int qtok = qbase + l15;
    int qpix = pbase + ((qtok >> 3) << 4) + (qtok & 7);
    bfx8 qf[8];
    #pragma unroll
    for (int cs = 0; cs < 8; cs++)
        qf[cs] = *(const bfx8*)(qk + (size_t)qpix * 512 + cs * 32 + lg * 8);

    // stage K half 0 (ch 0-127): [64][128] swizzled
    for (int g = t; g < 64 * 16; g += 256) {
        int row = g >> 4, cg = g & 15;
        int pix = pbase + ((row >> 3) << 4) + (row & 7);
        uint4 v = *(const uint4*)(qk + (size_t)pix * 512 + 256 + cg * 8);
        *(uint4*)(SH + row * 128 + ((cg ^ (row & 7)) << 3)) = v;
    }
    // stage V [256][64] swizzled
    for (int g = t; g < 256 * 8; g += 256) {
        int cr = g >> 3, c16 = g & 7;
        const uint_t* drow = (const uint_t*)(vT + (size_t)cr * NPIX);
        uint4 v = ld_u8_align(drow, pbase + (c16 << 4));
        *(uint4*)(SH + 8192 + cr * 64 + ((c16 ^ (cr & 7)) << 3)) = v;
    }
    __syncthreads();

    // QK pass 0: channels 0-127
    f32x4 s[4];
    #pragma unroll
    for (int j = 0; j < 4; j++) s[j] = f32x4{0.f, 0.f, 0.f, 0.f};
    #pragma unroll
    for (int cs = 0; cs < 4; cs++) {
        #pragma unroll
        for (int j = 0; j < 4; j++) {
            int krow = (j << 4) + l15;
            bfx8 kf = *(const bfx8*)(SH + krow * 128 + ((((cs << 2) + lg) ^ (krow & 7)) << 3));
            s[j] = __builtin_amdgcn_mfma_f32_16x16x32_bf16(qf[cs], kf, s[j], 0, 0, 0);
        }
    }
    __syncthreads();
    // stage K half 1 (ch 128-255) into same region
    for (int g = t; g < 64 * 16; g += 256) {
        int row = g >> 4, cg = g & 15;
        int pix = pbase + ((row >> 3) << 4) + (row & 7);
        uint4 v = *(const uint4*)(qk + (size_t)pix * 512 + 384 + cg * 8);
        *(uint4*)(SH + row * 128 + ((cg ^ (row & 7)) << 3)) = v;
    }
    __syncthreads();
    // QK pass 1: channels 128-255
    #pragma unroll
    for (int cs = 4; cs < 8; cs++) {
        #pragma unroll
        for (int j = 0; j < 4; j++) {
            int krow = (j << 4) + l15;
            bfx8 kf = *(const bfx8*)(SH + krow * 128 + (((((cs - 4) << 2) + lg) ^ (krow & 7)) << 3));
            s[j] = __builtin_amdgcn_mfma_f32_16x16x32_bf16(qf[cs], kf, s[j], 0, 0, 0);
        }
    }
    float p[4][4], lsum[4];
    #pragma unroll
    for (int r = 0; r < 4; r++) {
        float mx = s[0][r];
        #pragma unroll
        for (int j = 1; j < 4; j++) mx = fmaxf(mx, s[j][r]);
        mx = fmaxf(mx, __shfl_xor(mx, 1));
        mx = fmaxf(mx, __shfl_xor(mx, 2));
        mx = fmaxf(mx, __shfl_xor(mx, 4));
        mx = fmaxf(mx, __shfl_xor(mx, 8));
        float ps = 0.f;
        #pragma unroll
        for (int j = 0; j < 4; j++) {
            p[j][r] = __expf(scale * (s[j][r] - mx));
            ps += p[j][r];
        }
        ps += __shfl_xor(ps, 1);
        ps += __shfl_xor(ps, 2);
        ps += __shfl_xor(ps, 4);
        ps += __shfl_xor(ps, 8);
        lsum[r] = ps;
    }
    __syncthreads();   // all waves done with K -> P overlays K region
    ushort_t* Pw = SH + wv * 1088;
    #pragma unroll
    for (int j = 0; j < 4; j++)
        #pragma unroll
        for (int r = 0; r < 4; r++)
            Pw[(lg * 4 + r) * 68 + (j << 4) + l15] = f2bf(p[j][r]);
    asm volatile("s_waitcnt lgkmcnt(0)" ::: "memory");
    __builtin_amdgcn_sched_barrier(0);
    f32x4 o[16] = {};
    #pragma unroll
    for (int kt = 0; kt < 2; kt++) {
        bfx8 pf = *(const bfx8*)(Pw + l15 * 68 + (kt << 5) + (lg << 3));
        #pragma unroll
        for (int j = 0; j < 16; j++) {
            int cr = (j << 4) + l15;
            int c16 = ((kt << 2) + lg) ^ (cr & 7);
            bfx8 vf = *(const bfx8*)(SH + 8192 + cr * 64 + (c16 << 3));
            o[j] = __builtin_amdgcn_mfma_f32_16x16x32_bf16(pf, vf, o[j], 0, 0, 0);
        }
    }
    asm volatile("s_waitcnt lgkmcnt(0)" ::: "memory");
    __syncthreads();
    float inv[4];
    #pragma unroll
    for (int r = 0; r < 4; r++) inv[r] = 1.0f / lsum[r];
    ushort_t* Ep = SH + wv * 4224;    // 16 rows x 264 (528B, 16B-aligned)
    #pragma unroll
    for (int j = 0; j < 16; j++)
        #pragma unroll
        for (int r = 0; r < 4; r++)
            Ep[(lg * 4 + r) * 264 + (j << 4) + l15] = f2bf(o[j][r] * inv[r]);
    asm volatile("s_waitcnt lgkmcnt(0)" ::: "memory");
    __builtin_amdgcn_sched_barrier(0);
    size_t gb = ((size_t)wrel * 64 + qbase) * C_DIM;
    #pragma unroll
    for (int i = 0; i < 8; i++) {
        int off = i * 512 + lane * 8;
        int row = off >> 8, col = off & 255;
        uint4 v = *(const uint4*)(Ep + row * 264 + col);
        *(uint4*)(obuf + gb + off) = v;
    }
}

// ---------------- k=16 attention as batched-GEMM passes over 32 dense seqs ----------------
template <int PASS>
__global__ __launch_bounds__(256) void gemm_seq(
    const ushort_t* __restrict__ A, const ushort_t* __restrict__ B,
    const float* __restrict__ linv, void* __restrict__ outp)
{
    __shared__ ushort_t sm[8192];
    int m0 = blockIdx.x * 64, n0 = blockIdx.y * 64;
    int seq = blockIdx.z;
    int pbase = (seq >> 1) * 272 + (seq & 1) * 16;
    int t = threadIdx.x, lane = t & 63, wv = t >> 6;
    int l15 = lane & 15, lg = lane >> 4;
    int wr = wv >> 1, wc = wv & 1;

    f32x4 acc[2][2] = {};
    uint4 ra, rb;

    int g_row = t >> 2, g_p = t & 3;
    int g_ps = g_p ^ ((g_row >> 1) & 3);

    const ushort_t* Asrc;
    const ushort_t* Bsrc;
    if (PASS == 0) {
        Asrc = A + (size_t)(pbase + m0 + g_row) * 512 + g_ps * 8;
        Bsrc = B + (size_t)(pbase + n0 + g_row) * 512 + 256 + g_ps * 8;
    } else {
        Asrc = A + (size_t)seq * 65536 + (size_t)(m0 + g_row) * 256 + g_ps * 8;
        Bsrc = B + (size_t)(n0 + g_row) * NPIX + pbase + g_ps * 8;
    }

    ra = *(const uint4*)(Asrc);
    rb = *(const uint4*)(Bsrc);
    *(uint4*)(sm + t * 8) = ra;
    *(uint4*)(sm + 2048 + t * 8) = rb;
    __syncthreads();

    for (int ks = 0; ks < 8; ks++) {
        int coff = (ks & 1) * 4096, noff = ((ks & 1) ^ 1) * 4096;
        if (ks + 1 < 8) {
            int k1 = (ks + 1) * 32;
            ra = *(const uint4*)(Asrc + k1);
            rb = *(const uint4*)(Bsrc + k1);
        }
        bfx8 af[2], bf[2];
        #pragma unroll
        for (int i = 0; i < 2; i++) {
            int row = wr * 32 + i * 16 + l15;
            af[i] = *(const bfx8*)(sm + coff + row * 32 + ((lg ^ ((row >> 1) & 3)) << 3));
        }
        #pragma unroll
        for (int j = 0; j < 2; j++) {
            int col = wc * 32 + j * 16 + l15;
            bf[j] = *(const bfx8*)(sm + coff + 2048 + col * 32 + ((lg ^ ((col >> 1) & 3)) << 3));
        }
        #pragma unroll
        for (int i = 0; i < 2; i++)
            #pragma unroll
            for (int j = 0; j < 2; j++)
                acc[i][j] = __builtin_amdgcn_mfma_f32_16x16x32_bf16(af[i], bf[j], acc[i][j], 0, 0, 0);
        if (ks + 1 < 8) {
            *(uint4*)(sm + noff + t * 8) = ra;
            *(uint4*)(sm + noff + 2048 + t * 8) = rb;
        }
        __syncthreads();
    }

    if (PASS == 0) {
        float* S = (float*)outp + (size_t)seq * 65536;
        #pragma unroll
        for (int i = 0; i < 2; i++) {
            #pragma unroll
            for (int j = 0; j < 2; j++) {
                int col = n0 + wc * 32 + j * 16 + l15;
                #pragma unroll
                for (int r = 0; r < 4; r++) {
                    int row = m0 + wr * 32 + i * 16 + lg * 4 + r;
                    S[(size_t)row * 256 + col] = acc[i][j][r];
                }
            }
        }
        return;
    }
    ushort_t* ob = (ushort_t*)outp;
    #pragma unroll
    for (int i = 0; i < 2; i++) {
        #pragma unroll
        for (int j = 0; j < 2; j++) {
            int cl = wc * 32 + j * 16 + l15;
            #pragma unroll
            for (int r = 0; r < 4; r++) {
                int rl = wr * 32 + i * 16 + lg * 4 + r;
                float v = acc[i][j][r] * linv[seq * 256 + m0 + rl];
                sm[rl * 72 + cl] = f2bf(v);
            }
        }
    }
    __syncthreads();
    #pragma unroll
    for (int e = 0; e < 4096; e += 2048) {
        int idx = e + t * 8;
        int rl = idx >> 6, cl = idx & 63;
        uint4 v = *(const uint4*)(sm + rl * 72 + cl);
        *(uint4*)&ob[(size_t)seq * 65536 + (size_t)(m0 + rl) * 256 + n0 + cl] = v;
    }
}

// row softmax: S fp32 [8192 rows][256] -> P bf16 + 1/lsum
__global__ __launch_bounds__(256) void rowsm(
    const float* __restrict__ sbuf, ushort_t* __restrict__ pbuf,
    float* __restrict__ linv, float scale)
{
    __shared__ float red[8];
    int r = blockIdx.x, t = threadIdx.x;
    float s = sbuf[(size_t)r * 256 + t];
    float m = s;
    m = fmaxf(m, __shfl_down(m, 32)); m = fmaxf(m, __shfl_down(m, 16));
    m = fmaxf(m, __shfl_down(m, 8));  m = fmaxf(m, __shfl_down(m, 4));
    m = fmaxf(m, __shfl_down(m, 2));  m = fmaxf(m, __shfl_down(m, 1));
    if ((t & 63) == 0) red[t >> 6] = m;
    __syncthreads();
    m = fmaxf(fmaxf(red[0], red[1]), fmaxf(red[2], red[3]));
    float p = __expf(scale * (s - m));
    float ps = p;
    ps += __shfl_down(ps, 32); ps += __shfl_down(ps, 16); ps += __shfl_down(ps, 8);
    ps += __shfl_down(ps, 4);  ps += __shfl_down(ps, 2);  ps += __shfl_down(ps, 1);
    if ((t & 63) == 0) red[4 + (t >> 6)] = ps;
    __syncthreads();
    float sum = red[4] + red[5] + red[6] + red[7];
    pbuf[(size_t)r * 256 + t] = f2bf(p);
    if (t == 0) linv[r] = 1.0f / sum;
}

// ---------------- separable fold stage A: horizontal overlap-add ----------------
template <int K>
__global__ __launch_bounds__(256) void foldA(
    const ushort_t* __restrict__ obuf, float* __restrict__ rowsum)
{
    constexpr int Lh = 18 - K, Lw = 17 - K, L = Lh * Lw, T = K * K;
    int c = threadIdx.x;
    int bid = blockIdx.x;
    int dy = bid % K;
    int blh = bid / K;
    int lh = blh % Lh;
    int b = blh / Lh;
    float acc[16];
    #pragma unroll
    for (int x = 0; x < 16; x++) acc[x] = 0.f;
    const ushort_t* base = obuf + ((size_t)(b * L + lh * Lw) * T + dy * K) * C_DIM + c;
    #pragma unroll
    for (int lw = 0; lw < Lw; lw++)
        #pragma unroll
        for (int dx = 0; dx < K; dx++)
            acc[lw + dx] += bf2f(base[((size_t)lw * T + dx) * C_DIM]);
    float* orow = rowsum + (size_t)bid * 16 * C_DIM + c;
    #pragma unroll
    for (int x = 0; x < 16; x++) orow[(size_t)x * C_DIM] = acc[x];
}

// ---------------- separable fold stage B: vertical + residual + fused LN2 ----------------
template <int K>
__global__ __launch_bounds__(256) void foldB(
    const float* __restrict__ rowsum, const float* __restrict__ xin,
    float* __restrict__ y, const float* __restrict__ lw_,
    const float* __restrict__ lb_, ushort_t* __restrict__ lnout)
{
    constexpr int Lh = 18 - K;
    __shared__ float red[8];
    int p = blockIdx.x, c = threadIdx.x;
    int b = p / 272, rem = p - b * 272;
    int yy = rem >> 4, xx = rem & 15;
    float acc = xin[(size_t)p * C_DIM + c];
    #pragma unroll
    for (int dy = 0; dy < K; dy++) {
        int lh = yy - dy;
        if (lh >= 0 && lh < Lh)
            acc += rowsum[(((size_t)(b * Lh + lh) * K + dy) * 16 + xx) * C_DIM + c];
    }
    y[(size_t)p * C_DIM + c] = acc;
    float s = acc;
    s += __shfl_down(s, 32); s += __shfl_down(s, 16); s += __shfl_down(s, 8);
    s += __shfl_down(s, 4);  s += __shfl_down(s, 2);  s += __shfl_down(s, 1);
    if ((c & 63) == 0) red[c >> 6] = s;
    __syncthreads();
    float mu = (red[0] + red[1] + red[2] + red[3]) * (1.0f / 256.0f);
    float d = acc - mu;
    float s2 = d * d;
    s2 += __shfl_down(s2, 32); s2 += __shfl_down(s2, 16); s2 += __shfl_down(s2, 8);
    s2 += __shfl_down(s2, 4);  s2 += __shfl_down(s2, 2);  s2 += __shfl_down(s2, 1);
    if ((c & 63) == 0) red[4 + (c >> 6)] = s2;
    __syncthreads();
    float var = (red[4] + red[5] + red[6] + red[7]) * (1.0f / 256.0f);
    lnout[(size_t)p * C_DIM + c] = f2bf(d * rsqrtf(var + 1e-5f) * lw_[c] + lb_[c]);
}

// ---------------- k=16 fold: <=2 dense-seq terms + residual + fused LN2 ----------------
__global__ __launch_bounds__(256) void foldB16(
    const ushort_t* __restrict__ obuf, const float* __restrict__ xin,
    float* __restrict__ y, const float* __restrict__ lw_,
    const float* __restrict__ lb_, ushort_t* __restrict__ lnout)
{
    __shared__ float red[8];
    int p = blockIdx.x, c = threadIdx.x;
    int b = p / 272, rem = p - b * 272;
    int yy = rem >> 4, xx = rem & 15;
    float acc = xin[(size_t)p * C_DIM + c];
    if (yy <= 15)
        acc += bf2f(obuf[((size_t)(b * 2) * 256 + (yy * 16 + xx)) * C_DIM + c]);
    if (yy >= 1)
        acc += bf2f(obuf[((size_t)(b * 2 + 1) * 256 + ((yy - 1) * 16 + xx)) * C_DIM + c]);
    y[(size_t)p * C_DIM + c] = acc;
    float s = acc;
    s += __shfl_down(s, 32); s += __shfl_down(s, 16); s += __shfl_down(s, 8);
    s += __shfl_down(s, 4);  s += __shfl_down(s, 2);  s += __shfl_down(s, 1);
    if ((c & 63) == 0) red[c >> 6] = s;
    __syncthreads();
    float mu = (red[0] + red[1] + red[2] + red[3]) * (1.0f / 256.0f);
    float d = acc - mu;
    float s2 = d * d;
    s2 += __shfl_down(s2, 32); s2 += __shfl_down(s2, 16); s2 += __shfl_down(s2, 8);
    s2 += __shfl_down(s2, 4);  s2 += __shfl_down(s2, 2);  s2 += __shfl_down(s2, 1);
    if ((c & 63) == 0) red[4 + (c >> 6)] = s2;
    __syncthreads();
    float var = (red[4] + red[5] + red[6] + red[7]) * (1.0f / 256.0f);
    lnout[(size_t)p * C_DIM + c] = f2bf(d * rsqrtf(var + 1e-5f) * lw_[c] + lb_[c]);
}

// ---------------- overlap-add fold + residual (fallback path only) ----------------
__global__ __launch_bounds__(256) void fold_ln(
    const ushort_t* __restrict__ obuf, const float* __restrict__ xin,
    float* __restrict__ y, const float* __restrict__ lw,
    const float* __restrict__ lb, ushort_t* __restrict__ lnout, int do_ln,
    int k, int Lh, int Lw, int w0, int w1)
{
    __shared__ float red[8];
    int p = blockIdx.x;
    int c = threadIdx.x;
    int b = p / 272;
    int rem = p - b * 272;
    int yy = rem >> 4, xx = rem & 15;
    int L = Lh * Lw;
    int T = k * k;
    float acc = xin ? xin[(size_t)p * C_DIM + c] : y[(size_t)p * C_DIM + c];
    int lh0 = max(0, yy - k + 1), lh1 = min(Lh - 1, yy);
    int lw0 = max(0, xx - k + 1), lw1 = min(Lw - 1, xx);
    for (int lh = lh0; lh <= lh1; lh++) {
        for (int lw = lw0; lw <= lw1; lw++) {
            int widx = b * L + lh * Lw + lw;
            if (widx < w0 || widx >= w1) continue;
            int n = (yy - lh) * k + (xx - lw);
            acc += bf2f(obuf[((size_t)(widx - w0) * T + n) * C_DIM + c]);
        }
    }
    y[(size_t)p * C_DIM + c] = acc;
    if (!do_ln) return;
    float s = acc;
    s += __shfl_down(s, 32); s += __shfl_down(s, 16); s += __shfl_down(s, 8);
    s += __shfl_down(s, 4);  s += __shfl_down(s, 2);  s += __shfl_down(s, 1);
    if ((c & 63) == 0) red[c >> 6] = s;
    __syncthreads();
    float mu = (red[0] + red[1] + red[2] + red[3]) * (1.0f / 256.0f);
    float d = acc - mu;
    float s2 = d * d;
    s2 += __shfl_down(s2, 32); s2 += __shfl_down(s2, 16); s2 += __shfl_down(s2, 8);
    s2 += __shfl_down(s2, 4);  s2 += __shfl_down(s2, 2);  s2 += __shfl_down(s2, 1);
    if ((c & 63) == 0) red[4 + (c >> 6)] = s2;
    __syncthreads();
    float var = (red[4] + red[5] + red[6] + red[7]) * (1.0f / 256.0f);
    lnout[(size_t)p * C_DIM + c] = f2bf(d * rsqrtf(var + 1e-5f) * lw[c] + lb[c]);
}

// ---------------- classifier ----------------
__global__ __launch_bounds__(256) void classifier_k(
    const float* __restrict__ h, const float* __restrict__ cw,
    const float* __restrict__ cb, float* __restrict__ out)
{
    __shared__ float hrow[256];
    int b = blockIdx.x;
    int n = blockIdx.y * 256 + threadIdx.x;
    hrow[threadIdx.x] = h[(size_t)b * 272 * C_DIM + threadIdx.x];
    __syncthreads();
    if (n < 1000) {
        float acc = cb[n];
        const float* wr = cw + (size_t)n * C_DIM;
        for (int c = 0; c < 256; c++) acc += hrow[c] * wr[c];
        out[(size_t)b * 1000 + n] = acc;
    }
}

extern "C" void kernel_launch(void* const* d_in, const int* in_sizes, int n_in,
                              void* d_out, int out_size, void* d_ws, size_t ws_size,
                              hipStream_t stream)
{
    const float* x       = (const float*)d_in[0];
    const float* patch_w = (const float*)d_in[1];
    const float* patch_b = (const float*)d_in[2];
    const float* row_emb = (const float*)d_in[3];
    const float* col_emb = (const float*)d_in[4];
    const float* cls_tok = (const float*)d_in[5];
    const float* ln1_w   = (const float*)d_in[6];
    const float* ln1_b   = (const float*)d_in[7];
    const float* qkv_w   = (const float*)d_in[8];
    const float* ln2_w   = (const float*)d_in[9];
    const float* ln2_b   = (const float*)d_in[10];
    const float* mlp_w1  = (const float*)d_in[11];
    const float* mlp_b1  = (const float*)d_in[12];
    const float* mlp_w2  = (const float*)d_in[13];
    const float* mlp_b2  = (const float*)d_in[14];
    const float* cls_w   = (const float*)d_in[15];
    const float* cls_b   = (const float*)d_in[16];
    float* out = (float*)d_out;

    // workspace layout (all 16B aligned)
    float* xb0  = (float*)d_ws;                          // NPIX*256 f32
    float* xb1  = xb0 + (size_t)NPIX * 256;              // NPIX*256 f32
    ushort_t* lnb = (ushort_t*)(xb1 + (size_t)NPIX * 256);   // NPIX*256 bf16
    ushort_t* qkb = lnb + (size_t)NPIX * 256;            // NPIX*512 bf16 (Q|K)
    ushort_t* vT  = qkb + (size_t)NPIX * 512;            // 256*NPIX bf16
    ushort_t* h1  = vT + (size_t)256 * NPIX;             // NPIX*512 bf16
    ushort_t* wq  = h1 + (size_t)NPIX * 512;             // 7*768*256 bf16
    ushort_t* w1b = wq + (size_t)7 * 768 * 256;          // 7*512*256 bf16
    ushort_t* w2b = w1b + (size_t)7 * 512 * 256;         // 7*256*512 bf16
    float* scratch = (float*)(w2b + (size_t)7 * 256 * 512);
    float* rowsum  = scratch;                                 // 5,242,880 f32 (21MB)
    float* sbuf    = scratch;                                 // 32*65536 f32 (8MB)
    ushort_t* pbuf = (ushort_t*)(sbuf + (size_t)32 * 65536);  // 32*65536 bf16 (4MB)
    float* linv    = (float*)(pbuf + (size_t)32 * 65536);     // 8192 f32
    ushort_t* obuf = (ushort_t*)(rowsum + 5242880);           // rest of ws
    size_t obuf_off_bytes = (size_t)((char*)obuf - (char*)d_ws);
    size_t obuf_cap_e = (ws_size > obuf_off_bytes + 64)
                        ? (ws_size - obuf_off_bytes - 64) / 2 : 0;

    conv3_bf16<<<1024, 256, 0, stream>>>(qkv_w, wq, 7 * 768 * 256,
                                         mlp_w1, w1b, 7 * 512 * 256,
                                         mlp_w2, w2b, 7 * 256 * 512);

    patch_embed_ln<<<NPIX, 256, 0, stream>>>(x, patch_w, patch_b, row_emb,
                                             col_emb, cls_tok, ln1_w, ln1_b,
                                             xb0, lnb);

    const int KS[7] = {4, 4, 8, 8, 8, 16, 16};
    float* xcur = xb0;
    float* ybuf = xb1;

    for (int i = 0; i < 7; i++) {
        int k = KS[i];
        int Lh = 18 - k, Lw = 17 - k, L = Lh * Lw, T = k * k;
        float scale = 1.0f / std::sqrt((float)(256 / k));

        if (i > 0)
            layernorm_k<<<NPIX, 256, 0, stream>>>(xcur, ln1_w + i * 256,
                                                  ln1_b + i * 256, lnb);
        // QKV GEMM: M=NPIX, N=768, K=256
        gemm_v2<128, 128, 0><<<dim3(NPIX / 128, 6), 256, 0, stream>>>(
            lnb, wq + (size_t)i * 768 * 256, nullptr, nullptr, qkb, vT, 256, 512);

        int totalW = 16 * L;
        if (k == 16) {
            // dense attention over 32 contiguous 256-token sequences
            gemm_seq<0><<<dim3(4, 4, 32), 256, 0, stream>>>(qkb, qkb, nullptr, sbuf);
            rowsm<<<8192, 256, 0, stream>>>(sbuf, pbuf, linv, scale);
            gemm_seq<1><<<dim3(4, 4, 32), 256, 0, stream>>>(pbuf, vT, linv, obuf);
            foldB16<<<NPIX, 256, 0, stream>>>(obuf, xcur, ybuf,
                                              ln2_w + i * 256, ln2_b + i * 256, lnb);
        } else if ((size_t)totalW * T * C_DIM <= obuf_cap_e) {
            // single-chunk attention + separable fold
            if (k == 4) {
                attn_v4<<<(totalW + 1) / 2, 256, 0, stream>>>(qkb, vT, obuf, 0, totalW, scale);
                foldA<4><<<16 * 14 * 4, 256, 0, stream>>>(obuf, rowsum);
                foldB<4><<<NPIX, 256, 0, stream>>>(rowsum, xcur, ybuf,
                                                   ln2_w + i * 256, ln2_b + i * 256, lnb);
            } else {
                attn_v3<<<totalW, 256, 0, stream>>>(qkb, vT, obuf, 0, scale);
                foldA<8><<<16 * 10 * 8, 256, 0, stream>>>(obuf, rowsum);
                foldB<8><<<NPIX, 256, 0, stream>>>(rowsum, xcur, ybuf,
                                                   ln2_w + i * 256, ln2_b + i * 256, lnb);
            }
        } else {
            // fallback: chunked attention + direct fold
            size_t perW = (size_t)T * C_DIM;
            int maxW = (int)(obuf_cap_e / perW);
            if (maxW < 2) maxW = 2;
            if (k == 4) maxW &= ~1;
            for (int w0 = 0; w0 < totalW; w0 += maxW) {
                int nW = totalW - w0 < maxW ? totalW - w0 : maxW;
                if (k == 4)
                    attn_v4<<<(nW + 1) / 2, 256, 0, stream>>>(qkb, vT, obuf, w0, nW, scale);
                else
                    attn_v3<<<nW, 256, 0, stream>>>(qkb, vT, obuf, w0, scale);
                int last = (w0 + nW >= totalW);
                fold_ln<<<NPIX, 256, 0, stream>>>(obuf, (w0 == 0) ? xcur : nullptr,
                                                  ybuf, ln2_w + i * 256, ln2_b + i * 256,
                                                  lnb, last, k, Lh, Lw, w0, w0 + nW);
            }
        }

        // MLP1 + gelu: M=NPIX, N=512, K=256
        gemm_v2<64, 128, 2><<<dim3(NPIX / 64, 4), 256, 0, stream>>>(
            lnb, w1b + (size_t)i * 512 * 256, mlp_b1 + i * 512, nullptr, h1, nullptr, 256, 512);
        // MLP2 + bias + residual: M=NPIX, N=256, K=512 -> fp32 xcur
        gemm_v2<64, 64, 3><<<dim3(NPIX / 64, 4), 256, 0, stream>>>(
            h1, w2b + (size_t)i * 256 * 512, mlp_b2 + i * 256, ybuf, xcur, nullptr, 512, 256);
    }

    classifier_k<<<dim3(16, 4), 256, 0, stream>>>(xcur, cls_w, cls_b, out);
}